// Round 14
// baseline (217.169 us; speedup 1.0000x reference)
//
#include <hip/hip_runtime.h>
#include <hip/hip_bf16.h>
#include <math.h>

#define N_NODES 20000
#define MPAD 20096               // 157*128
#define N_EDGES 320000
#define EP (N_EDGES + N_NODES)   // 340000
#define F_IN 256
#define NHID 64
#define H1 8
#define D1 512
#define NCLS 40
#define NEG_SLOPE 0.2f
#define MAXD 128

typedef __attribute__((ext_vector_type(8))) short bf16x8;
typedef __attribute__((ext_vector_type(4))) float f32x4;

__device__ __forceinline__ float wave_max(float v) {
#pragma unroll
  for (int o = 32; o > 0; o >>= 1) v = fmaxf(v, __shfl_xor(v, o));
  return v;
}
__device__ __forceinline__ float wave_sum(float v) {
#pragma unroll
  for (int o = 32; o > 0; o >>= 1) v += __shfl_xor(v, o);
  return v;
}
__device__ __forceinline__ unsigned short f2bf(float f) {
  union { float f; unsigned int i; } c; c.f = f;
  unsigned int x = c.i;
  return (unsigned short)((x + 0x7fffu + ((x >> 16) & 1u)) >> 16);  // RNE
}
__device__ __forceinline__ float asf(unsigned int u) {
  union { unsigned int i; float f; } c; c.i = u; return c.f;
}
__device__ __forceinline__ float lrelu(float x) { return x > 0.f ? x : NEG_SLOPE * x; }

__device__ __forceinline__ void gload16(const void* g, void* l) {
  __builtin_amdgcn_global_load_lds((const __attribute__((address_space(1))) void*)g,
                                   (__attribute__((address_space(3))) void*)l, 16, 0, 0);
}

// ---------------- fused prep ----------------
#define PB_CONV 2512             // MPAD*F_IN/8/256
#define PB_TW1  (PB_CONV + 32)
#define PB_TW2  (PB_TW1 + 96)
#define PB_ZERO (PB_TW2 + 157)
#define PB_PAD  (PB_ZERO + 24)
__global__ __launch_bounds__(256) void prep_kernel(const float* __restrict__ x,
                                                   const float* __restrict__ W1,
                                                   const float* __restrict__ W2,
                                                   unsigned short* __restrict__ xb,
                                                   unsigned short* __restrict__ wb1t,
                                                   unsigned short* __restrict__ wb2t,
                                                   int* __restrict__ deg,
                                                   int* __restrict__ cursor,
                                                   unsigned short* __restrict__ out1b) {
  __shared__ float tsh[64][65];
  int bid = blockIdx.x;
  int t = threadIdx.x;
  if (bid < PB_CONV) {
    size_t base = ((size_t)bid * 256 + t) * 8;
    int row = (int)(base >> 8);
    ushort4 o0, o1;
    if (row < N_NODES) {
      float4 v0 = *(const float4*)&x[base];
      float4 v1 = *(const float4*)&x[base + 4];
      o0 = make_ushort4(f2bf(v0.x), f2bf(v0.y), f2bf(v0.z), f2bf(v0.w));
      o1 = make_ushort4(f2bf(v1.x), f2bf(v1.y), f2bf(v1.z), f2bf(v1.w));
    } else {
      o0 = make_ushort4(0, 0, 0, 0); o1 = o0;
    }
    *(ushort4*)&xb[base] = o0;
    *(ushort4*)&xb[base + 4] = o1;
  } else if (bid < PB_TW1) {
    int b2 = bid - PB_CONV;
    int bk = b2 & 3, bn = b2 >> 2;
    int tr = t >> 4, tc4 = (t & 15) * 4;
#pragma unroll
    for (int i = 0; i < 4; ++i) {
      int k = i * 16 + tr;
      float4 v = *(const float4*)&W1[(size_t)(bk * 64 + k) * D1 + bn * 64 + tc4];
      tsh[k][tc4] = v.x; tsh[k][tc4 + 1] = v.y; tsh[k][tc4 + 2] = v.z; tsh[k][tc4 + 3] = v.w;
    }
    __syncthreads();
#pragma unroll
    for (int i = 0; i < 4; ++i) {
      int n = i * 16 + tr;
      ushort4 o = make_ushort4(f2bf(tsh[tc4][n]), f2bf(tsh[tc4 + 1][n]),
                               f2bf(tsh[tc4 + 2][n]), f2bf(tsh[tc4 + 3][n]));
      *(ushort4*)&wb1t[(size_t)(bn * 64 + n) * F_IN + bk * 64 + tc4] = o;
    }
  } else if (bid < PB_TW2) {
    int idx = (bid - PB_TW1) * 256 + t;
    int c = idx >> 9, k = idx & 511;
    wb2t[idx] = f2bf((c < NCLS) ? W2[(size_t)k * NCLS + c] : 0.f);
  } else if (bid < PB_ZERO) {
    int idx = (bid - PB_TW2) * 256 + t;
    if (idx < N_NODES) deg[idx] = 0;
    else if (idx < 2 * N_NODES) cursor[idx - N_NODES] = 0;
  } else {
    int idx = (bid - PB_ZERO) * 256 + t;
    uint4 z = make_uint4(0, 0, 0, 0);
    *(uint4*)((char*)out1b + (size_t)N_NODES * D1 * 2 + (size_t)idx * 16) = z;
  }
}

// ---------------- CSR build ----------------
__global__ void count_deg(const int* __restrict__ ei, int* __restrict__ deg) {
  int e = blockIdx.x * blockDim.x + threadIdx.x;
  if (e >= EP) return;
  int dst = (e < N_EDGES) ? ei[N_EDGES + e] : (e - N_EDGES);
  atomicAdd(&deg[dst], 1);
}

#define SCAN_T 1024
#define SCAN_CHUNK 20
// offsets scan + 64-bin degree histogram -> binoff/bincur (for degree-bucketed perm)
__global__ __launch_bounds__(1024) void scan_kernel(const int* __restrict__ deg,
                                                    int* __restrict__ offsets,
                                                    int* __restrict__ binoff,
                                                    int* __restrict__ bincur) {
  __shared__ int wsum[16];
  __shared__ int hist[64];
  int t = threadIdx.x;
  int w = t >> 6, lane = t & 63;
  if (t < 64) hist[t] = 0;
  __syncthreads();
  int lo = t * SCAN_CHUNK;
  int hi = min(lo + SCAN_CHUNK, N_NODES);
  int s = 0;
  for (int i = lo; i < hi; ++i) {
    int d = deg[i];
    s += d;
    atomicAdd(&hist[min(d, 63)], 1);
  }
  int incl = s;
#pragma unroll
  for (int o = 1; o < 64; o <<= 1) {
    int v = __shfl_up(incl, o);
    if (lane >= o) incl += v;
  }
  if (lane == 63) wsum[w] = incl;
  __syncthreads();   // orders hist atomics + wsum writes
  if (t == 0) {
    int run = 0;
#pragma unroll
    for (int i = 0; i < 16; ++i) { int v = wsum[i]; wsum[i] = run; run += v; }
    int brun = 0;
#pragma unroll
    for (int i = 0; i < 64; ++i) { int v = hist[i]; binoff[i] = brun; brun += v; }
    binoff[64] = brun;
  }
  if (t < 64) bincur[t] = 0;
  __syncthreads();
  int off = wsum[w] + incl - s;
  for (int i = lo; i < hi; ++i) { offsets[i] = off; off += deg[i]; }
  if (hi == N_NODES && lo < N_NODES) offsets[N_NODES] = off;
}

__global__ void scatter_edges(const int* __restrict__ ei, const int* __restrict__ offsets,
                              int* __restrict__ cursor, int* __restrict__ edge_src) {
  int e = blockIdx.x * blockDim.x + threadIdx.x;
  if (e >= EP) return;
  int src, dst;
  if (e < N_EDGES) { src = ei[e]; dst = ei[N_EDGES + e]; }
  else             { src = dst = e - N_EDGES; }
  int pos = offsets[dst] + atomicAdd(&cursor[dst], 1);
  edge_src[pos] = src;
}

// degree-bucketed node permutation (counting-sort scatter). Order within a bucket is
// nondeterministic but unobservable: per-node math is independent & written per-node.
__global__ void scatter_perm(const int* __restrict__ offsets, const int* __restrict__ binoff,
                             int* __restrict__ bincur, int* __restrict__ perm) {
  int n = blockIdx.x * blockDim.x + threadIdx.x;
  if (n >= N_NODES) return;
  int d = min(offsets[n + 1] - offsets[n], 63);
  int pos = binoff[d] + atomicAdd(&bincur[d], 1);
  perm[pos] = n;
}

// ---------------- GEMM1 (MFMA): h1b = xb @ W1, fused alpha1 logits. BK=64 ----------------
__global__ __launch_bounds__(256) void gemm1_mfma(const unsigned short* __restrict__ xb,
                                                  const unsigned short* __restrict__ wb1t,
                                                  const float* __restrict__ a_src,
                                                  const float* __restrict__ a_dst,
                                                  unsigned short* __restrict__ h1b,
                                                  float* __restrict__ asrc,
                                                  float* __restrict__ adst) {
  __shared__ unsigned short As[128 * 64];
  __shared__ unsigned short Bs[128 * 64];
  int tid = threadIdx.x;
  int w = tid >> 6, lane = tid & 63;
  int bn = blockIdx.x & 3, bm = blockIdx.x >> 2;
  int row0 = bm * 128, col0 = bn * 128;
  int wr = w >> 1, wc = w & 1;
  int cl = lane & 15, hi = lane >> 4;
  f32x4 acc[4][4] = {};
  for (int k0 = 0; k0 < F_IN; k0 += 64) {
#pragma unroll
    for (int c = 0; c < 4; ++c) {
      int slot = c * 256 + tid;
      int r = slot >> 3;
      int q = (slot & 7) ^ (r & 7);
      gload16(xb + (size_t)(row0 + r) * F_IN + k0 + q * 8, (char*)As + (c * 256 + w * 64) * 16);
      gload16(wb1t + (size_t)(col0 + r) * F_IN + k0 + q * 8, (char*)Bs + (c * 256 + w * 64) * 16);
    }
    __syncthreads();
#pragma unroll
    for (int kk = 0; kk < 2; ++kk) {
      bf16x8 a[4], b[4];
#pragma unroll
      for (int m = 0; m < 4; ++m) {
        int r = wr * 64 + m * 16 + cl;
        a[m] = *(const bf16x8*)&As[r * 64 + ((((kk * 4 + hi)) ^ (r & 7)) << 3)];
      }
#pragma unroll
      for (int n = 0; n < 4; ++n) {
        int r = wc * 64 + n * 16 + cl;
        b[n] = *(const bf16x8*)&Bs[r * 64 + ((((kk * 4 + hi)) ^ (r & 7)) << 3)];
      }
#pragma unroll
      for (int m = 0; m < 4; ++m)
#pragma unroll
        for (int n = 0; n < 4; ++n)
          acc[m][n] = __builtin_amdgcn_mfma_f32_16x16x32_bf16(a[m], b[n], acc[m][n], 0, 0, 0);
    }
    __syncthreads();
  }
  int head = bn * 2 + wc;
  float asv[4], adv[4];
#pragma unroll
  for (int n = 0; n < 4; ++n) {
    asv[n] = a_src[head * 64 + n * 16 + cl];
    adv[n] = a_dst[head * 64 + n * 16 + cl];
  }
#pragma unroll
  for (int m = 0; m < 4; ++m) {
#pragma unroll
    for (int r = 0; r < 4; ++r) {
      int grow = row0 + wr * 64 + m * 16 + hi * 4 + r;
      float ps = acc[m][0][r] * asv[0] + acc[m][1][r] * asv[1] +
                 acc[m][2][r] * asv[2] + acc[m][3][r] * asv[3];
      float pd = acc[m][0][r] * adv[0] + acc[m][1][r] * adv[1] +
                 acc[m][2][r] * adv[2] + acc[m][3][r] * adv[3];
#pragma unroll
      for (int o = 8; o > 0; o >>= 1) { ps += __shfl_xor(ps, o); pd += __shfl_xor(pd, o); }
      if (grow < N_NODES) {
#pragma unroll
        for (int n = 0; n < 4; ++n)
          h1b[(size_t)grow * D1 + col0 + wc * 64 + n * 16 + cl] = f2bf(acc[m][n][r]);
        if (cl == 0) { asrc[grow * H1 + head] = ps; adst[grow * H1 + head] = pd; }
      }
    }
  }
}

// ---------------- alpha1: node-parallel softmax -> unnormalized alpha (head-major) + inv ----------------
__global__ __launch_bounds__(256) void alpha1_kernel(const int* __restrict__ offsets,
                                                     const int* __restrict__ edge_src,
                                                     const float* __restrict__ asrc,
                                                     const float* __restrict__ adst,
                                                     float* __restrict__ alphaE,
                                                     float* __restrict__ inv1) {
  int w = threadIdx.x >> 6, lane = threadIdx.x & 63;
  int n = blockIdx.x * 4 + w;
  int base = offsets[n];
  int deg = offsets[n + 1] - base;
  int h = lane & 7, et = lane >> 3;
  float adv = adst[n * H1 + h];
  float evr[8];
  float m = -INFINITY;
#pragma unroll
  for (int k = 0; k < 8; ++k) {
    int e = et + k * 8;
    float ev = -INFINITY;
    if (e < deg) ev = lrelu(asrc[edge_src[base + e] * H1 + h] + adv);
    evr[k] = ev;
    m = fmaxf(m, ev);
  }
  for (int e = et + 64; e < deg; e += 8)   // guard, never runs for this graph
    m = fmaxf(m, lrelu(asrc[edge_src[base + e] * H1 + h] + adv));
  m = fmaxf(m, __shfl_xor(m, 8));
  m = fmaxf(m, __shfl_xor(m, 16));
  m = fmaxf(m, __shfl_xor(m, 32));
  float ss = 0.f;
#pragma unroll
  for (int k = 0; k < 8; ++k) {
    int e = et + k * 8;
    if (e < deg) {
      float a = __expf(evr[k] - m);
      alphaE[(size_t)h * EP + base + e] = a;
      ss += a;
    }
  }
  for (int e = et + 64; e < deg; e += 8) { // guard
    float a = __expf(lrelu(asrc[edge_src[base + e] * H1 + h] + adv) - m);
    alphaE[(size_t)h * EP + base + e] = a;
    ss += a;
  }
  ss += __shfl_xor(ss, 8);
  ss += __shfl_xor(ss, 16);
  ss += __shfl_xor(ss, 32);
  if (et == 0) inv1[n * H1 + h] = 1.f / (ss + 1e-16f);
}

// ---------------- agg1 gather: head-sliced XCD-affine, degree-bucketed, unroll x4 ----------------
// bid&7 = head (round-robin block->XCD => per-XCD h1b re-read set = 2.56MB < 4MB L2).
// wave = 8 nodes x 1 head; nodes come from the degree-sorted perm so the 8 nodes in a
// wave have (near-)equal degree -> minimal exec-mask waste in the edge loop.
__global__ __launch_bounds__(256) void agg1_gather(const int* __restrict__ offsets,
                                                   const int* __restrict__ edge_src,
                                                   const int* __restrict__ perm,
                                                   const float* __restrict__ alphaE,
                                                   const float* __restrict__ inv1,
                                                   const unsigned short* __restrict__ h1b,
                                                   const float* __restrict__ b1,
                                                   unsigned short* __restrict__ out1b) {
  int w = threadIdx.x >> 6, lane = threadIdx.x & 63;
  int bid = blockIdx.x;
  int head = bid & 7;
  int ng = bid >> 3;
  int sub = lane >> 3, cl = lane & 7;
  int n = perm[ng * 32 + w * 8 + sub];
  int base = offsets[n];
  int deg = offsets[n + 1] - base;
  const float* aE = alphaE + (size_t)head * EP + base;
  const int* es = edge_src + base;
  const char* hb = (const char*)h1b + head * 128 + cl * 16;
  float acc[8] = {};
  int e = 0;
  for (; e + 3 < deg; e += 4) {
    float a0 = aE[e], a1 = aE[e + 1], a2 = aE[e + 2], a3 = aE[e + 3];
    int s0 = es[e], s1 = es[e + 1], s2 = es[e + 2], s3 = es[e + 3];
    uint4 u0 = *(const uint4*)(hb + ((size_t)s0 << 10));
    uint4 u1 = *(const uint4*)(hb + ((size_t)s1 << 10));
    uint4 u2 = *(const uint4*)(hb + ((size_t)s2 << 10));
    uint4 u3 = *(const uint4*)(hb + ((size_t)s3 << 10));
#pragma unroll
    for (int j = 0; j < 4; ++j) {
      unsigned int x0 = ((const unsigned int*)&u0)[j];
      unsigned int x1 = ((const unsigned int*)&u1)[j];
      unsigned int x2 = ((const unsigned int*)&u2)[j];
      unsigned int x3 = ((const unsigned int*)&u3)[j];
      acc[2 * j]     += a0 * asf(x0 << 16) + a1 * asf(x1 << 16)
                      + a2 * asf(x2 << 16) + a3 * asf(x3 << 16);
      acc[2 * j + 1] += a0 * asf(x0 & 0xffff0000u) + a1 * asf(x1 & 0xffff0000u)
                      + a2 * asf(x2 & 0xffff0000u) + a3 * asf(x3 & 0xffff0000u);
    }
  }
  if (e + 1 < deg) {           // x2 tail
    float a0 = aE[e], a1 = aE[e + 1];
    int s0 = es[e], s1 = es[e + 1];
    uint4 u0 = *(const uint4*)(hb + ((size_t)s0 << 10));
    uint4 u1 = *(const uint4*)(hb + ((size_t)s1 << 10));
#pragma unroll
    for (int j = 0; j < 4; ++j) {
      unsigned int x0 = ((const unsigned int*)&u0)[j];
      unsigned int x1 = ((const unsigned int*)&u1)[j];
      acc[2 * j]     += a0 * asf(x0 << 16) + a1 * asf(x1 << 16);
      acc[2 * j + 1] += a0 * asf(x0 & 0xffff0000u) + a1 * asf(x1 & 0xffff0000u);
    }
    e += 2;
  }
  if (e < deg) {               // x1 tail
    float a = aE[e];
    int s = es[e];
    uint4 uv = *(const uint4*)(hb + ((size_t)s << 10));
#pragma unroll
    for (int j = 0; j < 4; ++j) {
      unsigned int u = ((const unsigned int*)&uv)[j];
      acc[2 * j]     += a * asf(u << 16);
      acc[2 * j + 1] += a * asf(u & 0xffff0000u);
    }
  }
  float inv = inv1[n * H1 + head];
  int c0 = head * NHID + cl * 8;
  float4 b0 = *(const float4*)&b1[c0];
  float4 b4 = *(const float4*)&b1[c0 + 4];
  float v[8];
  v[0] = acc[0] * inv + b0.x; v[1] = acc[1] * inv + b0.y;
  v[2] = acc[2] * inv + b0.z; v[3] = acc[3] * inv + b0.w;
  v[4] = acc[4] * inv + b4.x; v[5] = acc[5] * inv + b4.y;
  v[6] = acc[6] * inv + b4.z; v[7] = acc[7] * inv + b4.w;
#pragma unroll
  for (int j = 0; j < 8; ++j) v[j] = v[j] > 0.f ? v[j] : (__expf(v[j]) - 1.f);  // ELU
  ushort4 o0 = make_ushort4(f2bf(v[0]), f2bf(v[1]), f2bf(v[2]), f2bf(v[3]));
  ushort4 o1 = make_ushort4(f2bf(v[4]), f2bf(v[5]), f2bf(v[6]), f2bf(v[7]));
  *(ushort4*)&out1b[(size_t)n * D1 + c0] = o0;
  *(ushort4*)&out1b[(size_t)n * D1 + c0 + 4] = o1;
}

// ---------------- GEMM2 (MFMA): h2(f32) = out1b @ W2 (+pad), fused alpha2 ----------------
__global__ __launch_bounds__(256) void gemm2_mfma(const unsigned short* __restrict__ ab,
                                                  const unsigned short* __restrict__ wb2t,
                                                  const float* __restrict__ a_src2,
                                                  const float* __restrict__ a_dst2,
                                                  float* __restrict__ h2,
                                                  float* __restrict__ asrc,
                                                  float* __restrict__ adst) {
  __shared__ unsigned short As[64 * 64];
  __shared__ unsigned short Bs[48 * 64];
  int tid = threadIdx.x;
  int w = tid >> 6, lane = tid & 63;
  int row0 = blockIdx.x * 64;
  int cl = lane & 15, hi = lane >> 4;
  f32x4 acc[3] = {};
  for (int k0 = 0; k0 < D1; k0 += 64) {
#pragma unroll
    for (int c = 0; c < 2; ++c) {
      int slot = c * 256 + tid;
      int r = slot >> 3;
      int q = (slot & 7) ^ (r & 7);
      gload16(ab + (size_t)(row0 + r) * D1 + k0 + q * 8, (char*)As + (c * 256 + w * 64) * 16);
    }
    {
      int r = tid >> 3;
      int q = (tid & 7) ^ (r & 7);
      gload16(wb2t + (size_t)r * D1 + k0 + q * 8, (char*)Bs + (w * 64) * 16);
      if (tid < 128) {
        int slot2 = 256 + tid;
        int r2 = slot2 >> 3;
        int q2 = (slot2 & 7) ^ (r2 & 7);
        gload16(wb2t + (size_t)r2 * D1 + k0 + q2 * 8, (char*)Bs + ((256 + w * 64)) * 16);
      }
    }
    __syncthreads();
#pragma unroll
    for (int kk = 0; kk < 2; ++kk) {
      int ra = w * 16 + cl;
      bf16x8 a = *(const bf16x8*)&As[ra * 64 + (((kk * 4 + hi) ^ (ra & 7)) << 3)];
#pragma unroll
      for (int n = 0; n < 3; ++n) {
        int rb = n * 16 + cl;
        bf16x8 b = *(const bf16x8*)&Bs[rb * 64 + (((kk * 4 + hi) ^ (rb & 7)) << 3)];
        acc[n] = __builtin_amdgcn_mfma_f32_16x16x32_bf16(a, b, acc[n], 0, 0, 0);
      }
    }
    __syncthreads();
  }
  float asv[3], adv[3];
#pragma unroll
  for (int n = 0; n < 3; ++n) {
    int c = n * 16 + cl;
    asv[n] = (c < NCLS) ? a_src2[c] : 0.f;
    adv[n] = (c < NCLS) ? a_dst2[c] : 0.f;
  }
#pragma unroll
  for (int r = 0; r < 4; ++r) {
    int grow = row0 + w * 16 + hi * 4 + r;
    float ps = acc[0][r] * asv[0] + acc[1][r] * asv[1] + acc[2][r] * asv[2];
    float pd = acc[0][r] * adv[0] + acc[1][r] * adv[1] + acc[2][r] * adv[2];
#pragma unroll
    for (int o = 8; o > 0; o >>= 1) { ps += __shfl_xor(ps, o); pd += __shfl_xor(pd, o); }
    if (grow < N_NODES) {
#pragma unroll
      for (int n = 0; n < 3; ++n) {
        int c = n * 16 + cl;
        if (c < NCLS) h2[(size_t)grow * NCLS + c] = acc[n][r];
      }
      if (cl == 0) { asrc[grow] = ps; adst[grow] = pd; }
    }
  }
}

// ---------------- agg2: LDS alpha + f32x2 gather (6 edges/iter) + b2 + log_softmax ----------------
__global__ __launch_bounds__(256) void agg2_kernel(const int* __restrict__ offsets,
                                                   const int* __restrict__ edge_src,
                                                   const float* __restrict__ asrc,
                                                   const float* __restrict__ adst,
                                                   const float* __restrict__ h2,
                                                   const float* __restrict__ b2,
                                                   float* __restrict__ out) {
  __shared__ float lalpha[4][MAXD + 8];
  __shared__ int   lsoff[4][MAXD + 8];
  int w = threadIdx.x >> 6;
  int lane = threadIdx.x & 63;
  int n = blockIdx.x * 4 + w;
  int base = offsets[n];
  int deg = offsets[n + 1] - base;
  int degc = min(deg, MAXD);
  int degp = ((degc + 5) / 6) * 6;

  float advv = adst[n];
  float m = -INFINITY;
  for (int e = lane; e < deg; e += 64) {
    int s = edge_src[base + e];
    float ev = lrelu(asrc[s] + advv);
    if (e < MAXD) { lsoff[w][e] = s * (NCLS * 4); lalpha[w][e] = ev; }
    m = fmaxf(m, ev);
  }
  m = wave_max(m);
  float ssum = 0.f;
  for (int e = lane; e < deg; e += 64) {
    float ev;
    if (e < MAXD) ev = lalpha[w][e];
    else { int s = edge_src[base + e]; ev = lrelu(asrc[s] + advv); }
    ssum += __expf(ev - m);
  }
  float inv = 1.f / (wave_sum(ssum) + 1e-16f);
  for (int e = lane; e < degc; e += 64) lalpha[w][e] = __expf(lalpha[w][e] - m) * inv;
  {
    int e = degc + lane;
    if (e < degp) { lalpha[w][e] = 0.f; lsoff[w][e] = 0; }
  }
  __builtin_amdgcn_wave_barrier();

  int esub = lane / 20;
  int cg = lane - esub * 20;
  bool act = esub < 3;
  float ax = 0.f, ay = 0.f;
  const char* hb = (const char*)h2 + cg * 8;
  for (int i = 0; i < degp; i += 6) {
    if (act) {
      int sA = i + esub, sB = i + 3 + esub;
      float aA = lalpha[w][sA], aB = lalpha[w][sB];
      int oA = lsoff[w][sA], oB = lsoff[w][sB];
      float2 hA = *(const float2*)(hb + oA);
      float2 hB = *(const float2*)(hb + oB);
      ax += aA * hA.x + aB * hB.x;
      ay += aA * hA.y + aB * hB.y;
    }
  }
  for (int e = MAXD + esub; e < deg; e += 3) {   // guard, never runs
    if (act) {
      int s = edge_src[base + e];
      float a = __expf(lrelu(asrc[s] + advv) - m) * inv;
      float2 hv = *(const float2*)(hb + (size_t)s * (NCLS * 4));
      ax += a * hv.x; ay += a * hv.y;
    }
  }
  float ax1 = __shfl(ax, lane + 20), ax2 = __shfl(ax, lane + 40);
  float ay1 = __shfl(ay, lane + 20), ay2 = __shfl(ay, lane + 40);
  float v0 = -INFINITY, v1 = -INFINITY;
  if (lane < 20) {
    v0 = ax + ax1 + ax2 + b2[2 * cg];
    v1 = ay + ay1 + ay2 + b2[2 * cg + 1];
  }
  float m2 = wave_max(fmaxf(v0, v1));
  float se = wave_sum(lane < 20 ? __expf(v0 - m2) + __expf(v1 - m2) : 0.f);
  if (lane < 20) {
    float ls = logf(se);
    *(float2*)&out[(size_t)n * NCLS + 2 * cg] = make_float2(v0 - m2 - ls, v1 - m2 - ls);
  }
}

extern "C" void kernel_launch(void* const* d_in, const int* in_sizes, int n_in,
                              void* d_out, int out_size, void* d_ws, size_t ws_size,
                              hipStream_t stream) {
  const float* x   = (const float*)d_in[0];
  const int*   ei  = (const int*)d_in[1];
  const float* W1  = (const float*)d_in[2];
  const float* as1 = (const float*)d_in[3];
  const float* ad1 = (const float*)d_in[4];
  const float* b1  = (const float*)d_in[5];
  const float* W2  = (const float*)d_in[6];
  const float* as2 = (const float*)d_in[7];
  const float* ad2 = (const float*)d_in[8];
  const float* b2  = (const float*)d_in[9];
  float* out = (float*)d_out;

  char* ws = (char*)d_ws;
  size_t off = 0;
  auto alloc = [&](size_t bytes) -> char* {
    char* p = ws + off;
    off += (bytes + 255) & ~(size_t)255;
    return p;
  };
  int* deg      = (int*)alloc((size_t)N_NODES * 4);
  int* cursor   = (int*)alloc((size_t)N_NODES * 4);
  int* offsets  = (int*)alloc((size_t)(N_NODES + 1) * 4);
  int* edge_src = (int*)alloc((size_t)EP * 4);
  int* binoff   = (int*)alloc(65 * 4);
  int* bincur   = (int*)alloc(64 * 4);
  int* perm     = (int*)alloc((size_t)N_NODES * 4);
  unsigned short* xb    = (unsigned short*)alloc((size_t)MPAD * F_IN * 2);
  unsigned short* wb1t  = (unsigned short*)alloc((size_t)D1 * F_IN * 2);
  unsigned short* wb2t  = (unsigned short*)alloc((size_t)48 * D1 * 2);
  unsigned short* h1b   = (unsigned short*)alloc((size_t)N_NODES * D1 * 2);
  unsigned short* out1b = (unsigned short*)alloc((size_t)MPAD * D1 * 2);
  float* asrc1  = (float*)alloc((size_t)N_NODES * H1 * 4);
  float* adst1  = (float*)alloc((size_t)N_NODES * H1 * 4);
  float* alphaE = (float*)alloc((size_t)H1 * EP * 4);
  float* inv1   = (float*)alloc((size_t)N_NODES * H1 * 4);
  float* h2     = (float*)alloc((size_t)N_NODES * NCLS * 4);
  float* asrc2  = (float*)alloc((size_t)N_NODES * 4);
  float* adst2  = (float*)alloc((size_t)N_NODES * 4);

  prep_kernel<<<PB_PAD, 256, 0, stream>>>(x, W1, W2, xb, wb1t, wb2t, deg, cursor, out1b);
  count_deg<<<(EP + 255) / 256, 256, 0, stream>>>(ei, deg);
  scan_kernel<<<1, SCAN_T, 0, stream>>>(deg, offsets, binoff, bincur);
  scatter_edges<<<(EP + 255) / 256, 256, 0, stream>>>(ei, offsets, cursor, edge_src);
  scatter_perm<<<(N_NODES + 255) / 256, 256, 0, stream>>>(offsets, binoff, bincur, perm);

  gemm1_mfma<<<157 * 4, 256, 0, stream>>>(xb, wb1t, as1, ad1, h1b, asrc1, adst1);
  alpha1_kernel<<<N_NODES / 4, 256, 0, stream>>>(offsets, edge_src, asrc1, adst1, alphaE, inv1);
  agg1_gather<<<(N_NODES / 32) * 8, 256, 0, stream>>>(offsets, edge_src, perm, alphaE, inv1, h1b, b1, out1b);

  gemm2_mfma<<<MPAD / 64, 256, 0, stream>>>(out1b, wb2t, as2, ad2, h2, asrc2, adst2);
  agg2_kernel<<<N_NODES / 4, 256, 0, stream>>>(offsets, edge_src, asrc2, adst2, h2, b2, out);
}

// Round 15
// 165.086 us; speedup vs baseline: 1.3155x; 1.3155x over previous
//
#include <hip/hip_runtime.h>
#include <hip/hip_bf16.h>
#include <math.h>

#define N_NODES 20000
#define MPAD 20096               // 157*128
#define N_EDGES 320000
#define EP (N_EDGES + N_NODES)   // 340000
#define F_IN 256
#define NHID 64
#define H1 8
#define D1 512
#define NCLS 40
#define NEG_SLOPE 0.2f
#define MAXD 128

typedef __attribute__((ext_vector_type(8))) short bf16x8;
typedef __attribute__((ext_vector_type(4))) float f32x4;

__device__ __forceinline__ float wave_max(float v) {
#pragma unroll
  for (int o = 32; o > 0; o >>= 1) v = fmaxf(v, __shfl_xor(v, o));
  return v;
}
__device__ __forceinline__ float wave_sum(float v) {
#pragma unroll
  for (int o = 32; o > 0; o >>= 1) v += __shfl_xor(v, o);
  return v;
}
__device__ __forceinline__ unsigned short f2bf(float f) {
  union { float f; unsigned int i; } c; c.f = f;
  unsigned int x = c.i;
  return (unsigned short)((x + 0x7fffu + ((x >> 16) & 1u)) >> 16);  // RNE
}
__device__ __forceinline__ float asf(unsigned int u) {
  union { unsigned int i; float f; } c; c.i = u; return c.f;
}
__device__ __forceinline__ float lrelu(float x) { return x > 0.f ? x : NEG_SLOPE * x; }

__device__ __forceinline__ void gload16(const void* g, void* l) {
  __builtin_amdgcn_global_load_lds((const __attribute__((address_space(1))) void*)g,
                                   (__attribute__((address_space(3))) void*)l, 16, 0, 0);
}

// ---------------- fused prep ----------------
#define PB_CONV 2512             // MPAD*F_IN/8/256
#define PB_TW1  (PB_CONV + 32)
#define PB_TW2  (PB_TW1 + 96)
#define PB_ZERO (PB_TW2 + 157)
#define PB_PAD  (PB_ZERO + 24)
__global__ __launch_bounds__(256) void prep_kernel(const float* __restrict__ x,
                                                   const float* __restrict__ W1,
                                                   const float* __restrict__ W2,
                                                   unsigned short* __restrict__ xb,
                                                   unsigned short* __restrict__ wb1t,
                                                   unsigned short* __restrict__ wb2t,
                                                   int* __restrict__ deg,
                                                   int* __restrict__ cursor,
                                                   unsigned short* __restrict__ out1b) {
  __shared__ float tsh[64][65];
  int bid = blockIdx.x;
  int t = threadIdx.x;
  if (bid < PB_CONV) {
    size_t base = ((size_t)bid * 256 + t) * 8;
    int row = (int)(base >> 8);
    ushort4 o0, o1;
    if (row < N_NODES) {
      float4 v0 = *(const float4*)&x[base];
      float4 v1 = *(const float4*)&x[base + 4];
      o0 = make_ushort4(f2bf(v0.x), f2bf(v0.y), f2bf(v0.z), f2bf(v0.w));
      o1 = make_ushort4(f2bf(v1.x), f2bf(v1.y), f2bf(v1.z), f2bf(v1.w));
    } else {
      o0 = make_ushort4(0, 0, 0, 0); o1 = o0;
    }
    *(ushort4*)&xb[base] = o0;
    *(ushort4*)&xb[base + 4] = o1;
  } else if (bid < PB_TW1) {
    int b2 = bid - PB_CONV;
    int bk = b2 & 3, bn = b2 >> 2;
    int tr = t >> 4, tc4 = (t & 15) * 4;
#pragma unroll
    for (int i = 0; i < 4; ++i) {
      int k = i * 16 + tr;
      float4 v = *(const float4*)&W1[(size_t)(bk * 64 + k) * D1 + bn * 64 + tc4];
      tsh[k][tc4] = v.x; tsh[k][tc4 + 1] = v.y; tsh[k][tc4 + 2] = v.z; tsh[k][tc4 + 3] = v.w;
    }
    __syncthreads();
#pragma unroll
    for (int i = 0; i < 4; ++i) {
      int n = i * 16 + tr;
      ushort4 o = make_ushort4(f2bf(tsh[tc4][n]), f2bf(tsh[tc4 + 1][n]),
                               f2bf(tsh[tc4 + 2][n]), f2bf(tsh[tc4 + 3][n]));
      *(ushort4*)&wb1t[(size_t)(bn * 64 + n) * F_IN + bk * 64 + tc4] = o;
    }
  } else if (bid < PB_TW2) {
    int idx = (bid - PB_TW1) * 256 + t;
    int c = idx >> 9, k = idx & 511;
    wb2t[idx] = f2bf((c < NCLS) ? W2[(size_t)k * NCLS + c] : 0.f);
  } else if (bid < PB_ZERO) {
    int idx = (bid - PB_TW2) * 256 + t;
    if (idx < N_NODES) deg[idx] = 0;
    else if (idx < 2 * N_NODES) cursor[idx - N_NODES] = 0;
  } else {
    int idx = (bid - PB_ZERO) * 256 + t;
    uint4 z = make_uint4(0, 0, 0, 0);
    *(uint4*)((char*)out1b + (size_t)N_NODES * D1 * 2 + (size_t)idx * 16) = z;
  }
}

// ---------------- CSR build ----------------
__global__ void count_deg(const int* __restrict__ ei, int* __restrict__ deg) {
  int e = blockIdx.x * blockDim.x + threadIdx.x;
  if (e >= EP) return;
  int dst = (e < N_EDGES) ? ei[N_EDGES + e] : (e - N_EDGES);
  atomicAdd(&deg[dst], 1);
}

#define SCAN_T 1024
#define SCAN_CHUNK 20
// offsets scan + fused degree-bucketed node permutation (LDS histogram + LDS atomics)
__global__ __launch_bounds__(1024) void scan_kernel(const int* __restrict__ deg,
                                                    int* __restrict__ offsets,
                                                    int* __restrict__ perm) {
  __shared__ int wsum[16];
  __shared__ int hist[64];   // becomes binoff after t0 scan
  __shared__ int bcur[64];
  int t = threadIdx.x;
  int w = t >> 6, lane = t & 63;
  if (t < 64) { hist[t] = 0; bcur[t] = 0; }
  __syncthreads();
  int lo = t * SCAN_CHUNK;
  int hi = min(lo + SCAN_CHUNK, N_NODES);
  int s = 0;
  for (int i = lo; i < hi; ++i) {
    int d = deg[i];
    s += d;
    atomicAdd(&hist[min(d, 63)], 1);
  }
  int incl = s;
#pragma unroll
  for (int o = 1; o < 64; o <<= 1) {
    int v = __shfl_up(incl, o);
    if (lane >= o) incl += v;
  }
  if (lane == 63) wsum[w] = incl;
  __syncthreads();   // orders hist atomics + wsum writes
  if (t == 0) {
    int run = 0;
#pragma unroll
    for (int i = 0; i < 16; ++i) { int v = wsum[i]; wsum[i] = run; run += v; }
    int brun = 0;
#pragma unroll
    for (int i = 0; i < 64; ++i) { int v = hist[i]; hist[i] = brun; brun += v; }
  }
  __syncthreads();
  int off = wsum[w] + incl - s;
  for (int i = lo; i < hi; ++i) {
    int d = deg[i];
    offsets[i] = off; off += d;
    int b = min(d, 63);
    int pos = hist[b] + atomicAdd(&bcur[b], 1);   // LDS atomic: cheap
    perm[pos] = i;
  }
  if (hi == N_NODES && lo < N_NODES) offsets[N_NODES] = off;
}

__global__ void scatter_edges(const int* __restrict__ ei, const int* __restrict__ offsets,
                              int* __restrict__ cursor, int* __restrict__ edge_src) {
  int e = blockIdx.x * blockDim.x + threadIdx.x;
  if (e >= EP) return;
  int src, dst;
  if (e < N_EDGES) { src = ei[e]; dst = ei[N_EDGES + e]; }
  else             { src = dst = e - N_EDGES; }
  int pos = offsets[dst] + atomicAdd(&cursor[dst], 1);
  edge_src[pos] = src;
}

// ---------------- GEMM1 (MFMA): h1b = xb @ W1, fused alpha1 logits. BK=64 ----------------
__global__ __launch_bounds__(256) void gemm1_mfma(const unsigned short* __restrict__ xb,
                                                  const unsigned short* __restrict__ wb1t,
                                                  const float* __restrict__ a_src,
                                                  const float* __restrict__ a_dst,
                                                  unsigned short* __restrict__ h1b,
                                                  float* __restrict__ asrc,
                                                  float* __restrict__ adst) {
  __shared__ unsigned short As[128 * 64];
  __shared__ unsigned short Bs[128 * 64];
  int tid = threadIdx.x;
  int w = tid >> 6, lane = tid & 63;
  int bn = blockIdx.x & 3, bm = blockIdx.x >> 2;
  int row0 = bm * 128, col0 = bn * 128;
  int wr = w >> 1, wc = w & 1;
  int cl = lane & 15, hi = lane >> 4;
  f32x4 acc[4][4] = {};
  for (int k0 = 0; k0 < F_IN; k0 += 64) {
#pragma unroll
    for (int c = 0; c < 4; ++c) {
      int slot = c * 256 + tid;
      int r = slot >> 3;
      int q = (slot & 7) ^ (r & 7);
      gload16(xb + (size_t)(row0 + r) * F_IN + k0 + q * 8, (char*)As + (c * 256 + w * 64) * 16);
      gload16(wb1t + (size_t)(col0 + r) * F_IN + k0 + q * 8, (char*)Bs + (c * 256 + w * 64) * 16);
    }
    __syncthreads();
#pragma unroll
    for (int kk = 0; kk < 2; ++kk) {
      bf16x8 a[4], b[4];
#pragma unroll
      for (int m = 0; m < 4; ++m) {
        int r = wr * 64 + m * 16 + cl;
        a[m] = *(const bf16x8*)&As[r * 64 + ((((kk * 4 + hi)) ^ (r & 7)) << 3)];
      }
#pragma unroll
      for (int n = 0; n < 4; ++n) {
        int r = wc * 64 + n * 16 + cl;
        b[n] = *(const bf16x8*)&Bs[r * 64 + ((((kk * 4 + hi)) ^ (r & 7)) << 3)];
      }
#pragma unroll
      for (int m = 0; m < 4; ++m)
#pragma unroll
        for (int n = 0; n < 4; ++n)
          acc[m][n] = __builtin_amdgcn_mfma_f32_16x16x32_bf16(a[m], b[n], acc[m][n], 0, 0, 0);
    }
    __syncthreads();
  }
  int head = bn * 2 + wc;
  float asv[4], adv[4];
#pragma unroll
  for (int n = 0; n < 4; ++n) {
    asv[n] = a_src[head * 64 + n * 16 + cl];
    adv[n] = a_dst[head * 64 + n * 16 + cl];
  }
#pragma unroll
  for (int m = 0; m < 4; ++m) {
#pragma unroll
    for (int r = 0; r < 4; ++r) {
      int grow = row0 + wr * 64 + m * 16 + hi * 4 + r;
      float ps = acc[m][0][r] * asv[0] + acc[m][1][r] * asv[1] +
                 acc[m][2][r] * asv[2] + acc[m][3][r] * asv[3];
      float pd = acc[m][0][r] * adv[0] + acc[m][1][r] * adv[1] +
                 acc[m][2][r] * adv[2] + acc[m][3][r] * adv[3];
#pragma unroll
      for (int o = 8; o > 0; o >>= 1) { ps += __shfl_xor(ps, o); pd += __shfl_xor(pd, o); }
      if (grow < N_NODES) {
#pragma unroll
        for (int n = 0; n < 4; ++n)
          h1b[(size_t)grow * D1 + col0 + wc * 64 + n * 16 + cl] = f2bf(acc[m][n][r]);
        if (cl == 0) { asrc[grow * H1 + head] = ps; adst[grow * H1 + head] = pd; }
      }
    }
  }
}

// ---------------- alpha1: node-parallel softmax -> unnormalized alpha (head-major) + inv ----------------
__global__ __launch_bounds__(256) void alpha1_kernel(const int* __restrict__ offsets,
                                                     const int* __restrict__ edge_src,
                                                     const float* __restrict__ asrc,
                                                     const float* __restrict__ adst,
                                                     float* __restrict__ alphaE,
                                                     float* __restrict__ inv1) {
  int w = threadIdx.x >> 6, lane = threadIdx.x & 63;
  int n = blockIdx.x * 4 + w;
  int base = offsets[n];
  int deg = offsets[n + 1] - base;
  int h = lane & 7, et = lane >> 3;
  float adv = adst[n * H1 + h];
  float evr[8];
  float m = -INFINITY;
#pragma unroll
  for (int k = 0; k < 8; ++k) {
    int e = et + k * 8;
    float ev = -INFINITY;
    if (e < deg) ev = lrelu(asrc[edge_src[base + e] * H1 + h] + adv);
    evr[k] = ev;
    m = fmaxf(m, ev);
  }
  for (int e = et + 64; e < deg; e += 8)   // guard, never runs for this graph
    m = fmaxf(m, lrelu(asrc[edge_src[base + e] * H1 + h] + adv));
  m = fmaxf(m, __shfl_xor(m, 8));
  m = fmaxf(m, __shfl_xor(m, 16));
  m = fmaxf(m, __shfl_xor(m, 32));
  float ss = 0.f;
#pragma unroll
  for (int k = 0; k < 8; ++k) {
    int e = et + k * 8;
    if (e < deg) {
      float a = __expf(evr[k] - m);
      alphaE[(size_t)h * EP + base + e] = a;
      ss += a;
    }
  }
  for (int e = et + 64; e < deg; e += 8) { // guard
    float a = __expf(lrelu(asrc[edge_src[base + e] * H1 + h] + adv) - m);
    alphaE[(size_t)h * EP + base + e] = a;
    ss += a;
  }
  ss += __shfl_xor(ss, 8);
  ss += __shfl_xor(ss, 16);
  ss += __shfl_xor(ss, 32);
  if (et == 0) inv1[n * H1 + h] = 1.f / (ss + 1e-16f);
}

// ---------------- agg1 gather: head-sliced XCD-affine, degree-bucketed, unroll x4 ----------------
__global__ __launch_bounds__(256) void agg1_gather(const int* __restrict__ offsets,
                                                   const int* __restrict__ edge_src,
                                                   const int* __restrict__ perm,
                                                   const float* __restrict__ alphaE,
                                                   const float* __restrict__ inv1,
                                                   const unsigned short* __restrict__ h1b,
                                                   const float* __restrict__ b1,
                                                   unsigned short* __restrict__ out1b) {
  int w = threadIdx.x >> 6, lane = threadIdx.x & 63;
  int bid = blockIdx.x;
  int head = bid & 7;
  int ng = bid >> 3;
  int sub = lane >> 3, cl = lane & 7;
  int n = perm[ng * 32 + w * 8 + sub];
  int base = offsets[n];
  int deg = offsets[n + 1] - base;
  const float* aE = alphaE + (size_t)head * EP + base;
  const int* es = edge_src + base;
  const char* hb = (const char*)h1b + head * 128 + cl * 16;
  float acc[8] = {};
  int e = 0;
  for (; e + 3 < deg; e += 4) {
    float a0 = aE[e], a1 = aE[e + 1], a2 = aE[e + 2], a3 = aE[e + 3];
    int s0 = es[e], s1 = es[e + 1], s2 = es[e + 2], s3 = es[e + 3];
    uint4 u0 = *(const uint4*)(hb + ((size_t)s0 << 10));
    uint4 u1 = *(const uint4*)(hb + ((size_t)s1 << 10));
    uint4 u2 = *(const uint4*)(hb + ((size_t)s2 << 10));
    uint4 u3 = *(const uint4*)(hb + ((size_t)s3 << 10));
#pragma unroll
    for (int j = 0; j < 4; ++j) {
      unsigned int x0 = ((const unsigned int*)&u0)[j];
      unsigned int x1 = ((const unsigned int*)&u1)[j];
      unsigned int x2 = ((const unsigned int*)&u2)[j];
      unsigned int x3 = ((const unsigned int*)&u3)[j];
      acc[2 * j]     += a0 * asf(x0 << 16) + a1 * asf(x1 << 16)
                      + a2 * asf(x2 << 16) + a3 * asf(x3 << 16);
      acc[2 * j + 1] += a0 * asf(x0 & 0xffff0000u) + a1 * asf(x1 & 0xffff0000u)
                      + a2 * asf(x2 & 0xffff0000u) + a3 * asf(x3 & 0xffff0000u);
    }
  }
  if (e + 1 < deg) {           // x2 tail
    float a0 = aE[e], a1 = aE[e + 1];
    int s0 = es[e], s1 = es[e + 1];
    uint4 u0 = *(const uint4*)(hb + ((size_t)s0 << 10));
    uint4 u1 = *(const uint4*)(hb + ((size_t)s1 << 10));
#pragma unroll
    for (int j = 0; j < 4; ++j) {
      unsigned int x0 = ((const unsigned int*)&u0)[j];
      unsigned int x1 = ((const unsigned int*)&u1)[j];
      acc[2 * j]     += a0 * asf(x0 << 16) + a1 * asf(x1 << 16);
      acc[2 * j + 1] += a0 * asf(x0 & 0xffff0000u) + a1 * asf(x1 & 0xffff0000u);
    }
    e += 2;
  }
  if (e < deg) {               // x1 tail
    float a = aE[e];
    int s = es[e];
    uint4 uv = *(const uint4*)(hb + ((size_t)s << 10));
#pragma unroll
    for (int j = 0; j < 4; ++j) {
      unsigned int u = ((const unsigned int*)&uv)[j];
      acc[2 * j]     += a * asf(u << 16);
      acc[2 * j + 1] += a * asf(u & 0xffff0000u);
    }
  }
  float inv = inv1[n * H1 + head];
  int c0 = head * NHID + cl * 8;
  float4 b0 = *(const float4*)&b1[c0];
  float4 b4 = *(const float4*)&b1[c0 + 4];
  float v[8];
  v[0] = acc[0] * inv + b0.x; v[1] = acc[1] * inv + b0.y;
  v[2] = acc[2] * inv + b0.z; v[3] = acc[3] * inv + b0.w;
  v[4] = acc[4] * inv + b4.x; v[5] = acc[5] * inv + b4.y;
  v[6] = acc[6] * inv + b4.z; v[7] = acc[7] * inv + b4.w;
#pragma unroll
  for (int j = 0; j < 8; ++j) v[j] = v[j] > 0.f ? v[j] : (__expf(v[j]) - 1.f);  // ELU
  ushort4 o0 = make_ushort4(f2bf(v[0]), f2bf(v[1]), f2bf(v[2]), f2bf(v[3]));
  ushort4 o1 = make_ushort4(f2bf(v[4]), f2bf(v[5]), f2bf(v[6]), f2bf(v[7]));
  *(ushort4*)&out1b[(size_t)n * D1 + c0] = o0;
  *(ushort4*)&out1b[(size_t)n * D1 + c0 + 4] = o1;
}

// ---------------- GEMM2 (MFMA): h2(f32) = out1b @ W2 (+pad), fused alpha2 ----------------
__global__ __launch_bounds__(256) void gemm2_mfma(const unsigned short* __restrict__ ab,
                                                  const unsigned short* __restrict__ wb2t,
                                                  const float* __restrict__ a_src2,
                                                  const float* __restrict__ a_dst2,
                                                  float* __restrict__ h2,
                                                  float* __restrict__ asrc,
                                                  float* __restrict__ adst) {
  __shared__ unsigned short As[64 * 64];
  __shared__ unsigned short Bs[48 * 64];
  int tid = threadIdx.x;
  int w = tid >> 6, lane = tid & 63;
  int row0 = blockIdx.x * 64;
  int cl = lane & 15, hi = lane >> 4;
  f32x4 acc[3] = {};
  for (int k0 = 0; k0 < D1; k0 += 64) {
#pragma unroll
    for (int c = 0; c < 2; ++c) {
      int slot = c * 256 + tid;
      int r = slot >> 3;
      int q = (slot & 7) ^ (r & 7);
      gload16(ab + (size_t)(row0 + r) * D1 + k0 + q * 8, (char*)As + (c * 256 + w * 64) * 16);
    }
    {
      int r = tid >> 3;
      int q = (tid & 7) ^ (r & 7);
      gload16(wb2t + (size_t)r * D1 + k0 + q * 8, (char*)Bs + (w * 64) * 16);
      if (tid < 128) {
        int slot2 = 256 + tid;
        int r2 = slot2 >> 3;
        int q2 = (slot2 & 7) ^ (r2 & 7);
        gload16(wb2t + (size_t)r2 * D1 + k0 + q2 * 8, (char*)Bs + ((256 + w * 64)) * 16);
      }
    }
    __syncthreads();
#pragma unroll
    for (int kk = 0; kk < 2; ++kk) {
      int ra = w * 16 + cl;
      bf16x8 a = *(const bf16x8*)&As[ra * 64 + (((kk * 4 + hi) ^ (ra & 7)) << 3)];
#pragma unroll
      for (int n = 0; n < 3; ++n) {
        int rb = n * 16 + cl;
        bf16x8 b = *(const bf16x8*)&Bs[rb * 64 + (((kk * 4 + hi) ^ (rb & 7)) << 3)];
        acc[n] = __builtin_amdgcn_mfma_f32_16x16x32_bf16(a, b, acc[n], 0, 0, 0);
      }
    }
    __syncthreads();
  }
  float asv[3], adv[3];
#pragma unroll
  for (int n = 0; n < 3; ++n) {
    int c = n * 16 + cl;
    asv[n] = (c < NCLS) ? a_src2[c] : 0.f;
    adv[n] = (c < NCLS) ? a_dst2[c] : 0.f;
  }
#pragma unroll
  for (int r = 0; r < 4; ++r) {
    int grow = row0 + w * 16 + hi * 4 + r;
    float ps = acc[0][r] * asv[0] + acc[1][r] * asv[1] + acc[2][r] * asv[2];
    float pd = acc[0][r] * adv[0] + acc[1][r] * adv[1] + acc[2][r] * adv[2];
#pragma unroll
    for (int o = 8; o > 0; o >>= 1) { ps += __shfl_xor(ps, o); pd += __shfl_xor(pd, o); }
    if (grow < N_NODES) {
#pragma unroll
      for (int n = 0; n < 3; ++n) {
        int c = n * 16 + cl;
        if (c < NCLS) h2[(size_t)grow * NCLS + c] = acc[n][r];
      }
      if (cl == 0) { asrc[grow] = ps; adst[grow] = pd; }
    }
  }
}

// ---------------- agg2: LDS alpha + f32x2 gather (6 edges/iter) + b2 + log_softmax ----------------
__global__ __launch_bounds__(256) void agg2_kernel(const int* __restrict__ offsets,
                                                   const int* __restrict__ edge_src,
                                                   const float* __restrict__ asrc,
                                                   const float* __restrict__ adst,
                                                   const float* __restrict__ h2,
                                                   const float* __restrict__ b2,
                                                   float* __restrict__ out) {
  __shared__ float lalpha[4][MAXD + 8];
  __shared__ int   lsoff[4][MAXD + 8];
  int w = threadIdx.x >> 6;
  int lane = threadIdx.x & 63;
  int n = blockIdx.x * 4 + w;
  int base = offsets[n];
  int deg = offsets[n + 1] - base;
  int degc = min(deg, MAXD);
  int degp = ((degc + 5) / 6) * 6;

  float advv = adst[n];
  float m = -INFINITY;
  for (int e = lane; e < deg; e += 64) {
    int s = edge_src[base + e];
    float ev = lrelu(asrc[s] + advv);
    if (e < MAXD) { lsoff[w][e] = s * (NCLS * 4); lalpha[w][e] = ev; }
    m = fmaxf(m, ev);
  }
  m = wave_max(m);
  float ssum = 0.f;
  for (int e = lane; e < deg; e += 64) {
    float ev;
    if (e < MAXD) ev = lalpha[w][e];
    else { int s = edge_src[base + e]; ev = lrelu(asrc[s] + advv); }
    ssum += __expf(ev - m);
  }
  float inv = 1.f / (wave_sum(ssum) + 1e-16f);
  for (int e = lane; e < degc; e += 64) lalpha[w][e] = __expf(lalpha[w][e] - m) * inv;
  {
    int e = degc + lane;
    if (e < degp) { lalpha[w][e] = 0.f; lsoff[w][e] = 0; }
  }
  __builtin_amdgcn_wave_barrier();

  int esub = lane / 20;
  int cg = lane - esub * 20;
  bool act = esub < 3;
  float ax = 0.f, ay = 0.f;
  const char* hb = (const char*)h2 + cg * 8;
  for (int i = 0; i < degp; i += 6) {
    if (act) {
      int sA = i + esub, sB = i + 3 + esub;
      float aA = lalpha[w][sA], aB = lalpha[w][sB];
      int oA = lsoff[w][sA], oB = lsoff[w][sB];
      float2 hA = *(const float2*)(hb + oA);
      float2 hB = *(const float2*)(hb + oB);
      ax += aA * hA.x + aB * hB.x;
      ay += aA * hA.y + aB * hB.y;
    }
  }
  for (int e = MAXD + esub; e < deg; e += 3) {   // guard, never runs
    if (act) {
      int s = edge_src[base + e];
      float a = __expf(lrelu(asrc[s] + advv) - m) * inv;
      float2 hv = *(const float2*)(hb + (size_t)s * (NCLS * 4));
      ax += a * hv.x; ay += a * hv.y;
    }
  }
  float ax1 = __shfl(ax, lane + 20), ax2 = __shfl(ax, lane + 40);
  float ay1 = __shfl(ay, lane + 20), ay2 = __shfl(ay, lane + 40);
  float v0 = -INFINITY, v1 = -INFINITY;
  if (lane < 20) {
    v0 = ax + ax1 + ax2 + b2[2 * cg];
    v1 = ay + ay1 + ay2 + b2[2 * cg + 1];
  }
  float m2 = wave_max(fmaxf(v0, v1));
  float se = wave_sum(lane < 20 ? __expf(v0 - m2) + __expf(v1 - m2) : 0.f);
  if (lane < 20) {
    float ls = logf(se);
    *(float2*)&out[(size_t)n * NCLS + 2 * cg] = make_float2(v0 - m2 - ls, v1 - m2 - ls);
  }
}

extern "C" void kernel_launch(void* const* d_in, const int* in_sizes, int n_in,
                              void* d_out, int out_size, void* d_ws, size_t ws_size,
                              hipStream_t stream) {
  const float* x   = (const float*)d_in[0];
  const int*   ei  = (const int*)d_in[1];
  const float* W1  = (const float*)d_in[2];
  const float* as1 = (const float*)d_in[3];
  const float* ad1 = (const float*)d_in[4];
  const float* b1  = (const float*)d_in[5];
  const float* W2  = (const float*)d_in[6];
  const float* as2 = (const float*)d_in[7];
  const float* ad2 = (const float*)d_in[8];
  const float* b2  = (const float*)d_in[9];
  float* out = (float*)d_out;

  char* ws = (char*)d_ws;
  size_t off = 0;
  auto alloc = [&](size_t bytes) -> char* {
    char* p = ws + off;
    off += (bytes + 255) & ~(size_t)255;
    return p;
  };
  int* deg      = (int*)alloc((size_t)N_NODES * 4);
  int* cursor   = (int*)alloc((size_t)N_NODES * 4);
  int* offsets  = (int*)alloc((size_t)(N_NODES + 1) * 4);
  int* edge_src = (int*)alloc((size_t)EP * 4);
  int* perm     = (int*)alloc((size_t)N_NODES * 4);
  unsigned short* xb    = (unsigned short*)alloc((size_t)MPAD * F_IN * 2);
  unsigned short* wb1t  = (unsigned short*)alloc((size_t)D1 * F_IN * 2);
  unsigned short* wb2t  = (unsigned short*)alloc((size_t)48 * D1 * 2);
  unsigned short* h1b   = (unsigned short*)alloc((size_t)N_NODES * D1 * 2);
  unsigned short* out1b = (unsigned short*)alloc((size_t)MPAD * D1 * 2);
  float* asrc1  = (float*)alloc((size_t)N_NODES * H1 * 4);
  float* adst1  = (float*)alloc((size_t)N_NODES * H1 * 4);
  float* alphaE = (float*)alloc((size_t)H1 * EP * 4);
  float* inv1   = (float*)alloc((size_t)N_NODES * H1 * 4);
  float* h2     = (float*)alloc((size_t)N_NODES * NCLS * 4);
  float* asrc2  = (float*)alloc((size_t)N_NODES * 4);
  float* adst2  = (float*)alloc((size_t)N_NODES * 4);

  prep_kernel<<<PB_PAD, 256, 0, stream>>>(x, W1, W2, xb, wb1t, wb2t, deg, cursor, out1b);
  count_deg<<<(EP + 255) / 256, 256, 0, stream>>>(ei, deg);
  scan_kernel<<<1, SCAN_T, 0, stream>>>(deg, offsets, perm);
  scatter_edges<<<(EP + 255) / 256, 256, 0, stream>>>(ei, offsets, cursor, edge_src);

  gemm1_mfma<<<157 * 4, 256, 0, stream>>>(xb, wb1t, as1, ad1, h1b, asrc1, adst1);
  alpha1_kernel<<<N_NODES / 4, 256, 0, stream>>>(offsets, edge_src, asrc1, adst1, alphaE, inv1);
  agg1_gather<<<(N_NODES / 32) * 8, 256, 0, stream>>>(offsets, edge_src, perm, alphaE, inv1, h1b, b1, out1b);

  gemm2_mfma<<<MPAD / 64, 256, 0, stream>>>(out1b, wb2t, as2, ad2, h2, asrc2, adst2);
  agg2_kernel<<<N_NODES / 4, 256, 0, stream>>>(offsets, edge_src, asrc2, adst2, h2, b2, out);
}

// Round 16
// 153.914 us; speedup vs baseline: 1.4110x; 1.0726x over previous
//
#include <hip/hip_runtime.h>
#include <hip/hip_bf16.h>
#include <math.h>

#define N_NODES 20000
#define MPAD 20096               // 157*128
#define N_EDGES 320000
#define EP (N_EDGES + N_NODES)   // 340000
#define F_IN 256
#define NHID 64
#define H1 8
#define D1 512
#define NCLS 40
#define NEG_SLOPE 0.2f
#define MAXD 128

typedef __attribute__((ext_vector_type(8))) short bf16x8;
typedef __attribute__((ext_vector_type(4))) float f32x4;

__device__ __forceinline__ float wave_max(float v) {
#pragma unroll
  for (int o = 32; o > 0; o >>= 1) v = fmaxf(v, __shfl_xor(v, o));
  return v;
}
__device__ __forceinline__ float wave_sum(float v) {
#pragma unroll
  for (int o = 32; o > 0; o >>= 1) v += __shfl_xor(v, o);
  return v;
}
__device__ __forceinline__ unsigned short f2bf(float f) {
  union { float f; unsigned int i; } c; c.f = f;
  unsigned int x = c.i;
  return (unsigned short)((x + 0x7fffu + ((x >> 16) & 1u)) >> 16);  // RNE
}
__device__ __forceinline__ float asf(unsigned int u) {
  union { unsigned int i; float f; } c; c.i = u; return c.f;
}
__device__ __forceinline__ float lrelu(float x) { return x > 0.f ? x : NEG_SLOPE * x; }

__device__ __forceinline__ void gload16(const void* g, void* l) {
  __builtin_amdgcn_global_load_lds((const __attribute__((address_space(1))) void*)g,
                                   (__attribute__((address_space(3))) void*)l, 16, 0, 0);
}

// ---------------- fused prep: convert_x | transpose_w1 | transpose_w2 | zero pad | count_deg ----------------
#define PB_CONV 2512             // MPAD*F_IN/8/256
#define PB_TW1  (PB_CONV + 32)
#define PB_TW2  (PB_TW1 + 96)
#define PB_PAD  (PB_TW2 + 24)    // 96*512 bf16 = 6144*16B
#define PB_CNT  (PB_PAD + 1329)  // count_deg over EP edges
__global__ __launch_bounds__(256) void prep_kernel(const float* __restrict__ x,
                                                   const float* __restrict__ W1,
                                                   const float* __restrict__ W2,
                                                   const int* __restrict__ ei,
                                                   unsigned short* __restrict__ xb,
                                                   unsigned short* __restrict__ wb1t,
                                                   unsigned short* __restrict__ wb2t,
                                                   int* __restrict__ deg,
                                                   unsigned short* __restrict__ out1b) {
  __shared__ float tsh[64][65];
  int bid = blockIdx.x;
  int t = threadIdx.x;
  if (bid < PB_CONV) {
    size_t base = ((size_t)bid * 256 + t) * 8;
    int row = (int)(base >> 8);
    ushort4 o0, o1;
    if (row < N_NODES) {
      float4 v0 = *(const float4*)&x[base];
      float4 v1 = *(const float4*)&x[base + 4];
      o0 = make_ushort4(f2bf(v0.x), f2bf(v0.y), f2bf(v0.z), f2bf(v0.w));
      o1 = make_ushort4(f2bf(v1.x), f2bf(v1.y), f2bf(v1.z), f2bf(v1.w));
    } else {
      o0 = make_ushort4(0, 0, 0, 0); o1 = o0;
    }
    *(ushort4*)&xb[base] = o0;
    *(ushort4*)&xb[base + 4] = o1;
  } else if (bid < PB_TW1) {
    int b2 = bid - PB_CONV;
    int bk = b2 & 3, bn = b2 >> 2;
    int tr = t >> 4, tc4 = (t & 15) * 4;
#pragma unroll
    for (int i = 0; i < 4; ++i) {
      int k = i * 16 + tr;
      float4 v = *(const float4*)&W1[(size_t)(bk * 64 + k) * D1 + bn * 64 + tc4];
      tsh[k][tc4] = v.x; tsh[k][tc4 + 1] = v.y; tsh[k][tc4 + 2] = v.z; tsh[k][tc4 + 3] = v.w;
    }
    __syncthreads();
#pragma unroll
    for (int i = 0; i < 4; ++i) {
      int n = i * 16 + tr;
      ushort4 o = make_ushort4(f2bf(tsh[tc4][n]), f2bf(tsh[tc4 + 1][n]),
                               f2bf(tsh[tc4 + 2][n]), f2bf(tsh[tc4 + 3][n]));
      *(ushort4*)&wb1t[(size_t)(bn * 64 + n) * F_IN + bk * 64 + tc4] = o;
    }
  } else if (bid < PB_TW2) {
    int idx = (bid - PB_TW1) * 256 + t;
    int c = idx >> 9, k = idx & 511;
    wb2t[idx] = f2bf((c < NCLS) ? W2[(size_t)k * NCLS + c] : 0.f);
  } else if (bid < PB_PAD) {
    int idx = (bid - PB_TW2) * 256 + t;
    uint4 z = make_uint4(0, 0, 0, 0);
    *(uint4*)((char*)out1b + (size_t)N_NODES * D1 * 2 + (size_t)idx * 16) = z;
  } else {
    int e = (bid - PB_PAD) * 256 + t;
    if (e < EP) {
      int dst = (e < N_EDGES) ? ei[N_EDGES + e] : (e - N_EDGES);
      atomicAdd(&deg[dst], 1);
    }
  }
}

#define SCAN_T 1024
#define SCAN_CHUNK 20
__global__ __launch_bounds__(1024) void scan_kernel(const int* __restrict__ deg,
                                                    int* __restrict__ offsets) {
  __shared__ int wsum[16];
  int t = threadIdx.x;
  int w = t >> 6, lane = t & 63;
  int lo = t * SCAN_CHUNK;
  int hi = min(lo + SCAN_CHUNK, N_NODES);
  int s = 0;
  for (int i = lo; i < hi; ++i) s += deg[i];
  int incl = s;
#pragma unroll
  for (int o = 1; o < 64; o <<= 1) {
    int v = __shfl_up(incl, o);
    if (lane >= o) incl += v;
  }
  if (lane == 63) wsum[w] = incl;
  __syncthreads();
  if (t == 0) {
    int run = 0;
#pragma unroll
    for (int i = 0; i < 16; ++i) { int v = wsum[i]; wsum[i] = run; run += v; }
  }
  __syncthreads();
  int off = wsum[w] + incl - s;
  for (int i = lo; i < hi; ++i) { offsets[i] = off; off += deg[i]; }
  if (hi == N_NODES && lo < N_NODES) offsets[N_NODES] = off;
}

// ---------------- GEMM1 (MFMA) + scatter_edges (block-range merged) ----------------
#define G1_BLOCKS 628            // 157*4
__global__ __launch_bounds__(256) void gemm1_mfma(const unsigned short* __restrict__ xb,
                                                  const unsigned short* __restrict__ wb1t,
                                                  const float* __restrict__ a_src,
                                                  const float* __restrict__ a_dst,
                                                  unsigned short* __restrict__ h1b,
                                                  float* __restrict__ asrc,
                                                  float* __restrict__ adst,
                                                  const int* __restrict__ ei,
                                                  const int* __restrict__ offsets,
                                                  int* __restrict__ cursor,
                                                  int* __restrict__ edge_src) {
  __shared__ unsigned short As[128 * 64];
  __shared__ unsigned short Bs[128 * 64];
  int tid = threadIdx.x;
  if (blockIdx.x >= G1_BLOCKS) {   // scatter_edges range (independent of GEMM work)
    int e = (blockIdx.x - G1_BLOCKS) * 256 + tid;
    if (e < EP) {
      int src, dst;
      if (e < N_EDGES) { src = ei[e]; dst = ei[N_EDGES + e]; }
      else             { src = dst = e - N_EDGES; }
      int pos = offsets[dst] + atomicAdd(&cursor[dst], 1);
      edge_src[pos] = src;
    }
    return;
  }
  int w = tid >> 6, lane = tid & 63;
  int bn = blockIdx.x & 3, bm = blockIdx.x >> 2;
  int row0 = bm * 128, col0 = bn * 128;
  int wr = w >> 1, wc = w & 1;
  int cl = lane & 15, hi = lane >> 4;
  f32x4 acc[4][4] = {};
  for (int k0 = 0; k0 < F_IN; k0 += 64) {
#pragma unroll
    for (int c = 0; c < 4; ++c) {
      int slot = c * 256 + tid;
      int r = slot >> 3;
      int q = (slot & 7) ^ (r & 7);
      gload16(xb + (size_t)(row0 + r) * F_IN + k0 + q * 8, (char*)As + (c * 256 + w * 64) * 16);
      gload16(wb1t + (size_t)(col0 + r) * F_IN + k0 + q * 8, (char*)Bs + (c * 256 + w * 64) * 16);
    }
    __syncthreads();
#pragma unroll
    for (int kk = 0; kk < 2; ++kk) {
      bf16x8 a[4], b[4];
#pragma unroll
      for (int m = 0; m < 4; ++m) {
        int r = wr * 64 + m * 16 + cl;
        a[m] = *(const bf16x8*)&As[r * 64 + ((((kk * 4 + hi)) ^ (r & 7)) << 3)];
      }
#pragma unroll
      for (int n = 0; n < 4; ++n) {
        int r = wc * 64 + n * 16 + cl;
        b[n] = *(const bf16x8*)&Bs[r * 64 + ((((kk * 4 + hi)) ^ (r & 7)) << 3)];
      }
#pragma unroll
      for (int m = 0; m < 4; ++m)
#pragma unroll
        for (int n = 0; n < 4; ++n)
          acc[m][n] = __builtin_amdgcn_mfma_f32_16x16x32_bf16(a[m], b[n], acc[m][n], 0, 0, 0);
    }
    __syncthreads();
  }
  int head = bn * 2 + wc;
  float asv[4], adv[4];
#pragma unroll
  for (int n = 0; n < 4; ++n) {
    asv[n] = a_src[head * 64 + n * 16 + cl];
    adv[n] = a_dst[head * 64 + n * 16 + cl];
  }
#pragma unroll
  for (int m = 0; m < 4; ++m) {
#pragma unroll
    for (int r = 0; r < 4; ++r) {
      int grow = row0 + wr * 64 + m * 16 + hi * 4 + r;
      float ps = acc[m][0][r] * asv[0] + acc[m][1][r] * asv[1] +
                 acc[m][2][r] * asv[2] + acc[m][3][r] * asv[3];
      float pd = acc[m][0][r] * adv[0] + acc[m][1][r] * adv[1] +
                 acc[m][2][r] * adv[2] + acc[m][3][r] * adv[3];
#pragma unroll
      for (int o = 8; o > 0; o >>= 1) { ps += __shfl_xor(ps, o); pd += __shfl_xor(pd, o); }
      if (grow < N_NODES) {
#pragma unroll
        for (int n = 0; n < 4; ++n)
          h1b[(size_t)grow * D1 + col0 + wc * 64 + n * 16 + cl] = f2bf(acc[m][n][r]);
        if (cl == 0) { asrc[grow * H1 + head] = ps; adst[grow * H1 + head] = pd; }
      }
    }
  }
}

// ---------------- alpha1: node-parallel softmax -> unnormalized alpha (head-major) + inv ----------------
__global__ __launch_bounds__(256) void alpha1_kernel(const int* __restrict__ offsets,
                                                     const int* __restrict__ edge_src,
                                                     const float* __restrict__ asrc,
                                                     const float* __restrict__ adst,
                                                     float* __restrict__ alphaE,
                                                     float* __restrict__ inv1) {
  int w = threadIdx.x >> 6, lane = threadIdx.x & 63;
  int n = blockIdx.x * 4 + w;
  int base = offsets[n];
  int deg = offsets[n + 1] - base;
  int h = lane & 7, et = lane >> 3;
  float adv = adst[n * H1 + h];
  float evr[8];
  float m = -INFINITY;
#pragma unroll
  for (int k = 0; k < 8; ++k) {
    int e = et + k * 8;
    float ev = -INFINITY;
    if (e < deg) ev = lrelu(asrc[edge_src[base + e] * H1 + h] + adv);
    evr[k] = ev;
    m = fmaxf(m, ev);
  }
  for (int e = et + 64; e < deg; e += 8)   // guard, never runs for this graph
    m = fmaxf(m, lrelu(asrc[edge_src[base + e] * H1 + h] + adv));
  m = fmaxf(m, __shfl_xor(m, 8));
  m = fmaxf(m, __shfl_xor(m, 16));
  m = fmaxf(m, __shfl_xor(m, 32));
  float ss = 0.f;
#pragma unroll
  for (int k = 0; k < 8; ++k) {
    int e = et + k * 8;
    if (e < deg) {
      float a = __expf(evr[k] - m);
      alphaE[(size_t)h * EP + base + e] = a;
      ss += a;
    }
  }
  for (int e = et + 64; e < deg; e += 8) { // guard
    float a = __expf(lrelu(asrc[edge_src[base + e] * H1 + h] + adv) - m);
    alphaE[(size_t)h * EP + base + e] = a;
    ss += a;
  }
  ss += __shfl_xor(ss, 8);
  ss += __shfl_xor(ss, 16);
  ss += __shfl_xor(ss, 32);
  if (et == 0) inv1[n * H1 + h] = 1.f / (ss + 1e-16f);
}

// ---------------- agg1 gather: head-sliced XCD-affine, sequential nodes, unroll x8 ----------------
// bid&7 = head (round-robin block->XCD => per-XCD h1b re-read set = 2.56MB < 4MB L2).
// wave = 8 sequential nodes x 1 head; 8 lanes/node x 16B. 8 row loads in flight per lane.
__global__ __launch_bounds__(256) void agg1_gather(const int* __restrict__ offsets,
                                                   const int* __restrict__ edge_src,
                                                   const float* __restrict__ alphaE,
                                                   const float* __restrict__ inv1,
                                                   const unsigned short* __restrict__ h1b,
                                                   const float* __restrict__ b1,
                                                   unsigned short* __restrict__ out1b) {
  int w = threadIdx.x >> 6, lane = threadIdx.x & 63;
  int bid = blockIdx.x;
  int head = bid & 7;
  int ng = bid >> 3;
  int sub = lane >> 3, cl = lane & 7;
  int n = ng * 32 + w * 8 + sub;
  int base = offsets[n];
  int deg = offsets[n + 1] - base;
  const float* aE = alphaE + (size_t)head * EP + base;
  const int* es = edge_src + base;
  const char* hb = (const char*)h1b + head * 128 + cl * 16;
  float acc[8] = {};
  int e = 0;
  for (; e + 7 < deg; e += 8) {      // x8: eight independent row loads in flight
    float av[8]; int sv[8];
#pragma unroll
    for (int q = 0; q < 8; ++q) { av[q] = aE[e + q]; sv[q] = es[e + q]; }
    uint4 uv[8];
#pragma unroll
    for (int q = 0; q < 8; ++q) uv[q] = *(const uint4*)(hb + ((size_t)sv[q] << 10));
#pragma unroll
    for (int q = 0; q < 8; ++q) {
#pragma unroll
      for (int j = 0; j < 4; ++j) {
        unsigned int u = ((const unsigned int*)&uv[q])[j];
        acc[2 * j]     += av[q] * asf(u << 16);
        acc[2 * j + 1] += av[q] * asf(u & 0xffff0000u);
      }
    }
  }
  for (; e + 3 < deg; e += 4) {      // x4 tail
    float av[4]; int sv[4];
#pragma unroll
    for (int q = 0; q < 4; ++q) { av[q] = aE[e + q]; sv[q] = es[e + q]; }
    uint4 uv[4];
#pragma unroll
    for (int q = 0; q < 4; ++q) uv[q] = *(const uint4*)(hb + ((size_t)sv[q] << 10));
#pragma unroll
    for (int q = 0; q < 4; ++q) {
#pragma unroll
      for (int j = 0; j < 4; ++j) {
        unsigned int u = ((const unsigned int*)&uv[q])[j];
        acc[2 * j]     += av[q] * asf(u << 16);
        acc[2 * j + 1] += av[q] * asf(u & 0xffff0000u);
      }
    }
  }
  if (e + 1 < deg) {                 // x2 tail
    float a0 = aE[e], a1 = aE[e + 1];
    int s0 = es[e], s1 = es[e + 1];
    uint4 u0 = *(const uint4*)(hb + ((size_t)s0 << 10));
    uint4 u1 = *(const uint4*)(hb + ((size_t)s1 << 10));
#pragma unroll
    for (int j = 0; j < 4; ++j) {
      unsigned int x0 = ((const unsigned int*)&u0)[j];
      unsigned int x1 = ((const unsigned int*)&u1)[j];
      acc[2 * j]     += a0 * asf(x0 << 16) + a1 * asf(x1 << 16);
      acc[2 * j + 1] += a0 * asf(x0 & 0xffff0000u) + a1 * asf(x1 & 0xffff0000u);
    }
    e += 2;
  }
  if (e < deg) {                     // x1 tail
    float a = aE[e];
    int s = es[e];
    uint4 uv = *(const uint4*)(hb + ((size_t)s << 10));
#pragma unroll
    for (int j = 0; j < 4; ++j) {
      unsigned int u = ((const unsigned int*)&uv)[j];
      acc[2 * j]     += a * asf(u << 16);
      acc[2 * j + 1] += a * asf(u & 0xffff0000u);
    }
  }
  float inv = inv1[n * H1 + head];
  int c0 = head * NHID + cl * 8;
  float4 b0 = *(const float4*)&b1[c0];
  float4 b4 = *(const float4*)&b1[c0 + 4];
  float v[8];
  v[0] = acc[0] * inv + b0.x; v[1] = acc[1] * inv + b0.y;
  v[2] = acc[2] * inv + b0.z; v[3] = acc[3] * inv + b0.w;
  v[4] = acc[4] * inv + b4.x; v[5] = acc[5] * inv + b4.y;
  v[6] = acc[6] * inv + b4.z; v[7] = acc[7] * inv + b4.w;
#pragma unroll
  for (int j = 0; j < 8; ++j) v[j] = v[j] > 0.f ? v[j] : (__expf(v[j]) - 1.f);  // ELU
  ushort4 o0 = make_ushort4(f2bf(v[0]), f2bf(v[1]), f2bf(v[2]), f2bf(v[3]));
  ushort4 o1 = make_ushort4(f2bf(v[4]), f2bf(v[5]), f2bf(v[6]), f2bf(v[7]));
  *(ushort4*)&out1b[(size_t)n * D1 + c0] = o0;
  *(ushort4*)&out1b[(size_t)n * D1 + c0 + 4] = o1;
}

// ---------------- GEMM2 (MFMA): h2(f32) = out1b @ W2 (+pad), fused alpha2 ----------------
__global__ __launch_bounds__(256) void gemm2_mfma(const unsigned short* __restrict__ ab,
                                                  const unsigned short* __restrict__ wb2t,
                                                  const float* __restrict__ a_src2,
                                                  const float* __restrict__ a_dst2,
                                                  float* __restrict__ h2,
                                                  float* __restrict__ asrc,
                                                  float* __restrict__ adst) {
  __shared__ unsigned short As[64 * 64];
  __shared__ unsigned short Bs[48 * 64];
  int tid = threadIdx.x;
  int w = tid >> 6, lane = tid & 63;
  int row0 = blockIdx.x * 64;
  int cl = lane & 15, hi = lane >> 4;
  f32x4 acc[3] = {};
  for (int k0 = 0; k0 < D1; k0 += 64) {
#pragma unroll
    for (int c = 0; c < 2; ++c) {
      int slot = c * 256 + tid;
      int r = slot >> 3;
      int q = (slot & 7) ^ (r & 7);
      gload16(ab + (size_t)(row0 + r) * D1 + k0 + q * 8, (char*)As + (c * 256 + w * 64) * 16);
    }
    {
      int r = tid >> 3;
      int q = (tid & 7) ^ (r & 7);
      gload16(wb2t + (size_t)r * D1 + k0 + q * 8, (char*)Bs + (w * 64) * 16);
      if (tid < 128) {
        int slot2 = 256 + tid;
        int r2 = slot2 >> 3;
        int q2 = (slot2 & 7) ^ (r2 & 7);
        gload16(wb2t + (size_t)r2 * D1 + k0 + q2 * 8, (char*)Bs + ((256 + w * 64)) * 16);
      }
    }
    __syncthreads();
#pragma unroll
    for (int kk = 0; kk < 2; ++kk) {
      int ra = w * 16 + cl;
      bf16x8 a = *(const bf16x8*)&As[ra * 64 + (((kk * 4 + hi) ^ (ra & 7)) << 3)];
#pragma unroll
      for (int n = 0; n < 3; ++n) {
        int rb = n * 16 + cl;
        bf16x8 b = *(const bf16x8*)&Bs[rb * 64 + (((kk * 4 + hi) ^ (rb & 7)) << 3)];
        acc[n] = __builtin_amdgcn_mfma_f32_16x16x32_bf16(a, b, acc[n], 0, 0, 0);
      }
    }
    __syncthreads();
  }
  float asv[3], adv[3];
#pragma unroll
  for (int n = 0; n < 3; ++n) {
    int c = n * 16 + cl;
    asv[n] = (c < NCLS) ? a_src2[c] : 0.f;
    adv[n] = (c < NCLS) ? a_dst2[c] : 0.f;
  }
#pragma unroll
  for (int r = 0; r < 4; ++r) {
    int grow = row0 + w * 16 + hi * 4 + r;
    float ps = acc[0][r] * asv[0] + acc[1][r] * asv[1] + acc[2][r] * asv[2];
    float pd = acc[0][r] * adv[0] + acc[1][r] * adv[1] + acc[2][r] * adv[2];
#pragma unroll
    for (int o = 8; o > 0; o >>= 1) { ps += __shfl_xor(ps, o); pd += __shfl_xor(pd, o); }
    if (grow < N_NODES) {
#pragma unroll
      for (int n = 0; n < 3; ++n) {
        int c = n * 16 + cl;
        if (c < NCLS) h2[(size_t)grow * NCLS + c] = acc[n][r];
      }
      if (cl == 0) { asrc[grow] = ps; adst[grow] = pd; }
    }
  }
}

// ---------------- agg2: LDS alpha + f32x2 gather (6 edges/iter) + b2 + log_softmax ----------------
__global__ __launch_bounds__(256) void agg2_kernel(const int* __restrict__ offsets,
                                                   const int* __restrict__ edge_src,
                                                   const float* __restrict__ asrc,
                                                   const float* __restrict__ adst,
                                                   const float* __restrict__ h2,
                                                   const float* __restrict__ b2,
                                                   float* __restrict__ out) {
  __shared__ float lalpha[4][MAXD + 8];
  __shared__ int   lsoff[4][MAXD + 8];
  int w = threadIdx.x >> 6;
  int lane = threadIdx.x & 63;
  int n = blockIdx.x * 4 + w;
  int base = offsets[n];
  int deg = offsets[n + 1] - base;
  int degc = min(deg, MAXD);
  int degp = ((degc + 5) / 6) * 6;

  float advv = adst[n];
  float m = -INFINITY;
  for (int e = lane; e < deg; e += 64) {
    int s = edge_src[base + e];
    float ev = lrelu(asrc[s] + advv);
    if (e < MAXD) { lsoff[w][e] = s * (NCLS * 4); lalpha[w][e] = ev; }
    m = fmaxf(m, ev);
  }
  m = wave_max(m);
  float ssum = 0.f;
  for (int e = lane; e < deg; e += 64) {
    float ev;
    if (e < MAXD) ev = lalpha[w][e];
    else { int s = edge_src[base + e]; ev = lrelu(asrc[s] + advv); }
    ssum += __expf(ev - m);
  }
  float inv = 1.f / (wave_sum(ssum) + 1e-16f);
  for (int e = lane; e < degc; e += 64) lalpha[w][e] = __expf(lalpha[w][e] - m) * inv;
  {
    int e = degc + lane;
    if (e < degp) { lalpha[w][e] = 0.f; lsoff[w][e] = 0; }
  }
  __builtin_amdgcn_wave_barrier();

  int esub = lane / 20;
  int cg = lane - esub * 20;
  bool act = esub < 3;
  float ax = 0.f, ay = 0.f;
  const char* hb = (const char*)h2 + cg * 8;
  for (int i = 0; i < degp; i += 6) {
    if (act) {
      int sA = i + esub, sB = i + 3 + esub;
      float aA = lalpha[w][sA], aB = lalpha[w][sB];
      int oA = lsoff[w][sA], oB = lsoff[w][sB];
      float2 hA = *(const float2*)(hb + oA);
      float2 hB = *(const float2*)(hb + oB);
      ax += aA * hA.x + aB * hB.x;
      ay += aA * hA.y + aB * hB.y;
    }
  }
  for (int e = MAXD + esub; e < deg; e += 3) {   // guard, never runs
    if (act) {
      int s = edge_src[base + e];
      float a = __expf(lrelu(asrc[s] + advv) - m) * inv;
      float2 hv = *(const float2*)(hb + (size_t)s * (NCLS * 4));
      ax += a * hv.x; ay += a * hv.y;
    }
  }
  float ax1 = __shfl(ax, lane + 20), ax2 = __shfl(ax, lane + 40);
  float ay1 = __shfl(ay, lane + 20), ay2 = __shfl(ay, lane + 40);
  float v0 = -INFINITY, v1 = -INFINITY;
  if (lane < 20) {
    v0 = ax + ax1 + ax2 + b2[2 * cg];
    v1 = ay + ay1 + ay2 + b2[2 * cg + 1];
  }
  float m2 = wave_max(fmaxf(v0, v1));
  float se = wave_sum(lane < 20 ? __expf(v0 - m2) + __expf(v1 - m2) : 0.f);
  if (lane < 20) {
    float ls = logf(se);
    *(float2*)&out[(size_t)n * NCLS + 2 * cg] = make_float2(v0 - m2 - ls, v1 - m2 - ls);
  }
}

extern "C" void kernel_launch(void* const* d_in, const int* in_sizes, int n_in,
                              void* d_out, int out_size, void* d_ws, size_t ws_size,
                              hipStream_t stream) {
  const float* x   = (const float*)d_in[0];
  const int*   ei  = (const int*)d_in[1];
  const float* W1  = (const float*)d_in[2];
  const float* as1 = (const float*)d_in[3];
  const float* ad1 = (const float*)d_in[4];
  const float* b1  = (const float*)d_in[5];
  const float* W2  = (const float*)d_in[6];
  const float* as2 = (const float*)d_in[7];
  const float* ad2 = (const float*)d_in[8];
  const float* b2  = (const float*)d_in[9];
  float* out = (float*)d_out;

  char* ws = (char*)d_ws;
  size_t off = 0;
  auto alloc = [&](size_t bytes) -> char* {
    char* p = ws + off;
    off += (bytes + 255) & ~(size_t)255;
    return p;
  };
  int* deg      = (int*)alloc((size_t)N_NODES * 4);
  int* cursor   = (int*)alloc((size_t)N_NODES * 4);
  int* offsets  = (int*)alloc((size_t)(N_NODES + 1) * 4);
  int* edge_src = (int*)alloc((size_t)EP * 4);
  unsigned short* xb    = (unsigned short*)alloc((size_t)MPAD * F_IN * 2);
  unsigned short* wb1t  = (unsigned short*)alloc((size_t)D1 * F_IN * 2);
  unsigned short* wb2t  = (unsigned short*)alloc((size_t)48 * D1 * 2);
  unsigned short* h1b   = (unsigned short*)alloc((size_t)N_NODES * D1 * 2);
  unsigned short* out1b = (unsigned short*)alloc((size_t)MPAD * D1 * 2);
  float* asrc1  = (float*)alloc((size_t)N_NODES * H1 * 4);
  float* adst1  = (float*)alloc((size_t)N_NODES * H1 * 4);
  float* alphaE = (float*)alloc((size_t)H1 * EP * 4);
  float* inv1   = (float*)alloc((size_t)N_NODES * H1 * 4);
  float* h2     = (float*)alloc((size_t)N_NODES * NCLS * 4);
  float* asrc2  = (float*)alloc((size_t)N_NODES * 4);
  float* adst2  = (float*)alloc((size_t)N_NODES * 4);

  hipMemsetAsync(deg, 0, (size_t)N_NODES * 4, stream);
  hipMemsetAsync(cursor, 0, (size_t)N_NODES * 4, stream);

  prep_kernel<<<PB_CNT, 256, 0, stream>>>(x, W1, W2, ei, xb, wb1t, wb2t, deg, out1b);
  scan_kernel<<<1, SCAN_T, 0, stream>>>(deg, offsets);
  gemm1_mfma<<<G1_BLOCKS + 1329, 256, 0, stream>>>(xb, wb1t, as1, ad1, h1b, asrc1, adst1,
                                                   ei, offsets, cursor, edge_src);
  alpha1_kernel<<<N_NODES / 4, 256, 0, stream>>>(offsets, edge_src, asrc1, adst1, alphaE, inv1);
  agg1_gather<<<(N_NODES / 32) * 8, 256, 0, stream>>>(offsets, edge_src, alphaE, inv1, h1b, b1, out1b);

  gemm2_mfma<<<MPAD / 64, 256, 0, stream>>>(out1b, wb2t, as2, ad2, h2, asrc2, adst2);
  agg2_kernel<<<N_NODES / 4, 256, 0, stream>>>(offsets, edge_src, asrc2, adst2, h2, b2, out);
}

// Round 17
// 148.524 us; speedup vs baseline: 1.4622x; 1.0363x over previous
//
#include <hip/hip_runtime.h>
#include <hip/hip_bf16.h>
#include <math.h>

#define N_NODES 20000
#define MPAD 20096               // 157*128
#define N_EDGES 320000
#define EP (N_EDGES + N_NODES)   // 340000
#define F_IN 256
#define NHID 64
#define H1 8
#define D1 512
#define NCLS 40
#define NEG_SLOPE 0.2f
#define MAXD 128

typedef __attribute__((ext_vector_type(8))) short bf16x8;
typedef __attribute__((ext_vector_type(4))) float f32x4;

__device__ __forceinline__ float wave_max(float v) {
#pragma unroll
  for (int o = 32; o > 0; o >>= 1) v = fmaxf(v, __shfl_xor(v, o));
  return v;
}
__device__ __forceinline__ float wave_sum(float v) {
#pragma unroll
  for (int o = 32; o > 0; o >>= 1) v += __shfl_xor(v, o);
  return v;
}
__device__ __forceinline__ unsigned short f2bf(float f) {
  union { float f; unsigned int i; } c; c.f = f;
  unsigned int x = c.i;
  return (unsigned short)((x + 0x7fffu + ((x >> 16) & 1u)) >> 16);  // RNE
}
__device__ __forceinline__ float asf(unsigned int u) {
  union { unsigned int i; float f; } c; c.i = u; return c.f;
}
__device__ __forceinline__ float lrelu(float x) { return x > 0.f ? x : NEG_SLOPE * x; }

__device__ __forceinline__ void gload16(const void* g, void* l) {
  __builtin_amdgcn_global_load_lds((const __attribute__((address_space(1))) void*)g,
                                   (__attribute__((address_space(3))) void*)l, 16, 0, 0);
}

// ---------------- fused prep: convert_x | transpose_w1 | transpose_w2 | zero pad | count_deg ----------------
#define PB_CONV 2512             // MPAD*F_IN/8/256
#define PB_TW1  (PB_CONV + 32)
#define PB_TW2  (PB_TW1 + 96)
#define PB_PAD  (PB_TW2 + 24)    // 96*512 bf16 = 6144*16B
#define PB_CNT  (PB_PAD + 1329)  // count_deg over EP edges
__global__ __launch_bounds__(256) void prep_kernel(const float* __restrict__ x,
                                                   const float* __restrict__ W1,
                                                   const float* __restrict__ W2,
                                                   const int* __restrict__ ei,
                                                   unsigned short* __restrict__ xb,
                                                   unsigned short* __restrict__ wb1t,
                                                   unsigned short* __restrict__ wb2t,
                                                   int* __restrict__ deg,
                                                   unsigned short* __restrict__ out1b) {
  __shared__ float tsh[64][65];
  int bid = blockIdx.x;
  int t = threadIdx.x;
  if (bid < PB_CONV) {
    size_t base = ((size_t)bid * 256 + t) * 8;
    int row = (int)(base >> 8);
    ushort4 o0, o1;
    if (row < N_NODES) {
      float4 v0 = *(const float4*)&x[base];
      float4 v1 = *(const float4*)&x[base + 4];
      o0 = make_ushort4(f2bf(v0.x), f2bf(v0.y), f2bf(v0.z), f2bf(v0.w));
      o1 = make_ushort4(f2bf(v1.x), f2bf(v1.y), f2bf(v1.z), f2bf(v1.w));
    } else {
      o0 = make_ushort4(0, 0, 0, 0); o1 = o0;
    }
    *(ushort4*)&xb[base] = o0;
    *(ushort4*)&xb[base + 4] = o1;
  } else if (bid < PB_TW1) {
    int b2 = bid - PB_CONV;
    int bk = b2 & 3, bn = b2 >> 2;
    int tr = t >> 4, tc4 = (t & 15) * 4;
#pragma unroll
    for (int i = 0; i < 4; ++i) {
      int k = i * 16 + tr;
      float4 v = *(const float4*)&W1[(size_t)(bk * 64 + k) * D1 + bn * 64 + tc4];
      tsh[k][tc4] = v.x; tsh[k][tc4 + 1] = v.y; tsh[k][tc4 + 2] = v.z; tsh[k][tc4 + 3] = v.w;
    }
    __syncthreads();
#pragma unroll
    for (int i = 0; i < 4; ++i) {
      int n = i * 16 + tr;
      ushort4 o = make_ushort4(f2bf(tsh[tc4][n]), f2bf(tsh[tc4 + 1][n]),
                               f2bf(tsh[tc4 + 2][n]), f2bf(tsh[tc4 + 3][n]));
      *(ushort4*)&wb1t[(size_t)(bn * 64 + n) * F_IN + bk * 64 + tc4] = o;
    }
  } else if (bid < PB_TW2) {
    int idx = (bid - PB_TW1) * 256 + t;
    int c = idx >> 9, k = idx & 511;
    wb2t[idx] = f2bf((c < NCLS) ? W2[(size_t)k * NCLS + c] : 0.f);
  } else if (bid < PB_PAD) {
    int idx = (bid - PB_TW2) * 256 + t;
    uint4 z = make_uint4(0, 0, 0, 0);
    *(uint4*)((char*)out1b + (size_t)N_NODES * D1 * 2 + (size_t)idx * 16) = z;
  } else {
    int e = (bid - PB_PAD) * 256 + t;
    if (e < EP) {
      int dst = (e < N_EDGES) ? ei[N_EDGES + e] : (e - N_EDGES);
      atomicAdd(&deg[dst], 1);
    }
  }
}

#define SCAN_T 1024
#define SCAN_CHUNK 20
__global__ __launch_bounds__(1024) void scan_kernel(const int* __restrict__ deg,
                                                    int* __restrict__ offsets) {
  __shared__ int wsum[16];
  int t = threadIdx.x;
  int w = t >> 6, lane = t & 63;
  int lo = t * SCAN_CHUNK;
  int hi = min(lo + SCAN_CHUNK, N_NODES);
  int s = 0;
  for (int i = lo; i < hi; ++i) s += deg[i];
  int incl = s;
#pragma unroll
  for (int o = 1; o < 64; o <<= 1) {
    int v = __shfl_up(incl, o);
    if (lane >= o) incl += v;
  }
  if (lane == 63) wsum[w] = incl;
  __syncthreads();
  if (t == 0) {
    int run = 0;
#pragma unroll
    for (int i = 0; i < 16; ++i) { int v = wsum[i]; wsum[i] = run; run += v; }
  }
  __syncthreads();
  int off = wsum[w] + incl - s;
  for (int i = lo; i < hi; ++i) { offsets[i] = off; off += deg[i]; }
  if (hi == N_NODES && lo < N_NODES) offsets[N_NODES] = off;
}

// ---------------- GEMM1 (MFMA) + scatter_edges (block-range merged) ----------------
#define G1_BLOCKS 628            // 157*4
__global__ __launch_bounds__(256) void gemm1_mfma(const unsigned short* __restrict__ xb,
                                                  const unsigned short* __restrict__ wb1t,
                                                  const float* __restrict__ a_src,
                                                  const float* __restrict__ a_dst,
                                                  unsigned short* __restrict__ h1b,
                                                  float* __restrict__ asrc,
                                                  float* __restrict__ adst,
                                                  const int* __restrict__ ei,
                                                  const int* __restrict__ offsets,
                                                  int* __restrict__ cursor,
                                                  int* __restrict__ edge_src) {
  __shared__ unsigned short As[128 * 64];
  __shared__ unsigned short Bs[128 * 64];
  int tid = threadIdx.x;
  if (blockIdx.x >= G1_BLOCKS) {   // scatter_edges range (independent of GEMM work)
    int e = (blockIdx.x - G1_BLOCKS) * 256 + tid;
    if (e < EP) {
      int src, dst;
      if (e < N_EDGES) { src = ei[e]; dst = ei[N_EDGES + e]; }
      else             { src = dst = e - N_EDGES; }
      int pos = offsets[dst] + atomicAdd(&cursor[dst], 1);
      edge_src[pos] = src;
    }
    return;
  }
  int w = tid >> 6, lane = tid & 63;
  int bn = blockIdx.x & 3, bm = blockIdx.x >> 2;
  int row0 = bm * 128, col0 = bn * 128;
  int wr = w >> 1, wc = w & 1;
  int cl = lane & 15, hi = lane >> 4;
  f32x4 acc[4][4] = {};
  for (int k0 = 0; k0 < F_IN; k0 += 64) {
#pragma unroll
    for (int c = 0; c < 4; ++c) {
      int slot = c * 256 + tid;
      int r = slot >> 3;
      int q = (slot & 7) ^ (r & 7);
      gload16(xb + (size_t)(row0 + r) * F_IN + k0 + q * 8, (char*)As + (c * 256 + w * 64) * 16);
      gload16(wb1t + (size_t)(col0 + r) * F_IN + k0 + q * 8, (char*)Bs + (c * 256 + w * 64) * 16);
    }
    __syncthreads();
#pragma unroll
    for (int kk = 0; kk < 2; ++kk) {
      bf16x8 a[4], b[4];
#pragma unroll
      for (int m = 0; m < 4; ++m) {
        int r = wr * 64 + m * 16 + cl;
        a[m] = *(const bf16x8*)&As[r * 64 + ((((kk * 4 + hi)) ^ (r & 7)) << 3)];
      }
#pragma unroll
      for (int n = 0; n < 4; ++n) {
        int r = wc * 64 + n * 16 + cl;
        b[n] = *(const bf16x8*)&Bs[r * 64 + ((((kk * 4 + hi)) ^ (r & 7)) << 3)];
      }
#pragma unroll
      for (int m = 0; m < 4; ++m)
#pragma unroll
        for (int n = 0; n < 4; ++n)
          acc[m][n] = __builtin_amdgcn_mfma_f32_16x16x32_bf16(a[m], b[n], acc[m][n], 0, 0, 0);
    }
    __syncthreads();
  }
  int head = bn * 2 + wc;
  float asv[4], adv[4];
#pragma unroll
  for (int n = 0; n < 4; ++n) {
    asv[n] = a_src[head * 64 + n * 16 + cl];
    adv[n] = a_dst[head * 64 + n * 16 + cl];
  }
#pragma unroll
  for (int m = 0; m < 4; ++m) {
#pragma unroll
    for (int r = 0; r < 4; ++r) {
      int grow = row0 + wr * 64 + m * 16 + hi * 4 + r;
      float ps = acc[m][0][r] * asv[0] + acc[m][1][r] * asv[1] +
                 acc[m][2][r] * asv[2] + acc[m][3][r] * asv[3];
      float pd = acc[m][0][r] * adv[0] + acc[m][1][r] * adv[1] +
                 acc[m][2][r] * adv[2] + acc[m][3][r] * adv[3];
#pragma unroll
      for (int o = 8; o > 0; o >>= 1) { ps += __shfl_xor(ps, o); pd += __shfl_xor(pd, o); }
      if (grow < N_NODES) {
#pragma unroll
        for (int n = 0; n < 4; ++n)
          h1b[(size_t)grow * D1 + col0 + wc * 64 + n * 16 + cl] = f2bf(acc[m][n][r]);
        if (cl == 0) { asrc[grow * H1 + head] = ps; adst[grow * H1 + head] = pd; }
      }
    }
  }
}

// ---------------- alpha1: node-parallel softmax -> unnormalized alpha (head-major) + inv ----------------
__global__ __launch_bounds__(256) void alpha1_kernel(const int* __restrict__ offsets,
                                                     const int* __restrict__ edge_src,
                                                     const float* __restrict__ asrc,
                                                     const float* __restrict__ adst,
                                                     float* __restrict__ alphaE,
                                                     float* __restrict__ inv1) {
  int w = threadIdx.x >> 6, lane = threadIdx.x & 63;
  int n = blockIdx.x * 4 + w;
  int base = offsets[n];
  int deg = offsets[n + 1] - base;
  int h = lane & 7, et = lane >> 3;
  float adv = adst[n * H1 + h];
  float evr[8];
  float m = -INFINITY;
#pragma unroll
  for (int k = 0; k < 8; ++k) {
    int e = et + k * 8;
    float ev = -INFINITY;
    if (e < deg) ev = lrelu(asrc[edge_src[base + e] * H1 + h] + adv);
    evr[k] = ev;
    m = fmaxf(m, ev);
  }
  for (int e = et + 64; e < deg; e += 8)   // guard, never runs for this graph
    m = fmaxf(m, lrelu(asrc[edge_src[base + e] * H1 + h] + adv));
  m = fmaxf(m, __shfl_xor(m, 8));
  m = fmaxf(m, __shfl_xor(m, 16));
  m = fmaxf(m, __shfl_xor(m, 32));
  float ss = 0.f;
#pragma unroll
  for (int k = 0; k < 8; ++k) {
    int e = et + k * 8;
    if (e < deg) {
      float a = __expf(evr[k] - m);
      alphaE[(size_t)h * EP + base + e] = a;
      ss += a;
    }
  }
  for (int e = et + 64; e < deg; e += 8) { // guard
    float a = __expf(lrelu(asrc[edge_src[base + e] * H1 + h] + adv) - m);
    alphaE[(size_t)h * EP + base + e] = a;
    ss += a;
  }
  ss += __shfl_xor(ss, 8);
  ss += __shfl_xor(ss, 16);
  ss += __shfl_xor(ss, 32);
  if (et == 0) inv1[n * H1 + h] = 1.f / (ss + 1e-16f);
}

// ---------------- agg1 gather: head-sliced XCD-affine, sequential nodes, unroll x4 ----------------
// bid&7 = head (round-robin block->XCD => per-XCD h1b re-read set = 2.56MB < 4MB L2).
// wave = 8 sequential nodes x 1 head; 8 lanes/node x 16B. 4 row loads in flight per lane
// (x4 was the ILP/occupancy sweet spot: x8 ballooned VGPR 32->52, occupancy 59->32%).
__global__ __launch_bounds__(256) void agg1_gather(const int* __restrict__ offsets,
                                                   const int* __restrict__ edge_src,
                                                   const float* __restrict__ alphaE,
                                                   const float* __restrict__ inv1,
                                                   const unsigned short* __restrict__ h1b,
                                                   const float* __restrict__ b1,
                                                   unsigned short* __restrict__ out1b) {
  int w = threadIdx.x >> 6, lane = threadIdx.x & 63;
  int bid = blockIdx.x;
  int head = bid & 7;
  int ng = bid >> 3;
  int sub = lane >> 3, cl = lane & 7;
  int n = ng * 32 + w * 8 + sub;
  int base = offsets[n];
  int deg = offsets[n + 1] - base;
  const float* aE = alphaE + (size_t)head * EP + base;
  const int* es = edge_src + base;
  const char* hb = (const char*)h1b + head * 128 + cl * 16;
  float acc[8] = {};
  int e = 0;
  for (; e + 3 < deg; e += 4) {
    float a0 = aE[e], a1 = aE[e + 1], a2 = aE[e + 2], a3 = aE[e + 3];
    int s0 = es[e], s1 = es[e + 1], s2 = es[e + 2], s3 = es[e + 3];
    uint4 u0 = *(const uint4*)(hb + ((size_t)s0 << 10));
    uint4 u1 = *(const uint4*)(hb + ((size_t)s1 << 10));
    uint4 u2 = *(const uint4*)(hb + ((size_t)s2 << 10));
    uint4 u3 = *(const uint4*)(hb + ((size_t)s3 << 10));
#pragma unroll
    for (int j = 0; j < 4; ++j) {
      unsigned int x0 = ((const unsigned int*)&u0)[j];
      unsigned int x1 = ((const unsigned int*)&u1)[j];
      unsigned int x2 = ((const unsigned int*)&u2)[j];
      unsigned int x3 = ((const unsigned int*)&u3)[j];
      acc[2 * j]     += a0 * asf(x0 << 16) + a1 * asf(x1 << 16)
                      + a2 * asf(x2 << 16) + a3 * asf(x3 << 16);
      acc[2 * j + 1] += a0 * asf(x0 & 0xffff0000u) + a1 * asf(x1 & 0xffff0000u)
                      + a2 * asf(x2 & 0xffff0000u) + a3 * asf(x3 & 0xffff0000u);
    }
  }
  if (e + 1 < deg) {           // x2 tail
    float a0 = aE[e], a1 = aE[e + 1];
    int s0 = es[e], s1 = es[e + 1];
    uint4 u0 = *(const uint4*)(hb + ((size_t)s0 << 10));
    uint4 u1 = *(const uint4*)(hb + ((size_t)s1 << 10));
#pragma unroll
    for (int j = 0; j < 4; ++j) {
      unsigned int x0 = ((const unsigned int*)&u0)[j];
      unsigned int x1 = ((const unsigned int*)&u1)[j];
      acc[2 * j]     += a0 * asf(x0 << 16) + a1 * asf(x1 << 16);
      acc[2 * j + 1] += a0 * asf(x0 & 0xffff0000u) + a1 * asf(x1 & 0xffff0000u);
    }
    e += 2;
  }
  if (e < deg) {               // x1 tail
    float a = aE[e];
    int s = es[e];
    uint4 uv = *(const uint4*)(hb + ((size_t)s << 10));
#pragma unroll
    for (int j = 0; j < 4; ++j) {
      unsigned int u = ((const unsigned int*)&uv)[j];
      acc[2 * j]     += a * asf(u << 16);
      acc[2 * j + 1] += a * asf(u & 0xffff0000u);
    }
  }
  float inv = inv1[n * H1 + head];
  int c0 = head * NHID + cl * 8;
  float4 b0 = *(const float4*)&b1[c0];
  float4 b4 = *(const float4*)&b1[c0 + 4];
  float v[8];
  v[0] = acc[0] * inv + b0.x; v[1] = acc[1] * inv + b0.y;
  v[2] = acc[2] * inv + b0.z; v[3] = acc[3] * inv + b0.w;
  v[4] = acc[4] * inv + b4.x; v[5] = acc[5] * inv + b4.y;
  v[6] = acc[6] * inv + b4.z; v[7] = acc[7] * inv + b4.w;
#pragma unroll
  for (int j = 0; j < 8; ++j) v[j] = v[j] > 0.f ? v[j] : (__expf(v[j]) - 1.f);  // ELU
  ushort4 o0 = make_ushort4(f2bf(v[0]), f2bf(v[1]), f2bf(v[2]), f2bf(v[3]));
  ushort4 o1 = make_ushort4(f2bf(v[4]), f2bf(v[5]), f2bf(v[6]), f2bf(v[7]));
  *(ushort4*)&out1b[(size_t)n * D1 + c0] = o0;
  *(ushort4*)&out1b[(size_t)n * D1 + c0 + 4] = o1;
}

// ---------------- GEMM2 (MFMA): h2(f32) = out1b @ W2 (+pad), fused alpha2 ----------------
__global__ __launch_bounds__(256) void gemm2_mfma(const unsigned short* __restrict__ ab,
                                                  const unsigned short* __restrict__ wb2t,
                                                  const float* __restrict__ a_src2,
                                                  const float* __restrict__ a_dst2,
                                                  float* __restrict__ h2,
                                                  float* __restrict__ asrc,
                                                  float* __restrict__ adst) {
  __shared__ unsigned short As[64 * 64];
  __shared__ unsigned short Bs[48 * 64];
  int tid = threadIdx.x;
  int w = tid >> 6, lane = tid & 63;
  int row0 = blockIdx.x * 64;
  int cl = lane & 15, hi = lane >> 4;
  f32x4 acc[3] = {};
  for (int k0 = 0; k0 < D1; k0 += 64) {
#pragma unroll
    for (int c = 0; c < 2; ++c) {
      int slot = c * 256 + tid;
      int r = slot >> 3;
      int q = (slot & 7) ^ (r & 7);
      gload16(ab + (size_t)(row0 + r) * D1 + k0 + q * 8, (char*)As + (c * 256 + w * 64) * 16);
    }
    {
      int r = tid >> 3;
      int q = (tid & 7) ^ (r & 7);
      gload16(wb2t + (size_t)r * D1 + k0 + q * 8, (char*)Bs + (w * 64) * 16);
      if (tid < 128) {
        int slot2 = 256 + tid;
        int r2 = slot2 >> 3;
        int q2 = (slot2 & 7) ^ (r2 & 7);
        gload16(wb2t + (size_t)r2 * D1 + k0 + q2 * 8, (char*)Bs + ((256 + w * 64)) * 16);
      }
    }
    __syncthreads();
#pragma unroll
    for (int kk = 0; kk < 2; ++kk) {
      int ra = w * 16 + cl;
      bf16x8 a = *(const bf16x8*)&As[ra * 64 + (((kk * 4 + hi) ^ (ra & 7)) << 3)];
#pragma unroll
      for (int n = 0; n < 3; ++n) {
        int rb = n * 16 + cl;
        bf16x8 b = *(const bf16x8*)&Bs[rb * 64 + (((kk * 4 + hi) ^ (rb & 7)) << 3)];
        acc[n] = __builtin_amdgcn_mfma_f32_16x16x32_bf16(a, b, acc[n], 0, 0, 0);
      }
    }
    __syncthreads();
  }
  float asv[3], adv[3];
#pragma unroll
  for (int n = 0; n < 3; ++n) {
    int c = n * 16 + cl;
    asv[n] = (c < NCLS) ? a_src2[c] : 0.f;
    adv[n] = (c < NCLS) ? a_dst2[c] : 0.f;
  }
#pragma unroll
  for (int r = 0; r < 4; ++r) {
    int grow = row0 + w * 16 + hi * 4 + r;
    float ps = acc[0][r] * asv[0] + acc[1][r] * asv[1] + acc[2][r] * asv[2];
    float pd = acc[0][r] * adv[0] + acc[1][r] * adv[1] + acc[2][r] * adv[2];
#pragma unroll
    for (int o = 8; o > 0; o >>= 1) { ps += __shfl_xor(ps, o); pd += __shfl_xor(pd, o); }
    if (grow < N_NODES) {
#pragma unroll
      for (int n = 0; n < 3; ++n) {
        int c = n * 16 + cl;
        if (c < NCLS) h2[(size_t)grow * NCLS + c] = acc[n][r];
      }
      if (cl == 0) { asrc[grow] = ps; adst[grow] = pd; }
    }
  }
}

// ---------------- agg2: LDS alpha + f32x2 gather (6 edges/iter) + b2 + log_softmax ----------------
__global__ __launch_bounds__(256) void agg2_kernel(const int* __restrict__ offsets,
                                                   const int* __restrict__ edge_src,
                                                   const float* __restrict__ asrc,
                                                   const float* __restrict__ adst,
                                                   const float* __restrict__ h2,
                                                   const float* __restrict__ b2,
                                                   float* __restrict__ out) {
  __shared__ float lalpha[4][MAXD + 8];
  __shared__ int   lsoff[4][MAXD + 8];
  int w = threadIdx.x >> 6;
  int lane = threadIdx.x & 63;
  int n = blockIdx.x * 4 + w;
  int base = offsets[n];
  int deg = offsets[n + 1] - base;
  int degc = min(deg, MAXD);
  int degp = ((degc + 5) / 6) * 6;

  float advv = adst[n];
  float m = -INFINITY;
  for (int e = lane; e < deg; e += 64) {
    int s = edge_src[base + e];
    float ev = lrelu(asrc[s] + advv);
    if (e < MAXD) { lsoff[w][e] = s * (NCLS * 4); lalpha[w][e] = ev; }
    m = fmaxf(m, ev);
  }
  m = wave_max(m);
  float ssum = 0.f;
  for (int e = lane; e < deg; e += 64) {
    float ev;
    if (e < MAXD) ev = lalpha[w][e];
    else { int s = edge_src[base + e]; ev = lrelu(asrc[s] + advv); }
    ssum += __expf(ev - m);
  }
  float inv = 1.f / (wave_sum(ssum) + 1e-16f);
  for (int e = lane; e < degc; e += 64) lalpha[w][e] = __expf(lalpha[w][e] - m) * inv;
  {
    int e = degc + lane;
    if (e < degp) { lalpha[w][e] = 0.f; lsoff[w][e] = 0; }
  }
  __builtin_amdgcn_wave_barrier();

  int esub = lane / 20;
  int cg = lane - esub * 20;
  bool act = esub < 3;
  float ax = 0.f, ay = 0.f;
  const char* hb = (const char*)h2 + cg * 8;
  for (int i = 0; i < degp; i += 6) {
    if (act) {
      int sA = i + esub, sB = i + 3 + esub;
      float aA = lalpha[w][sA], aB = lalpha[w][sB];
      int oA = lsoff[w][sA], oB = lsoff[w][sB];
      float2 hA = *(const float2*)(hb + oA);
      float2 hB = *(const float2*)(hb + oB);
      ax += aA * hA.x + aB * hB.x;
      ay += aA * hA.y + aB * hB.y;
    }
  }
  for (int e = MAXD + esub; e < deg; e += 3) {   // guard, never runs
    if (act) {
      int s = edge_src[base + e];
      float a = __expf(lrelu(asrc[s] + advv) - m) * inv;
      float2 hv = *(const float2*)(hb + (size_t)s * (NCLS * 4));
      ax += a * hv.x; ay += a * hv.y;
    }
  }
  float ax1 = __shfl(ax, lane + 20), ax2 = __shfl(ax, lane + 40);
  float ay1 = __shfl(ay, lane + 20), ay2 = __shfl(ay, lane + 40);
  float v0 = -INFINITY, v1 = -INFINITY;
  if (lane < 20) {
    v0 = ax + ax1 + ax2 + b2[2 * cg];
    v1 = ay + ay1 + ay2 + b2[2 * cg + 1];
  }
  float m2 = wave_max(fmaxf(v0, v1));
  float se = wave_sum(lane < 20 ? __expf(v0 - m2) + __expf(v1 - m2) : 0.f);
  if (lane < 20) {
    float ls = logf(se);
    *(float2*)&out[(size_t)n * NCLS + 2 * cg] = make_float2(v0 - m2 - ls, v1 - m2 - ls);
  }
}

extern "C" void kernel_launch(void* const* d_in, const int* in_sizes, int n_in,
                              void* d_out, int out_size, void* d_ws, size_t ws_size,
                              hipStream_t stream) {
  const float* x   = (const float*)d_in[0];
  const int*   ei  = (const int*)d_in[1];
  const float* W1  = (const float*)d_in[2];
  const float* as1 = (const float*)d_in[3];
  const float* ad1 = (const float*)d_in[4];
  const float* b1  = (const float*)d_in[5];
  const float* W2  = (const float*)d_in[6];
  const float* as2 = (const float*)d_in[7];
  const float* ad2 = (const float*)d_in[8];
  const float* b2  = (const float*)d_in[9];
  float* out = (float*)d_out;

  char* ws = (char*)d_ws;
  size_t off = 0;
  auto alloc = [&](size_t bytes) -> char* {
    char* p = ws + off;
    off += (bytes + 255) & ~(size_t)255;
    return p;
  };
  int* deg      = (int*)alloc((size_t)N_NODES * 4);
  int* cursor   = (int*)alloc((size_t)N_NODES * 4);
  int* offsets  = (int*)alloc((size_t)(N_NODES + 1) * 4);
  int* edge_src = (int*)alloc((size_t)EP * 4);
  unsigned short* xb    = (unsigned short*)alloc((size_t)MPAD * F_IN * 2);
  unsigned short* wb1t  = (unsigned short*)alloc((size_t)D1 * F_IN * 2);
  unsigned short* wb2t  = (unsigned short*)alloc((size_t)48 * D1 * 2);
  unsigned short* h1b   = (unsigned short*)alloc((size_t)N_NODES * D1 * 2);
  unsigned short* out1b = (unsigned short*)alloc((size_t)MPAD * D1 * 2);
  float* asrc1  = (float*)alloc((size_t)N_NODES * H1 * 4);
  float* adst1  = (float*)alloc((size_t)N_NODES * H1 * 4);
  float* alphaE = (float*)alloc((size_t)H1 * EP * 4);
  float* inv1   = (float*)alloc((size_t)N_NODES * H1 * 4);
  float* h2     = (float*)alloc((size_t)N_NODES * NCLS * 4);
  float* asrc2  = (float*)alloc((size_t)N_NODES * 4);
  float* adst2  = (float*)alloc((size_t)N_NODES * 4);

  hipMemsetAsync(deg, 0, (size_t)N_NODES * 4, stream);
  hipMemsetAsync(cursor, 0, (size_t)N_NODES * 4, stream);

  prep_kernel<<<PB_CNT, 256, 0, stream>>>(x, W1, W2, ei, xb, wb1t, wb2t, deg, out1b);
  scan_kernel<<<1, SCAN_T, 0, stream>>>(deg, offsets);
  gemm1_mfma<<<G1_BLOCKS + 1329, 256, 0, stream>>>(xb, wb1t, as1, ad1, h1b, asrc1, adst1,
                                                   ei, offsets, cursor, edge_src);
  alpha1_kernel<<<N_NODES / 4, 256, 0, stream>>>(offsets, edge_src, asrc1, adst1, alphaE, inv1);
  agg1_gather<<<(N_NODES / 32) * 8, 256, 0, stream>>>(offsets, edge_src, alphaE, inv1, h1b, b1, out1b);

  gemm2_mfma<<<MPAD / 64, 256, 0, stream>>>(out1b, wb2t, as2, ad2, h2, asrc2, adst2);
  agg2_kernel<<<N_NODES / 4, 256, 0, stream>>>(offsets, edge_src, asrc2, adst2, h2, b2, out);
}

// Round 18
// 145.932 us; speedup vs baseline: 1.4882x; 1.0178x over previous
//
#include <hip/hip_runtime.h>
#include <hip/hip_bf16.h>
#include <math.h>

#define N_NODES 20000
#define MPAD 20096               // 157*128
#define N_EDGES 320000
#define EP (N_EDGES + N_NODES)   // 340000
#define F_IN 256
#define NHID 64
#define H1 8
#define D1 512
#define NCLS 40
#define NEG_SLOPE 0.2f
#define MAXD 128

typedef __attribute__((ext_vector_type(8))) short bf16x8;
typedef __attribute__((ext_vector_type(4))) float f32x4;

__device__ __forceinline__ float wave_max(float v) {
#pragma unroll
  for (int o = 32; o > 0; o >>= 1) v = fmaxf(v, __shfl_xor(v, o));
  return v;
}
__device__ __forceinline__ float wave_sum(float v) {
#pragma unroll
  for (int o = 32; o > 0; o >>= 1) v += __shfl_xor(v, o);
  return v;
}
__device__ __forceinline__ unsigned short f2bf(float f) {
  union { float f; unsigned int i; } c; c.f = f;
  unsigned int x = c.i;
  return (unsigned short)((x + 0x7fffu + ((x >> 16) & 1u)) >> 16);  // RNE
}
__device__ __forceinline__ float asf(unsigned int u) {
  union { unsigned int i; float f; } c; c.i = u; return c.f;
}
__device__ __forceinline__ float lrelu(float x) { return x > 0.f ? x : NEG_SLOPE * x; }

__device__ __forceinline__ void gload16(const void* g, void* l) {
  __builtin_amdgcn_global_load_lds((const __attribute__((address_space(1))) void*)g,
                                   (__attribute__((address_space(3))) void*)l, 16, 0, 0);
}

// ---------------- fused prep: convert_x | transpose_w1 | transpose_w2 | zero pad | count_deg ----------------
#define PB_CONV 2512             // MPAD*F_IN/8/256
#define PB_TW1  (PB_CONV + 32)
#define PB_TW2  (PB_TW1 + 96)
#define PB_PAD  (PB_TW2 + 24)    // 96*512 bf16 = 6144*16B
#define PB_CNT  (PB_PAD + 1329)  // count_deg over EP edges
__global__ __launch_bounds__(256) void prep_kernel(const float* __restrict__ x,
                                                   const float* __restrict__ W1,
                                                   const float* __restrict__ W2,
                                                   const int* __restrict__ ei,
                                                   unsigned short* __restrict__ xb,
                                                   unsigned short* __restrict__ wb1t,
                                                   unsigned short* __restrict__ wb2t,
                                                   int* __restrict__ deg,
                                                   unsigned short* __restrict__ out1b) {
  __shared__ float tsh[64][65];
  int bid = blockIdx.x;
  int t = threadIdx.x;
  if (bid < PB_CONV) {
    size_t base = ((size_t)bid * 256 + t) * 8;
    int row = (int)(base >> 8);
    ushort4 o0, o1;
    if (row < N_NODES) {
      float4 v0 = *(const float4*)&x[base];
      float4 v1 = *(const float4*)&x[base + 4];
      o0 = make_ushort4(f2bf(v0.x), f2bf(v0.y), f2bf(v0.z), f2bf(v0.w));
      o1 = make_ushort4(f2bf(v1.x), f2bf(v1.y), f2bf(v1.z), f2bf(v1.w));
    } else {
      o0 = make_ushort4(0, 0, 0, 0); o1 = o0;
    }
    *(ushort4*)&xb[base] = o0;
    *(ushort4*)&xb[base + 4] = o1;
  } else if (bid < PB_TW1) {
    int b2 = bid - PB_CONV;
    int bk = b2 & 3, bn = b2 >> 2;
    int tr = t >> 4, tc4 = (t & 15) * 4;
#pragma unroll
    for (int i = 0; i < 4; ++i) {
      int k = i * 16 + tr;
      float4 v = *(const float4*)&W1[(size_t)(bk * 64 + k) * D1 + bn * 64 + tc4];
      tsh[k][tc4] = v.x; tsh[k][tc4 + 1] = v.y; tsh[k][tc4 + 2] = v.z; tsh[k][tc4 + 3] = v.w;
    }
    __syncthreads();
#pragma unroll
    for (int i = 0; i < 4; ++i) {
      int n = i * 16 + tr;
      ushort4 o = make_ushort4(f2bf(tsh[tc4][n]), f2bf(tsh[tc4 + 1][n]),
                               f2bf(tsh[tc4 + 2][n]), f2bf(tsh[tc4 + 3][n]));
      *(ushort4*)&wb1t[(size_t)(bn * 64 + n) * F_IN + bk * 64 + tc4] = o;
    }
  } else if (bid < PB_TW2) {
    int idx = (bid - PB_TW1) * 256 + t;
    int c = idx >> 9, k = idx & 511;
    wb2t[idx] = f2bf((c < NCLS) ? W2[(size_t)k * NCLS + c] : 0.f);
  } else if (bid < PB_PAD) {
    int idx = (bid - PB_TW2) * 256 + t;
    uint4 z = make_uint4(0, 0, 0, 0);
    *(uint4*)((char*)out1b + (size_t)N_NODES * D1 * 2 + (size_t)idx * 16) = z;
  } else {
    int e = (bid - PB_PAD) * 256 + t;
    if (e < EP) {
      int dst = (e < N_EDGES) ? ei[N_EDGES + e] : (e - N_EDGES);
      atomicAdd(&deg[dst], 1);
    }
  }
}

#define SCAN_T 1024
#define SCAN_CHUNK 20
__global__ __launch_bounds__(1024) void scan_kernel(const int* __restrict__ deg,
                                                    int* __restrict__ offsets) {
  __shared__ int wsum[16];
  int t = threadIdx.x;
  int w = t >> 6, lane = t & 63;
  int lo = t * SCAN_CHUNK;
  int hi = min(lo + SCAN_CHUNK, N_NODES);
  int s = 0;
  for (int i = lo; i < hi; ++i) s += deg[i];
  int incl = s;
#pragma unroll
  for (int o = 1; o < 64; o <<= 1) {
    int v = __shfl_up(incl, o);
    if (lane >= o) incl += v;
  }
  if (lane == 63) wsum[w] = incl;
  __syncthreads();
  if (t == 0) {
    int run = 0;
#pragma unroll
    for (int i = 0; i < 16; ++i) { int v = wsum[i]; wsum[i] = run; run += v; }
  }
  __syncthreads();
  int off = wsum[w] + incl - s;
  for (int i = lo; i < hi; ++i) { offsets[i] = off; off += deg[i]; }
  if (hi == N_NODES && lo < N_NODES) offsets[N_NODES] = off;
}

// ---------------- GEMM1 (MFMA) + scatter_edges (block-range merged) ----------------
#define G1_BLOCKS 628            // 157*4
__global__ __launch_bounds__(256) void gemm1_mfma(const unsigned short* __restrict__ xb,
                                                  const unsigned short* __restrict__ wb1t,
                                                  const float* __restrict__ a_src,
                                                  const float* __restrict__ a_dst,
                                                  unsigned short* __restrict__ h1b,
                                                  float* __restrict__ asrc,
                                                  float* __restrict__ adst,
                                                  const int* __restrict__ ei,
                                                  const int* __restrict__ offsets,
                                                  int* __restrict__ cursor,
                                                  int* __restrict__ edge_src) {
  __shared__ unsigned short As[128 * 64];
  __shared__ unsigned short Bs[128 * 64];
  int tid = threadIdx.x;
  if (blockIdx.x >= G1_BLOCKS) {   // scatter_edges range (independent of GEMM work)
    int e = (blockIdx.x - G1_BLOCKS) * 256 + tid;
    if (e < EP) {
      int src, dst;
      if (e < N_EDGES) { src = ei[e]; dst = ei[N_EDGES + e]; }
      else             { src = dst = e - N_EDGES; }
      int pos = offsets[dst] + atomicAdd(&cursor[dst], 1);
      edge_src[pos] = src;
    }
    return;
  }
  int w = tid >> 6, lane = tid & 63;
  int bn = blockIdx.x & 3, bm = blockIdx.x >> 2;
  int row0 = bm * 128, col0 = bn * 128;
  int wr = w >> 1, wc = w & 1;
  int cl = lane & 15, hi = lane >> 4;
  f32x4 acc[4][4] = {};
  for (int k0 = 0; k0 < F_IN; k0 += 64) {
#pragma unroll
    for (int c = 0; c < 4; ++c) {
      int slot = c * 256 + tid;
      int r = slot >> 3;
      int q = (slot & 7) ^ (r & 7);
      gload16(xb + (size_t)(row0 + r) * F_IN + k0 + q * 8, (char*)As + (c * 256 + w * 64) * 16);
      gload16(wb1t + (size_t)(col0 + r) * F_IN + k0 + q * 8, (char*)Bs + (c * 256 + w * 64) * 16);
    }
    __syncthreads();
#pragma unroll
    for (int kk = 0; kk < 2; ++kk) {
      bf16x8 a[4], b[4];
#pragma unroll
      for (int m = 0; m < 4; ++m) {
        int r = wr * 64 + m * 16 + cl;
        a[m] = *(const bf16x8*)&As[r * 64 + ((((kk * 4 + hi)) ^ (r & 7)) << 3)];
      }
#pragma unroll
      for (int n = 0; n < 4; ++n) {
        int r = wc * 64 + n * 16 + cl;
        b[n] = *(const bf16x8*)&Bs[r * 64 + ((((kk * 4 + hi)) ^ (r & 7)) << 3)];
      }
#pragma unroll
      for (int m = 0; m < 4; ++m)
#pragma unroll
        for (int n = 0; n < 4; ++n)
          acc[m][n] = __builtin_amdgcn_mfma_f32_16x16x32_bf16(a[m], b[n], acc[m][n], 0, 0, 0);
    }
    __syncthreads();
  }
  int head = bn * 2 + wc;
  float asv[4], adv[4];
#pragma unroll
  for (int n = 0; n < 4; ++n) {
    asv[n] = a_src[head * 64 + n * 16 + cl];
    adv[n] = a_dst[head * 64 + n * 16 + cl];
  }
#pragma unroll
  for (int m = 0; m < 4; ++m) {
#pragma unroll
    for (int r = 0; r < 4; ++r) {
      int grow = row0 + wr * 64 + m * 16 + hi * 4 + r;
      float ps = acc[m][0][r] * asv[0] + acc[m][1][r] * asv[1] +
                 acc[m][2][r] * asv[2] + acc[m][3][r] * asv[3];
      float pd = acc[m][0][r] * adv[0] + acc[m][1][r] * adv[1] +
                 acc[m][2][r] * adv[2] + acc[m][3][r] * adv[3];
#pragma unroll
      for (int o = 8; o > 0; o >>= 1) { ps += __shfl_xor(ps, o); pd += __shfl_xor(pd, o); }
      if (grow < N_NODES) {
#pragma unroll
        for (int n = 0; n < 4; ++n)
          h1b[(size_t)grow * D1 + col0 + wc * 64 + n * 16 + cl] = f2bf(acc[m][n][r]);
        if (cl == 0) { asrc[grow * H1 + head] = ps; adst[grow * H1 + head] = pd; }
      }
    }
  }
}

// ---------------- alpha1: node-parallel softmax -> PACKED (bf16 alpha | src) head-major + inv ----------------
// pack = (f2bf(exp(ev-m)) << 16) | src  (src < 20000 < 2^16). Gather unpacks with 2 ANDs.
__global__ __launch_bounds__(256) void alpha1_kernel(const int* __restrict__ offsets,
                                                     const int* __restrict__ edge_src,
                                                     const float* __restrict__ asrc,
                                                     const float* __restrict__ adst,
                                                     unsigned int* __restrict__ alphaP,
                                                     float* __restrict__ inv1) {
  int w = threadIdx.x >> 6, lane = threadIdx.x & 63;
  int n = blockIdx.x * 4 + w;
  int base = offsets[n];
  int deg = offsets[n + 1] - base;
  int h = lane & 7, et = lane >> 3;
  float adv = adst[n * H1 + h];
  float evr[8];
  int   svr[8];
  float m = -INFINITY;
#pragma unroll
  for (int k = 0; k < 8; ++k) {
    int e = et + k * 8;
    float ev = -INFINITY;
    int sv = 0;
    if (e < deg) {
      sv = edge_src[base + e];
      ev = lrelu(asrc[sv * H1 + h] + adv);
    }
    evr[k] = ev; svr[k] = sv;
    m = fmaxf(m, ev);
  }
  for (int e = et + 64; e < deg; e += 8)   // guard, never runs for this graph
    m = fmaxf(m, lrelu(asrc[edge_src[base + e] * H1 + h] + adv));
  m = fmaxf(m, __shfl_xor(m, 8));
  m = fmaxf(m, __shfl_xor(m, 16));
  m = fmaxf(m, __shfl_xor(m, 32));
  float ss = 0.f;
#pragma unroll
  for (int k = 0; k < 8; ++k) {
    int e = et + k * 8;
    if (e < deg) {
      float a = __expf(evr[k] - m);
      alphaP[(size_t)h * EP + base + e] =
          ((unsigned int)f2bf(a) << 16) | (unsigned int)svr[k];
      ss += a;
    }
  }
  for (int e = et + 64; e < deg; e += 8) { // guard
    int sv = edge_src[base + e];
    float a = __expf(lrelu(asrc[sv * H1 + h] + adv) - m);
    alphaP[(size_t)h * EP + base + e] = ((unsigned int)f2bf(a) << 16) | (unsigned int)sv;
    ss += a;
  }
  ss += __shfl_xor(ss, 8);
  ss += __shfl_xor(ss, 16);
  ss += __shfl_xor(ss, 32);
  if (et == 0) inv1[n * H1 + h] = 1.f / (ss + 1e-16f);
}

// ---------------- agg1 gather: head-sliced XCD-affine, packed meta, unroll x4 ----------------
// bid&7 = head (round-robin block->XCD => per-XCD h1b re-read set = 2.56MB < 4MB L2).
// One packed u32 per edge carries (bf16 alpha | src): 4 meta + 4 row loads per x4 iter.
__global__ __launch_bounds__(256) void agg1_gather(const int* __restrict__ offsets,
                                                   const unsigned int* __restrict__ alphaP,
                                                   const float* __restrict__ inv1,
                                                   const unsigned short* __restrict__ h1b,
                                                   const float* __restrict__ b1,
                                                   unsigned short* __restrict__ out1b) {
  int w = threadIdx.x >> 6, lane = threadIdx.x & 63;
  int bid = blockIdx.x;
  int head = bid & 7;
  int ng = bid >> 3;
  int sub = lane >> 3, cl = lane & 7;
  int n = ng * 32 + w * 8 + sub;
  int base = offsets[n];
  int deg = offsets[n + 1] - base;
  const unsigned int* pE = alphaP + (size_t)head * EP + base;
  const char* hb = (const char*)h1b + head * 128 + cl * 16;
  float acc[8] = {};
  int e = 0;
  for (; e + 3 < deg; e += 4) {
    unsigned int p0 = pE[e], p1 = pE[e + 1], p2 = pE[e + 2], p3 = pE[e + 3];
    uint4 u0 = *(const uint4*)(hb + ((size_t)(p0 & 0xffffu) << 10));
    uint4 u1 = *(const uint4*)(hb + ((size_t)(p1 & 0xffffu) << 10));
    uint4 u2 = *(const uint4*)(hb + ((size_t)(p2 & 0xffffu) << 10));
    uint4 u3 = *(const uint4*)(hb + ((size_t)(p3 & 0xffffu) << 10));
    float a0 = asf(p0 & 0xffff0000u), a1 = asf(p1 & 0xffff0000u);
    float a2 = asf(p2 & 0xffff0000u), a3 = asf(p3 & 0xffff0000u);
#pragma unroll
    for (int j = 0; j < 4; ++j) {
      unsigned int x0 = ((const unsigned int*)&u0)[j];
      unsigned int x1 = ((const unsigned int*)&u1)[j];
      unsigned int x2 = ((const unsigned int*)&u2)[j];
      unsigned int x3 = ((const unsigned int*)&u3)[j];
      acc[2 * j]     += a0 * asf(x0 << 16) + a1 * asf(x1 << 16)
                      + a2 * asf(x2 << 16) + a3 * asf(x3 << 16);
      acc[2 * j + 1] += a0 * asf(x0 & 0xffff0000u) + a1 * asf(x1 & 0xffff0000u)
                      + a2 * asf(x2 & 0xffff0000u) + a3 * asf(x3 & 0xffff0000u);
    }
  }
  if (e + 1 < deg) {           // x2 tail
    unsigned int p0 = pE[e], p1 = pE[e + 1];
    uint4 u0 = *(const uint4*)(hb + ((size_t)(p0 & 0xffffu) << 10));
    uint4 u1 = *(const uint4*)(hb + ((size_t)(p1 & 0xffffu) << 10));
    float a0 = asf(p0 & 0xffff0000u), a1 = asf(p1 & 0xffff0000u);
#pragma unroll
    for (int j = 0; j < 4; ++j) {
      unsigned int x0 = ((const unsigned int*)&u0)[j];
      unsigned int x1 = ((const unsigned int*)&u1)[j];
      acc[2 * j]     += a0 * asf(x0 << 16) + a1 * asf(x1 << 16);
      acc[2 * j + 1] += a0 * asf(x0 & 0xffff0000u) + a1 * asf(x1 & 0xffff0000u);
    }
    e += 2;
  }
  if (e < deg) {               // x1 tail
    unsigned int p0 = pE[e];
    uint4 uv = *(const uint4*)(hb + ((size_t)(p0 & 0xffffu) << 10));
    float a = asf(p0 & 0xffff0000u);
#pragma unroll
    for (int j = 0; j < 4; ++j) {
      unsigned int u = ((const unsigned int*)&uv)[j];
      acc[2 * j]     += a * asf(u << 16);
      acc[2 * j + 1] += a * asf(u & 0xffff0000u);
    }
  }
  float inv = inv1[n * H1 + head];
  int c0 = head * NHID + cl * 8;
  float4 b0 = *(const float4*)&b1[c0];
  float4 b4 = *(const float4*)&b1[c0 + 4];
  float v[8];
  v[0] = acc[0] * inv + b0.x; v[1] = acc[1] * inv + b0.y;
  v[2] = acc[2] * inv + b0.z; v[3] = acc[3] * inv + b0.w;
  v[4] = acc[4] * inv + b4.x; v[5] = acc[5] * inv + b4.y;
  v[6] = acc[6] * inv + b4.z; v[7] = acc[7] * inv + b4.w;
#pragma unroll
  for (int j = 0; j < 8; ++j) v[j] = v[j] > 0.f ? v[j] : (__expf(v[j]) - 1.f);  // ELU
  ushort4 o0 = make_ushort4(f2bf(v[0]), f2bf(v[1]), f2bf(v[2]), f2bf(v[3]));
  ushort4 o1 = make_ushort4(f2bf(v[4]), f2bf(v[5]), f2bf(v[6]), f2bf(v[7]));
  *(ushort4*)&out1b[(size_t)n * D1 + c0] = o0;
  *(ushort4*)&out1b[(size_t)n * D1 + c0 + 4] = o1;
}

// ---------------- GEMM2 (MFMA): h2(f32) = out1b @ W2 (+pad), fused alpha2 ----------------
__global__ __launch_bounds__(256) void gemm2_mfma(const unsigned short* __restrict__ ab,
                                                  const unsigned short* __restrict__ wb2t,
                                                  const float* __restrict__ a_src2,
                                                  const float* __restrict__ a_dst2,
                                                  float* __restrict__ h2,
                                                  float* __restrict__ asrc,
                                                  float* __restrict__ adst) {
  __shared__ unsigned short As[64 * 64];
  __shared__ unsigned short Bs[48 * 64];
  int tid = threadIdx.x;
  int w = tid >> 6, lane = tid & 63;
  int row0 = blockIdx.x * 64;
  int cl = lane & 15, hi = lane >> 4;
  f32x4 acc[3] = {};
  for (int k0 = 0; k0 < D1; k0 += 64) {
#pragma unroll
    for (int c = 0; c < 2; ++c) {
      int slot = c * 256 + tid;
      int r = slot >> 3;
      int q = (slot & 7) ^ (r & 7);
      gload16(ab + (size_t)(row0 + r) * D1 + k0 + q * 8, (char*)As + (c * 256 + w * 64) * 16);
    }
    {
      int r = tid >> 3;
      int q = (tid & 7) ^ (r & 7);
      gload16(wb2t + (size_t)r * D1 + k0 + q * 8, (char*)Bs + (w * 64) * 16);
      if (tid < 128) {
        int slot2 = 256 + tid;
        int r2 = slot2 >> 3;
        int q2 = (slot2 & 7) ^ (r2 & 7);
        gload16(wb2t + (size_t)r2 * D1 + k0 + q2 * 8, (char*)Bs + ((256 + w * 64)) * 16);
      }
    }
    __syncthreads();
#pragma unroll
    for (int kk = 0; kk < 2; ++kk) {
      int ra = w * 16 + cl;
      bf16x8 a = *(const bf16x8*)&As[ra * 64 + (((kk * 4 + hi) ^ (ra & 7)) << 3)];
#pragma unroll
      for (int n = 0; n < 3; ++n) {
        int rb = n * 16 + cl;
        bf16x8 b = *(const bf16x8*)&Bs[rb * 64 + (((kk * 4 + hi) ^ (rb & 7)) << 3)];
        acc[n] = __builtin_amdgcn_mfma_f32_16x16x32_bf16(a, b, acc[n], 0, 0, 0);
      }
    }
    __syncthreads();
  }
  float asv[3], adv[3];
#pragma unroll
  for (int n = 0; n < 3; ++n) {
    int c = n * 16 + cl;
    asv[n] = (c < NCLS) ? a_src2[c] : 0.f;
    adv[n] = (c < NCLS) ? a_dst2[c] : 0.f;
  }
#pragma unroll
  for (int r = 0; r < 4; ++r) {
    int grow = row0 + w * 16 + hi * 4 + r;
    float ps = acc[0][r] * asv[0] + acc[1][r] * asv[1] + acc[2][r] * asv[2];
    float pd = acc[0][r] * adv[0] + acc[1][r] * adv[1] + acc[2][r] * adv[2];
#pragma unroll
    for (int o = 8; o > 0; o >>= 1) { ps += __shfl_xor(ps, o); pd += __shfl_xor(pd, o); }
    if (grow < N_NODES) {
#pragma unroll
      for (int n = 0; n < 3; ++n) {
        int c = n * 16 + cl;
        if (c < NCLS) h2[(size_t)grow * NCLS + c] = acc[n][r];
      }
      if (cl == 0) { asrc[grow] = ps; adst[grow] = pd; }
    }
  }
}

// ---------------- agg2: LDS alpha + f32x2 gather (6 edges/iter) + b2 + log_softmax ----------------
__global__ __launch_bounds__(256) void agg2_kernel(const int* __restrict__ offsets,
                                                   const int* __restrict__ edge_src,
                                                   const float* __restrict__ asrc,
                                                   const float* __restrict__ adst,
                                                   const float* __restrict__ h2,
                                                   const float* __restrict__ b2,
                                                   float* __restrict__ out) {
  __shared__ float lalpha[4][MAXD + 8];
  __shared__ int   lsoff[4][MAXD + 8];
  int w = threadIdx.x >> 6;
  int lane = threadIdx.x & 63;
  int n = blockIdx.x * 4 + w;
  int base = offsets[n];
  int deg = offsets[n + 1] - base;
  int degc = min(deg, MAXD);
  int degp = ((degc + 5) / 6) * 6;

  float advv = adst[n];
  float m = -INFINITY;
  for (int e = lane; e < deg; e += 64) {
    int s = edge_src[base + e];
    float ev = lrelu(asrc[s] + advv);
    if (e < MAXD) { lsoff[w][e] = s * (NCLS * 4); lalpha[w][e] = ev; }
    m = fmaxf(m, ev);
  }
  m = wave_max(m);
  float ssum = 0.f;
  for (int e = lane; e < deg; e += 64) {
    float ev;
    if (e < MAXD) ev = lalpha[w][e];
    else { int s = edge_src[base + e]; ev = lrelu(asrc[s] + advv); }
    ssum += __expf(ev - m);
  }
  float inv = 1.f / (wave_sum(ssum) + 1e-16f);
  for (int e = lane; e < degc; e += 64) lalpha[w][e] = __expf(lalpha[w][e] - m) * inv;
  {
    int e = degc + lane;
    if (e < degp) { lalpha[w][e] = 0.f; lsoff[w][e] = 0; }
  }
  __builtin_amdgcn_wave_barrier();

  int esub = lane / 20;
  int cg = lane - esub * 20;
  bool act = esub < 3;
  float ax = 0.f, ay = 0.f;
  const char* hb = (const char*)h2 + cg * 8;
  for (int i = 0; i < degp; i += 6) {
    if (act) {
      int sA = i + esub, sB = i + 3 + esub;
      float aA = lalpha[w][sA], aB = lalpha[w][sB];
      int oA = lsoff[w][sA], oB = lsoff[w][sB];
      float2 hA = *(const float2*)(hb + oA);
      float2 hB = *(const float2*)(hb + oB);
      ax += aA * hA.x + aB * hB.x;
      ay += aA * hA.y + aB * hB.y;
    }
  }
  for (int e = MAXD + esub; e < deg; e += 3) {   // guard, never runs
    if (act) {
      int s = edge_src[base + e];
      float a = __expf(lrelu(asrc[s] + advv) - m) * inv;
      float2 hv = *(const float2*)(hb + (size_t)s * (NCLS * 4));
      ax += a * hv.x; ay += a * hv.y;
    }
  }
  float ax1 = __shfl(ax, lane + 20), ax2 = __shfl(ax, lane + 40);
  float ay1 = __shfl(ay, lane + 20), ay2 = __shfl(ay, lane + 40);
  float v0 = -INFINITY, v1 = -INFINITY;
  if (lane < 20) {
    v0 = ax + ax1 + ax2 + b2[2 * cg];
    v1 = ay + ay1 + ay2 + b2[2 * cg + 1];
  }
  float m2 = wave_max(fmaxf(v0, v1));
  float se = wave_sum(lane < 20 ? __expf(v0 - m2) + __expf(v1 - m2) : 0.f);
  if (lane < 20) {
    float ls = logf(se);
    *(float2*)&out[(size_t)n * NCLS + 2 * cg] = make_float2(v0 - m2 - ls, v1 - m2 - ls);
  }
}

extern "C" void kernel_launch(void* const* d_in, const int* in_sizes, int n_in,
                              void* d_out, int out_size, void* d_ws, size_t ws_size,
                              hipStream_t stream) {
  const float* x   = (const float*)d_in[0];
  const int*   ei  = (const int*)d_in[1];
  const float* W1  = (const float*)d_in[2];
  const float* as1 = (const float*)d_in[3];
  const float* ad1 = (const float*)d_in[4];
  const float* b1  = (const float*)d_in[5];
  const float* W2  = (const float*)d_in[6];
  const float* as2 = (const float*)d_in[7];
  const float* ad2 = (const float*)d_in[8];
  const float* b2  = (const float*)d_in[9];
  float* out = (float*)d_out;

  char* ws = (char*)d_ws;
  size_t off = 0;
  auto alloc = [&](size_t bytes) -> char* {
    char* p = ws + off;
    off += (bytes + 255) & ~(size_t)255;
    return p;
  };
  int* deg      = (int*)alloc((size_t)N_NODES * 4);   // deg+cursor adjacent: one memset
  int* cursor   = (int*)alloc((size_t)N_NODES * 4);
  int* offsets  = (int*)alloc((size_t)(N_NODES + 1) * 4);
  int* edge_src = (int*)alloc((size_t)EP * 4);
  unsigned short* xb    = (unsigned short*)alloc((size_t)MPAD * F_IN * 2);
  unsigned short* wb1t  = (unsigned short*)alloc((size_t)D1 * F_IN * 2);
  unsigned short* wb2t  = (unsigned short*)alloc((size_t)48 * D1 * 2);
  unsigned short* h1b   = (unsigned short*)alloc((size_t)N_NODES * D1 * 2);
  unsigned short* out1b = (unsigned short*)alloc((size_t)MPAD * D1 * 2);
  float* asrc1  = (float*)alloc((size_t)N_NODES * H1 * 4);
  float* adst1  = (float*)alloc((size_t)N_NODES * H1 * 4);
  unsigned int* alphaP = (unsigned int*)alloc((size_t)H1 * EP * 4);
  float* inv1   = (float*)alloc((size_t)N_NODES * H1 * 4);
  float* h2     = (float*)alloc((size_t)N_NODES * NCLS * 4);
  float* asrc2  = (float*)alloc((size_t)N_NODES * 4);
  float* adst2  = (float*)alloc((size_t)N_NODES * 4);

  hipMemsetAsync(deg, 0, (size_t)((char*)offsets - (char*)deg), stream);  // deg + cursor

  prep_kernel<<<PB_CNT, 256, 0, stream>>>(x, W1, W2, ei, xb, wb1t, wb2t, deg, out1b);
  scan_kernel<<<1, SCAN_T, 0, stream>>>(deg, offsets);
  gemm1_mfma<<<G1_BLOCKS + 1329, 256, 0, stream>>>(xb, wb1t, as1, ad1, h1b, asrc1, adst1,
                                                   ei, offsets, cursor, edge_src);
  alpha1_kernel<<<N_NODES / 4, 256, 0, stream>>>(offsets, edge_src, asrc1, adst1, alphaP, inv1);
  agg1_gather<<<(N_NODES / 32) * 8, 256, 0, stream>>>(offsets, alphaP, inv1, h1b, b1, out1b);

  gemm2_mfma<<<MPAD / 64, 256, 0, stream>>>(out1b, wb2t, as2, ad2, h2, asrc2, adst2);
  agg2_kernel<<<N_NODES / 4, 256, 0, stream>>>(offsets, edge_src, asrc2, adst2, h2, b2, out);
}

// Round 19
// 144.564 us; speedup vs baseline: 1.5022x; 1.0095x over previous
//
#include <hip/hip_runtime.h>
#include <hip/hip_bf16.h>
#include <math.h>

#define N_NODES 20000
#define MPAD 20096               // 157*128
#define N_EDGES 320000
#define EP (N_EDGES + N_NODES)   // 340000
#define F_IN 256
#define NHID 64
#define H1 8
#define D1 512
#define NCLS 40
#define NEG_SLOPE 0.2f
#define MAXD 128

typedef __attribute__((ext_vector_type(8))) short bf16x8;
typedef __attribute__((ext_vector_type(4))) float f32x4;
typedef __attribute__((ext_vector_type(2))) float f32x2;

__device__ __forceinline__ float wave_max(float v) {
#pragma unroll
  for (int o = 32; o > 0; o >>= 1) v = fmaxf(v, __shfl_xor(v, o));
  return v;
}
__device__ __forceinline__ float wave_sum(float v) {
#pragma unroll
  for (int o = 32; o > 0; o >>= 1) v += __shfl_xor(v, o);
  return v;
}
__device__ __forceinline__ unsigned short f2bf(float f) {
  union { float f; unsigned int i; } c; c.f = f;
  unsigned int x = c.i;
  return (unsigned short)((x + 0x7fffu + ((x >> 16) & 1u)) >> 16);  // RNE
}
__device__ __forceinline__ float asf(unsigned int u) {
  union { unsigned int i; float f; } c; c.i = u; return c.f;
}
__device__ __forceinline__ float lrelu(float x) { return x > 0.f ? x : NEG_SLOPE * x; }

__device__ __forceinline__ void gload16(const void* g, void* l) {
  __builtin_amdgcn_global_load_lds((const __attribute__((address_space(1))) void*)g,
                                   (__attribute__((address_space(3))) void*)l, 16, 0, 0);
}

// ---------------- fused prep: convert_x | transpose_w1 | transpose_w2 | zero pad | count_deg ----------------
#define PB_CONV 2512             // MPAD*F_IN/8/256
#define PB_TW1  (PB_CONV + 32)
#define PB_TW2  (PB_TW1 + 96)
#define PB_PAD  (PB_TW2 + 24)    // 96*512 bf16 = 6144*16B
#define PB_CNT  (PB_PAD + 1329)  // count_deg over EP edges
__global__ __launch_bounds__(256) void prep_kernel(const float* __restrict__ x,
                                                   const float* __restrict__ W1,
                                                   const float* __restrict__ W2,
                                                   const int* __restrict__ ei,
                                                   unsigned short* __restrict__ xb,
                                                   unsigned short* __restrict__ wb1t,
                                                   unsigned short* __restrict__ wb2t,
                                                   int* __restrict__ deg,
                                                   unsigned short* __restrict__ out1b) {
  __shared__ float tsh[64][65];
  int bid = blockIdx.x;
  int t = threadIdx.x;
  if (bid < PB_CONV) {
    size_t base = ((size_t)bid * 256 + t) * 8;
    int row = (int)(base >> 8);
    ushort4 o0, o1;
    if (row < N_NODES) {
      float4 v0 = *(const float4*)&x[base];
      float4 v1 = *(const float4*)&x[base + 4];
      o0 = make_ushort4(f2bf(v0.x), f2bf(v0.y), f2bf(v0.z), f2bf(v0.w));
      o1 = make_ushort4(f2bf(v1.x), f2bf(v1.y), f2bf(v1.z), f2bf(v1.w));
    } else {
      o0 = make_ushort4(0, 0, 0, 0); o1 = o0;
    }
    *(ushort4*)&xb[base] = o0;
    *(ushort4*)&xb[base + 4] = o1;
  } else if (bid < PB_TW1) {
    int b2 = bid - PB_CONV;
    int bk = b2 & 3, bn = b2 >> 2;
    int tr = t >> 4, tc4 = (t & 15) * 4;
#pragma unroll
    for (int i = 0; i < 4; ++i) {
      int k = i * 16 + tr;
      float4 v = *(const float4*)&W1[(size_t)(bk * 64 + k) * D1 + bn * 64 + tc4];
      tsh[k][tc4] = v.x; tsh[k][tc4 + 1] = v.y; tsh[k][tc4 + 2] = v.z; tsh[k][tc4 + 3] = v.w;
    }
    __syncthreads();
#pragma unroll
    for (int i = 0; i < 4; ++i) {
      int n = i * 16 + tr;
      ushort4 o = make_ushort4(f2bf(tsh[tc4][n]), f2bf(tsh[tc4 + 1][n]),
                               f2bf(tsh[tc4 + 2][n]), f2bf(tsh[tc4 + 3][n]));
      *(ushort4*)&wb1t[(size_t)(bn * 64 + n) * F_IN + bk * 64 + tc4] = o;
    }
  } else if (bid < PB_TW2) {
    int idx = (bid - PB_TW1) * 256 + t;
    int c = idx >> 9, k = idx & 511;
    wb2t[idx] = f2bf((c < NCLS) ? W2[(size_t)k * NCLS + c] : 0.f);
  } else if (bid < PB_PAD) {
    int idx = (bid - PB_TW2) * 256 + t;
    uint4 z = make_uint4(0, 0, 0, 0);
    *(uint4*)((char*)out1b + (size_t)N_NODES * D1 * 2 + (size_t)idx * 16) = z;
  } else {
    int e = (bid - PB_PAD) * 256 + t;
    if (e < EP) {
      int dst = (e < N_EDGES) ? ei[N_EDGES + e] : (e - N_EDGES);
      atomicAdd(&deg[dst], 1);
    }
  }
}

#define SCAN_T 1024
#define SCAN_CHUNK 20
__global__ __launch_bounds__(1024) void scan_kernel(const int* __restrict__ deg,
                                                    int* __restrict__ offsets) {
  __shared__ int wsum[16];
  int t = threadIdx.x;
  int w = t >> 6, lane = t & 63;
  int lo = t * SCAN_CHUNK;
  int hi = min(lo + SCAN_CHUNK, N_NODES);
  int s = 0;
  for (int i = lo; i < hi; ++i) s += deg[i];
  int incl = s;
#pragma unroll
  for (int o = 1; o < 64; o <<= 1) {
    int v = __shfl_up(incl, o);
    if (lane >= o) incl += v;
  }
  if (lane == 63) wsum[w] = incl;
  __syncthreads();
  if (t == 0) {
    int run = 0;
#pragma unroll
    for (int i = 0; i < 16; ++i) { int v = wsum[i]; wsum[i] = run; run += v; }
  }
  __syncthreads();
  int off = wsum[w] + incl - s;
  for (int i = lo; i < hi; ++i) { offsets[i] = off; off += deg[i]; }
  if (hi == N_NODES && lo < N_NODES) offsets[N_NODES] = off;
}

// ---------------- GEMM1 (MFMA) + scatter_edges (block-range merged) ----------------
#define G1_BLOCKS 628            // 157*4
__global__ __launch_bounds__(256) void gemm1_mfma(const unsigned short* __restrict__ xb,
                                                  const unsigned short* __restrict__ wb1t,
                                                  const float* __restrict__ a_src,
                                                  const float* __restrict__ a_dst,
                                                  unsigned short* __restrict__ h1b,
                                                  float* __restrict__ asrc,
                                                  float* __restrict__ adst,
                                                  const int* __restrict__ ei,
                                                  const int* __restrict__ offsets,
                                                  int* __restrict__ cursor,
                                                  int* __restrict__ edge_src) {
  __shared__ unsigned short As[128 * 64];
  __shared__ unsigned short Bs[128 * 64];
  int tid = threadIdx.x;
  if (blockIdx.x >= G1_BLOCKS) {   // scatter_edges range (independent of GEMM work)
    int e = (blockIdx.x - G1_BLOCKS) * 256 + tid;
    if (e < EP) {
      int src, dst;
      if (e < N_EDGES) { src = ei[e]; dst = ei[N_EDGES + e]; }
      else             { src = dst = e - N_EDGES; }
      int pos = offsets[dst] + atomicAdd(&cursor[dst], 1);
      edge_src[pos] = src;
    }
    return;
  }
  int w = tid >> 6, lane = tid & 63;
  int bn = blockIdx.x & 3, bm = blockIdx.x >> 2;
  int row0 = bm * 128, col0 = bn * 128;
  int wr = w >> 1, wc = w & 1;
  int cl = lane & 15, hi = lane >> 4;
  f32x4 acc[4][4] = {};
  for (int k0 = 0; k0 < F_IN; k0 += 64) {
#pragma unroll
    for (int c = 0; c < 4; ++c) {
      int slot = c * 256 + tid;
      int r = slot >> 3;
      int q = (slot & 7) ^ (r & 7);
      gload16(xb + (size_t)(row0 + r) * F_IN + k0 + q * 8, (char*)As + (c * 256 + w * 64) * 16);
      gload16(wb1t + (size_t)(col0 + r) * F_IN + k0 + q * 8, (char*)Bs + (c * 256 + w * 64) * 16);
    }
    __syncthreads();
#pragma unroll
    for (int kk = 0; kk < 2; ++kk) {
      bf16x8 a[4], b[4];
#pragma unroll
      for (int m = 0; m < 4; ++m) {
        int r = wr * 64 + m * 16 + cl;
        a[m] = *(const bf16x8*)&As[r * 64 + ((((kk * 4 + hi)) ^ (r & 7)) << 3)];
      }
#pragma unroll
      for (int n = 0; n < 4; ++n) {
        int r = wc * 64 + n * 16 + cl;
        b[n] = *(const bf16x8*)&Bs[r * 64 + ((((kk * 4 + hi)) ^ (r & 7)) << 3)];
      }
#pragma unroll
      for (int m = 0; m < 4; ++m)
#pragma unroll
        for (int n = 0; n < 4; ++n)
          acc[m][n] = __builtin_amdgcn_mfma_f32_16x16x32_bf16(a[m], b[n], acc[m][n], 0, 0, 0);
    }
    __syncthreads();
  }
  int head = bn * 2 + wc;
  float asv[4], adv[4];
#pragma unroll
  for (int n = 0; n < 4; ++n) {
    asv[n] = a_src[head * 64 + n * 16 + cl];
    adv[n] = a_dst[head * 64 + n * 16 + cl];
  }
#pragma unroll
  for (int m = 0; m < 4; ++m) {
#pragma unroll
    for (int r = 0; r < 4; ++r) {
      int grow = row0 + wr * 64 + m * 16 + hi * 4 + r;
      float ps = acc[m][0][r] * asv[0] + acc[m][1][r] * asv[1] +
                 acc[m][2][r] * asv[2] + acc[m][3][r] * asv[3];
      float pd = acc[m][0][r] * adv[0] + acc[m][1][r] * adv[1] +
                 acc[m][2][r] * adv[2] + acc[m][3][r] * adv[3];
#pragma unroll
      for (int o = 8; o > 0; o >>= 1) { ps += __shfl_xor(ps, o); pd += __shfl_xor(pd, o); }
      if (grow < N_NODES) {
#pragma unroll
        for (int n = 0; n < 4; ++n)
          h1b[(size_t)grow * D1 + col0 + wc * 64 + n * 16 + cl] = f2bf(acc[m][n][r]);
        if (cl == 0) { asrc[grow * H1 + head] = ps; adst[grow * H1 + head] = pd; }
      }
    }
  }
}

// ---------------- alpha1: node-parallel softmax -> PACKED (bf16 alpha | src) head-major + inv ----------------
__global__ __launch_bounds__(256) void alpha1_kernel(const int* __restrict__ offsets,
                                                     const int* __restrict__ edge_src,
                                                     const float* __restrict__ asrc,
                                                     const float* __restrict__ adst,
                                                     unsigned int* __restrict__ alphaP,
                                                     float* __restrict__ inv1) {
  int w = threadIdx.x >> 6, lane = threadIdx.x & 63;
  int n = blockIdx.x * 4 + w;
  int base = offsets[n];
  int deg = offsets[n + 1] - base;
  int h = lane & 7, et = lane >> 3;
  float adv = adst[n * H1 + h];
  float evr[8];
  int   svr[8];
  float m = -INFINITY;
#pragma unroll
  for (int k = 0; k < 8; ++k) {
    int e = et + k * 8;
    float ev = -INFINITY;
    int sv = 0;
    if (e < deg) {
      sv = edge_src[base + e];
      ev = lrelu(asrc[sv * H1 + h] + adv);
    }
    evr[k] = ev; svr[k] = sv;
    m = fmaxf(m, ev);
  }
  for (int e = et + 64; e < deg; e += 8)   // guard, never runs for this graph
    m = fmaxf(m, lrelu(asrc[edge_src[base + e] * H1 + h] + adv));
  m = fmaxf(m, __shfl_xor(m, 8));
  m = fmaxf(m, __shfl_xor(m, 16));
  m = fmaxf(m, __shfl_xor(m, 32));
  float ss = 0.f;
#pragma unroll
  for (int k = 0; k < 8; ++k) {
    int e = et + k * 8;
    if (e < deg) {
      float a = __expf(evr[k] - m);
      alphaP[(size_t)h * EP + base + e] =
          ((unsigned int)f2bf(a) << 16) | (unsigned int)svr[k];
      ss += a;
    }
  }
  for (int e = et + 64; e < deg; e += 8) { // guard
    int sv = edge_src[base + e];
    float a = __expf(lrelu(asrc[sv * H1 + h] + adv) - m);
    alphaP[(size_t)h * EP + base + e] = ((unsigned int)f2bf(a) << 16) | (unsigned int)sv;
    ss += a;
  }
  ss += __shfl_xor(ss, 8);
  ss += __shfl_xor(ss, 16);
  ss += __shfl_xor(ss, 32);
  if (et == 0) inv1[n * H1 + h] = 1.f / (ss + 1e-16f);
}

// ---------------- agg1 gather: head-sliced XCD-affine, packed meta, unroll x4, pk-f32 math ----------------
// bid&7 = head (round-robin block->XCD => per-XCD h1b re-read set = 2.56MB < 4MB L2).
// f32x2 accumulators -> v_pk_fma_f32 (2 FMA/inst) in the unpack-FMA block.
__global__ __launch_bounds__(256) void agg1_gather(const int* __restrict__ offsets,
                                                   const unsigned int* __restrict__ alphaP,
                                                   const float* __restrict__ inv1,
                                                   const unsigned short* __restrict__ h1b,
                                                   const float* __restrict__ b1,
                                                   unsigned short* __restrict__ out1b) {
  int w = threadIdx.x >> 6, lane = threadIdx.x & 63;
  int bid = blockIdx.x;
  int head = bid & 7;
  int ng = bid >> 3;
  int sub = lane >> 3, cl = lane & 7;
  int n = ng * 32 + w * 8 + sub;
  int base = offsets[n];
  int deg = offsets[n + 1] - base;
  const unsigned int* pE = alphaP + (size_t)head * EP + base;
  const char* hb = (const char*)h1b + head * 128 + cl * 16;
  f32x2 accv[4] = {};
  int e = 0;
  for (; e + 3 < deg; e += 4) {
    unsigned int p0 = pE[e], p1 = pE[e + 1], p2 = pE[e + 2], p3 = pE[e + 3];
    uint4 u0 = *(const uint4*)(hb + ((size_t)(p0 & 0xffffu) << 10));
    uint4 u1 = *(const uint4*)(hb + ((size_t)(p1 & 0xffffu) << 10));
    uint4 u2 = *(const uint4*)(hb + ((size_t)(p2 & 0xffffu) << 10));
    uint4 u3 = *(const uint4*)(hb + ((size_t)(p3 & 0xffffu) << 10));
    f32x2 a0 = {asf(p0 & 0xffff0000u), asf(p0 & 0xffff0000u)};
    f32x2 a1 = {asf(p1 & 0xffff0000u), asf(p1 & 0xffff0000u)};
    f32x2 a2 = {asf(p2 & 0xffff0000u), asf(p2 & 0xffff0000u)};
    f32x2 a3 = {asf(p3 & 0xffff0000u), asf(p3 & 0xffff0000u)};
#pragma unroll
    for (int j = 0; j < 4; ++j) {
      unsigned int x0 = ((const unsigned int*)&u0)[j];
      unsigned int x1 = ((const unsigned int*)&u1)[j];
      unsigned int x2 = ((const unsigned int*)&u2)[j];
      unsigned int x3 = ((const unsigned int*)&u3)[j];
      f32x2 h0 = {asf(x0 << 16), asf(x0 & 0xffff0000u)};
      f32x2 h1v = {asf(x1 << 16), asf(x1 & 0xffff0000u)};
      f32x2 h2v = {asf(x2 << 16), asf(x2 & 0xffff0000u)};
      f32x2 h3v = {asf(x3 << 16), asf(x3 & 0xffff0000u)};
      accv[j] += a0 * h0 + a1 * h1v + a2 * h2v + a3 * h3v;
    }
  }
  if (e + 1 < deg) {           // x2 tail
    unsigned int p0 = pE[e], p1 = pE[e + 1];
    uint4 u0 = *(const uint4*)(hb + ((size_t)(p0 & 0xffffu) << 10));
    uint4 u1 = *(const uint4*)(hb + ((size_t)(p1 & 0xffffu) << 10));
    f32x2 a0 = {asf(p0 & 0xffff0000u), asf(p0 & 0xffff0000u)};
    f32x2 a1 = {asf(p1 & 0xffff0000u), asf(p1 & 0xffff0000u)};
#pragma unroll
    for (int j = 0; j < 4; ++j) {
      unsigned int x0 = ((const unsigned int*)&u0)[j];
      unsigned int x1 = ((const unsigned int*)&u1)[j];
      f32x2 h0 = {asf(x0 << 16), asf(x0 & 0xffff0000u)};
      f32x2 h1v = {asf(x1 << 16), asf(x1 & 0xffff0000u)};
      accv[j] += a0 * h0 + a1 * h1v;
    }
    e += 2;
  }
  if (e < deg) {               // x1 tail
    unsigned int p0 = pE[e];
    uint4 uv = *(const uint4*)(hb + ((size_t)(p0 & 0xffffu) << 10));
    f32x2 a0 = {asf(p0 & 0xffff0000u), asf(p0 & 0xffff0000u)};
#pragma unroll
    for (int j = 0; j < 4; ++j) {
      unsigned int u = ((const unsigned int*)&uv)[j];
      f32x2 h0 = {asf(u << 16), asf(u & 0xffff0000u)};
      accv[j] += a0 * h0;
    }
  }
  float inv = inv1[n * H1 + head];
  int c0 = head * NHID + cl * 8;
  float4 b0 = *(const float4*)&b1[c0];
  float4 b4 = *(const float4*)&b1[c0 + 4];
  float v[8];
  v[0] = accv[0].x * inv + b0.x; v[1] = accv[0].y * inv + b0.y;
  v[2] = accv[1].x * inv + b0.z; v[3] = accv[1].y * inv + b0.w;
  v[4] = accv[2].x * inv + b4.x; v[5] = accv[2].y * inv + b4.y;
  v[6] = accv[3].x * inv + b4.z; v[7] = accv[3].y * inv + b4.w;
#pragma unroll
  for (int j = 0; j < 8; ++j) v[j] = v[j] > 0.f ? v[j] : (__expf(v[j]) - 1.f);  // ELU
  ushort4 o0 = make_ushort4(f2bf(v[0]), f2bf(v[1]), f2bf(v[2]), f2bf(v[3]));
  ushort4 o1 = make_ushort4(f2bf(v[4]), f2bf(v[5]), f2bf(v[6]), f2bf(v[7]));
  *(ushort4*)&out1b[(size_t)n * D1 + c0] = o0;
  *(ushort4*)&out1b[(size_t)n * D1 + c0 + 4] = o1;
}

// ---------------- GEMM2 (MFMA): h2(f32) = out1b @ W2 (+pad), fused alpha2 ----------------
__global__ __launch_bounds__(256) void gemm2_mfma(const unsigned short* __restrict__ ab,
                                                  const unsigned short* __restrict__ wb2t,
                                                  const float* __restrict__ a_src2,
                                                  const float* __restrict__ a_dst2,
                                                  float* __restrict__ h2,
                                                  float* __restrict__ asrc,
                                                  float* __restrict__ adst) {
  __shared__ unsigned short As[64 * 64];
  __shared__ unsigned short Bs[48 * 64];
  int tid = threadIdx.x;
  int w = tid >> 6, lane = tid & 63;
  int row0 = blockIdx.x * 64;
  int cl = lane & 15, hi = lane >> 4;
  f32x4 acc[3] = {};
  for (int k0 = 0; k0 < D1; k0 += 64) {
#pragma unroll
    for (int c = 0; c < 2; ++c) {
      int slot = c * 256 + tid;
      int r = slot >> 3;
      int q = (slot & 7) ^ (r & 7);
      gload16(ab + (size_t)(row0 + r) * D1 + k0 + q * 8, (char*)As + (c * 256 + w * 64) * 16);
    }
    {
      int r = tid >> 3;
      int q = (tid & 7) ^ (r & 7);
      gload16(wb2t + (size_t)r * D1 + k0 + q * 8, (char*)Bs + (w * 64) * 16);
      if (tid < 128) {
        int slot2 = 256 + tid;
        int r2 = slot2 >> 3;
        int q2 = (slot2 & 7) ^ (r2 & 7);
        gload16(wb2t + (size_t)r2 * D1 + k0 + q2 * 8, (char*)Bs + ((256 + w * 64)) * 16);
      }
    }
    __syncthreads();
#pragma unroll
    for (int kk = 0; kk < 2; ++kk) {
      int ra = w * 16 + cl;
      bf16x8 a = *(const bf16x8*)&As[ra * 64 + (((kk * 4 + hi) ^ (ra & 7)) << 3)];
#pragma unroll
      for (int n = 0; n < 3; ++n) {
        int rb = n * 16 + cl;
        bf16x8 b = *(const bf16x8*)&Bs[rb * 64 + (((kk * 4 + hi) ^ (rb & 7)) << 3)];
        acc[n] = __builtin_amdgcn_mfma_f32_16x16x32_bf16(a, b, acc[n], 0, 0, 0);
      }
    }
    __syncthreads();
  }
  float asv[3], adv[3];
#pragma unroll
  for (int n = 0; n < 3; ++n) {
    int c = n * 16 + cl;
    asv[n] = (c < NCLS) ? a_src2[c] : 0.f;
    adv[n] = (c < NCLS) ? a_dst2[c] : 0.f;
  }
#pragma unroll
  for (int r = 0; r < 4; ++r) {
    int grow = row0 + w * 16 + hi * 4 + r;
    float ps = acc[0][r] * asv[0] + acc[1][r] * asv[1] + acc[2][r] * asv[2];
    float pd = acc[0][r] * adv[0] + acc[1][r] * adv[1] + acc[2][r] * adv[2];
#pragma unroll
    for (int o = 8; o > 0; o >>= 1) { ps += __shfl_xor(ps, o); pd += __shfl_xor(pd, o); }
    if (grow < N_NODES) {
#pragma unroll
      for (int n = 0; n < 3; ++n) {
        int c = n * 16 + cl;
        if (c < NCLS) h2[(size_t)grow * NCLS + c] = acc[n][r];
      }
      if (cl == 0) { asrc[grow] = ps; adst[grow] = pd; }
    }
  }
}

// ---------------- agg2: LDS alpha + f32x2 gather (6 edges/iter, pk-f32) + b2 + log_softmax ----------------
__global__ __launch_bounds__(256) void agg2_kernel(const int* __restrict__ offsets,
                                                   const int* __restrict__ edge_src,
                                                   const float* __restrict__ asrc,
                                                   const float* __restrict__ adst,
                                                   const float* __restrict__ h2,
                                                   const float* __restrict__ b2,
                                                   float* __restrict__ out) {
  __shared__ float lalpha[4][MAXD + 8];
  __shared__ int   lsoff[4][MAXD + 8];
  int w = threadIdx.x >> 6;
  int lane = threadIdx.x & 63;
  int n = blockIdx.x * 4 + w;
  int base = offsets[n];
  int deg = offsets[n + 1] - base;
  int degc = min(deg, MAXD);
  int degp = ((degc + 5) / 6) * 6;

  float advv = adst[n];
  float m = -INFINITY;
  for (int e = lane; e < deg; e += 64) {
    int s = edge_src[base + e];
    float ev = lrelu(asrc[s] + advv);
    if (e < MAXD) { lsoff[w][e] = s * (NCLS * 4); lalpha[w][e] = ev; }
    m = fmaxf(m, ev);
  }
  m = wave_max(m);
  float ssum = 0.f;
  for (int e = lane; e < deg; e += 64) {
    float ev;
    if (e < MAXD) ev = lalpha[w][e];
    else { int s = edge_src[base + e]; ev = lrelu(asrc[s] + advv); }
    ssum += __expf(ev - m);
  }
  float inv = 1.f / (wave_sum(ssum) + 1e-16f);
  for (int e = lane; e < degc; e += 64) lalpha[w][e] = __expf(lalpha[w][e] - m) * inv;
  {
    int e = degc + lane;
    if (e < degp) { lalpha[w][e] = 0.f; lsoff[w][e] = 0; }
  }
  __builtin_amdgcn_wave_barrier();

  int esub = lane / 20;
  int cg = lane - esub * 20;
  bool act = esub < 3;
  f32x2 axy = {0.f, 0.f};
  const char* hb = (const char*)h2 + cg * 8;
  for (int i = 0; i < degp; i += 6) {
    if (act) {
      int sA = i + esub, sB = i + 3 + esub;
      float aA = lalpha[w][sA], aB = lalpha[w][sB];
      int oA = lsoff[w][sA], oB = lsoff[w][sB];
      float2 hA = *(const float2*)(hb + oA);
      float2 hB = *(const float2*)(hb + oB);
      f32x2 vA = {hA.x, hA.y}, vB = {hB.x, hB.y};
      f32x2 aA2 = {aA, aA}, aB2 = {aB, aB};
      axy += aA2 * vA + aB2 * vB;
    }
  }
  for (int e = MAXD + esub; e < deg; e += 3) {   // guard, never runs
    if (act) {
      int s = edge_src[base + e];
      float a = __expf(lrelu(asrc[s] + advv) - m) * inv;
      float2 hv = *(const float2*)(hb + (size_t)s * (NCLS * 4));
      axy.x += a * hv.x; axy.y += a * hv.y;
    }
  }
  float ax = axy.x, ay = axy.y;
  float ax1 = __shfl(ax, lane + 20), ax2 = __shfl(ax, lane + 40);
  float ay1 = __shfl(ay, lane + 20), ay2 = __shfl(ay, lane + 40);
  float v0 = -INFINITY, v1 = -INFINITY;
  if (lane < 20) {
    v0 = ax + ax1 + ax2 + b2[2 * cg];
    v1 = ay + ay1 + ay2 + b2[2 * cg + 1];
  }
  float m2 = wave_max(fmaxf(v0, v1));
  float se = wave_sum(lane < 20 ? __expf(v0 - m2) + __expf(v1 - m2) : 0.f);
  if (lane < 20) {
    float ls = logf(se);
    *(float2*)&out[(size_t)n * NCLS + 2 * cg] = make_float2(v0 - m2 - ls, v1 - m2 - ls);
  }
}

extern "C" void kernel_launch(void* const* d_in, const int* in_sizes, int n_in,
                              void* d_out, int out_size, void* d_ws, size_t ws_size,
                              hipStream_t stream) {
  const float* x   = (const float*)d_in[0];
  const int*   ei  = (const int*)d_in[1];
  const float* W1  = (const float*)d_in[2];
  const float* as1 = (const float*)d_in[3];
  const float* ad1 = (const float*)d_in[4];
  const float* b1  = (const float*)d_in[5];
  const float* W2  = (const float*)d_in[6];
  const float* as2 = (const float*)d_in[7];
  const float* ad2 = (const float*)d_in[8];
  const float* b2  = (const float*)d_in[9];
  float* out = (float*)d_out;

  char* ws = (char*)d_ws;
  size_t off = 0;
  auto alloc = [&](size_t bytes) -> char* {
    char* p = ws + off;
    off += (bytes + 255) & ~(size_t)255;
    return p;
  };
  int* deg      = (int*)alloc((size_t)N_NODES * 4);   // deg+cursor adjacent: one memset
  int* cursor   = (int*)alloc((size_t)N_NODES * 4);
  int* offsets  = (int*)alloc((size_t)(N_NODES + 1) * 4);
  int* edge_src = (int*)alloc((size_t)EP * 4);
  unsigned short* xb    = (unsigned short*)alloc((size_t)MPAD * F_IN * 2);
  unsigned short* wb1t  = (unsigned short*)alloc((size_t)D1 * F_IN * 2);
  unsigned short* wb2t  = (unsigned short*)alloc((size_t)48 * D1 * 2);
  unsigned short* h1b   = (unsigned short*)alloc((size_t)N_NODES * D1 * 2);
  unsigned short* out1b = (unsigned short*)alloc((size_t)MPAD * D1 * 2);
  float* asrc1  = (float*)alloc((size_t)N_NODES * H1 * 4);
  float* adst1  = (float*)alloc((size_t)N_NODES * H1 * 4);
  unsigned int* alphaP = (unsigned int*)alloc((size_t)H1 * EP * 4);
  float* inv1   = (float*)alloc((size_t)N_NODES * H1 * 4);
  float* h2     = (float*)alloc((size_t)N_NODES * NCLS * 4);
  float* asrc2  = (float*)alloc((size_t)N_NODES * 4);
  float* adst2  = (float*)alloc((size_t)N_NODES * 4);

  hipMemsetAsync(deg, 0, (size_t)((char*)offsets - (char*)deg), stream);  // deg + cursor

  prep_kernel<<<PB_CNT, 256, 0, stream>>>(x, W1, W2, ei, xb, wb1t, wb2t, deg, out1b);
  scan_kernel<<<1, SCAN_T, 0, stream>>>(deg, offsets);
  gemm1_mfma<<<G1_BLOCKS + 1329, 256, 0, stream>>>(xb, wb1t, as1, ad1, h1b, asrc1, adst1,
                                                   ei, offsets, cursor, edge_src);
  alpha1_kernel<<<N_NODES / 4, 256, 0, stream>>>(offsets, edge_src, asrc1, adst1, alphaP, inv1);
  agg1_gather<<<(N_NODES / 32) * 8, 256, 0, stream>>>(offsets, alphaP, inv1, h1b, b1, out1b);

  gemm2_mfma<<<MPAD / 64, 256, 0, stream>>>(out1b, wb2t, as2, ad2, h2, asrc2, adst2);
  agg2_kernel<<<N_NODES / 4, 256, 0, stream>>>(offsets, edge_src, asrc2, adst2, h2, b2, out);
}

// Round 20
// 141.845 us; speedup vs baseline: 1.5310x; 1.0192x over previous
//
#include <hip/hip_runtime.h>
#include <hip/hip_bf16.h>
#include <math.h>

#define N_NODES 20000
#define MPAD 20096               // 157*128
#define N_EDGES 320000
#define EP (N_EDGES + N_NODES)   // 340000
#define F_IN 256
#define NHID 64
#define H1 8
#define D1 512
#define NCLS 40
#define NEG_SLOPE 0.2f
#define MAXD 128

typedef __attribute__((ext_vector_type(8))) short bf16x8;
typedef __attribute__((ext_vector_type(4))) float f32x4;
typedef __attribute__((ext_vector_type(2))) float f32x2;

__device__ __forceinline__ float wave_max(float v) {
#pragma unroll
  for (int o = 32; o > 0; o >>= 1) v = fmaxf(v, __shfl_xor(v, o));
  return v;
}
__device__ __forceinline__ float wave_sum(float v) {
#pragma unroll
  for (int o = 32; o > 0; o >>= 1) v += __shfl_xor(v, o);
  return v;
}
__device__ __forceinline__ unsigned short f2bf(float f) {
  union { float f; unsigned int i; } c; c.f = f;
  unsigned int x = c.i;
  return (unsigned short)((x + 0x7fffu + ((x >> 16) & 1u)) >> 16);  // RNE
}
__device__ __forceinline__ float asf(unsigned int u) {
  union { unsigned int i; float f; } c; c.i = u; return c.f;
}
__device__ __forceinline__ float lrelu(float x) { return x > 0.f ? x : NEG_SLOPE * x; }

__device__ __forceinline__ void gload16(const void* g, void* l) {
  __builtin_amdgcn_global_load_lds((const __attribute__((address_space(1))) void*)g,
                                   (__attribute__((address_space(3))) void*)l, 16, 0, 0);
}

// ---------------- fused prep: convert_x | transpose_w1 | transpose_w2 | zero pad | count_deg ----------------
#define PB_CONV 2512             // MPAD*F_IN/8/256
#define PB_TW1  (PB_CONV + 32)
#define PB_TW2  (PB_TW1 + 96)
#define PB_PAD  (PB_TW2 + 24)    // 96*512 bf16 = 6144*16B
#define PB_CNT  (PB_PAD + 1329)  // count_deg over EP edges
__global__ __launch_bounds__(256) void prep_kernel(const float* __restrict__ x,
                                                   const float* __restrict__ W1,
                                                   const float* __restrict__ W2,
                                                   const int* __restrict__ ei,
                                                   unsigned short* __restrict__ xb,
                                                   unsigned short* __restrict__ wb1t,
                                                   unsigned short* __restrict__ wb2t,
                                                   int* __restrict__ deg,
                                                   unsigned short* __restrict__ out1b) {
  __shared__ float tsh[64][65];
  int bid = blockIdx.x;
  int t = threadIdx.x;
  if (bid < PB_CONV) {
    size_t base = ((size_t)bid * 256 + t) * 8;
    int row = (int)(base >> 8);
    ushort4 o0, o1;
    if (row < N_NODES) {
      float4 v0 = *(const float4*)&x[base];
      float4 v1 = *(const float4*)&x[base + 4];
      o0 = make_ushort4(f2bf(v0.x), f2bf(v0.y), f2bf(v0.z), f2bf(v0.w));
      o1 = make_ushort4(f2bf(v1.x), f2bf(v1.y), f2bf(v1.z), f2bf(v1.w));
    } else {
      o0 = make_ushort4(0, 0, 0, 0); o1 = o0;
    }
    *(ushort4*)&xb[base] = o0;
    *(ushort4*)&xb[base + 4] = o1;
  } else if (bid < PB_TW1) {
    int b2 = bid - PB_CONV;
    int bk = b2 & 3, bn = b2 >> 2;
    int tr = t >> 4, tc4 = (t & 15) * 4;
#pragma unroll
    for (int i = 0; i < 4; ++i) {
      int k = i * 16 + tr;
      float4 v = *(const float4*)&W1[(size_t)(bk * 64 + k) * D1 + bn * 64 + tc4];
      tsh[k][tc4] = v.x; tsh[k][tc4 + 1] = v.y; tsh[k][tc4 + 2] = v.z; tsh[k][tc4 + 3] = v.w;
    }
    __syncthreads();
#pragma unroll
    for (int i = 0; i < 4; ++i) {
      int n = i * 16 + tr;
      ushort4 o = make_ushort4(f2bf(tsh[tc4][n]), f2bf(tsh[tc4 + 1][n]),
                               f2bf(tsh[tc4 + 2][n]), f2bf(tsh[tc4 + 3][n]));
      *(ushort4*)&wb1t[(size_t)(bn * 64 + n) * F_IN + bk * 64 + tc4] = o;
    }
  } else if (bid < PB_TW2) {
    int idx = (bid - PB_TW1) * 256 + t;
    int c = idx >> 9, k = idx & 511;
    wb2t[idx] = f2bf((c < NCLS) ? W2[(size_t)k * NCLS + c] : 0.f);
  } else if (bid < PB_PAD) {
    int idx = (bid - PB_TW2) * 256 + t;
    uint4 z = make_uint4(0, 0, 0, 0);
    *(uint4*)((char*)out1b + (size_t)N_NODES * D1 * 2 + (size_t)idx * 16) = z;
  } else {
    int e = (bid - PB_PAD) * 256 + t;
    if (e < EP) {
      int dst = (e < N_EDGES) ? ei[N_EDGES + e] : (e - N_EDGES);
      atomicAdd(&deg[dst], 1);
    }
  }
}

#define SCAN_T 1024
#define SCAN_CHUNK 20
__global__ __launch_bounds__(1024) void scan_kernel(const int* __restrict__ deg,
                                                    int* __restrict__ offsets) {
  __shared__ int wsum[16];
  int t = threadIdx.x;
  int w = t >> 6, lane = t & 63;
  int lo = t * SCAN_CHUNK;
  int hi = min(lo + SCAN_CHUNK, N_NODES);
  int s = 0;
  for (int i = lo; i < hi; ++i) s += deg[i];
  int incl = s;
#pragma unroll
  for (int o = 1; o < 64; o <<= 1) {
    int v = __shfl_up(incl, o);
    if (lane >= o) incl += v;
  }
  if (lane == 63) wsum[w] = incl;
  __syncthreads();
  if (t == 0) {
    int run = 0;
#pragma unroll
    for (int i = 0; i < 16; ++i) { int v = wsum[i]; wsum[i] = run; run += v; }
  }
  __syncthreads();
  int off = wsum[w] + incl - s;
  for (int i = lo; i < hi; ++i) { offsets[i] = off; off += deg[i]; }
  if (hi == N_NODES && lo < N_NODES) offsets[N_NODES] = off;
}

// ---------------- GEMM1 (MFMA) + scatter_edges (block-range merged) ----------------
#define G1_BLOCKS 628            // 157*4
__global__ __launch_bounds__(256) void gemm1_mfma(const unsigned short* __restrict__ xb,
                                                  const unsigned short* __restrict__ wb1t,
                                                  const float* __restrict__ a_src,
                                                  const float* __restrict__ a_dst,
                                                  unsigned short* __restrict__ h1b,
                                                  float* __restrict__ asrc,
                                                  float* __restrict__ adst,
                                                  const int* __restrict__ ei,
                                                  const int* __restrict__ offsets,
                                                  int* __restrict__ cursor,
                                                  int* __restrict__ edge_src) {
  __shared__ unsigned short As[128 * 64];
  __shared__ unsigned short Bs[128 * 64];
  int tid = threadIdx.x;
  if (blockIdx.x >= G1_BLOCKS) {   // scatter_edges range (independent of GEMM work)
    int e = (blockIdx.x - G1_BLOCKS) * 256 + tid;
    if (e < EP) {
      int src, dst;
      if (e < N_EDGES) { src = ei[e]; dst = ei[N_EDGES + e]; }
      else             { src = dst = e - N_EDGES; }
      int pos = offsets[dst] + atomicAdd(&cursor[dst], 1);
      edge_src[pos] = src;
    }
    return;
  }
  int w = tid >> 6, lane = tid & 63;
  int bn = blockIdx.x & 3, bm = blockIdx.x >> 2;
  int row0 = bm * 128, col0 = bn * 128;
  int wr = w >> 1, wc = w & 1;
  int cl = lane & 15, hi = lane >> 4;
  f32x4 acc[4][4] = {};
  for (int k0 = 0; k0 < F_IN; k0 += 64) {
#pragma unroll
    for (int c = 0; c < 4; ++c) {
      int slot = c * 256 + tid;
      int r = slot >> 3;
      int q = (slot & 7) ^ (r & 7);
      gload16(xb + (size_t)(row0 + r) * F_IN + k0 + q * 8, (char*)As + (c * 256 + w * 64) * 16);
      gload16(wb1t + (size_t)(col0 + r) * F_IN + k0 + q * 8, (char*)Bs + (c * 256 + w * 64) * 16);
    }
    __syncthreads();
#pragma unroll
    for (int kk = 0; kk < 2; ++kk) {
      bf16x8 a[4], b[4];
#pragma unroll
      for (int m = 0; m < 4; ++m) {
        int r = wr * 64 + m * 16 + cl;
        a[m] = *(const bf16x8*)&As[r * 64 + ((((kk * 4 + hi)) ^ (r & 7)) << 3)];
      }
#pragma unroll
      for (int n = 0; n < 4; ++n) {
        int r = wc * 64 + n * 16 + cl;
        b[n] = *(const bf16x8*)&Bs[r * 64 + ((((kk * 4 + hi)) ^ (r & 7)) << 3)];
      }
#pragma unroll
      for (int m = 0; m < 4; ++m)
#pragma unroll
        for (int n = 0; n < 4; ++n)
          acc[m][n] = __builtin_amdgcn_mfma_f32_16x16x32_bf16(a[m], b[n], acc[m][n], 0, 0, 0);
    }
    __syncthreads();
  }
  int head = bn * 2 + wc;
  float asv[4], adv[4];
#pragma unroll
  for (int n = 0; n < 4; ++n) {
    asv[n] = a_src[head * 64 + n * 16 + cl];
    adv[n] = a_dst[head * 64 + n * 16 + cl];
  }
#pragma unroll
  for (int m = 0; m < 4; ++m) {
#pragma unroll
    for (int r = 0; r < 4; ++r) {
      int grow = row0 + wr * 64 + m * 16 + hi * 4 + r;
      float ps = acc[m][0][r] * asv[0] + acc[m][1][r] * asv[1] +
                 acc[m][2][r] * asv[2] + acc[m][3][r] * asv[3];
      float pd = acc[m][0][r] * adv[0] + acc[m][1][r] * adv[1] +
                 acc[m][2][r] * adv[2] + acc[m][3][r] * adv[3];
#pragma unroll
      for (int o = 8; o > 0; o >>= 1) { ps += __shfl_xor(ps, o); pd += __shfl_xor(pd, o); }
      if (grow < N_NODES) {
#pragma unroll
        for (int n = 0; n < 4; ++n)
          h1b[(size_t)grow * D1 + col0 + wc * 64 + n * 16 + cl] = f2bf(acc[m][n][r]);
        if (cl == 0) { asrc[grow * H1 + head] = ps; adst[grow * H1 + head] = pd; }
      }
    }
  }
}

// ---------------- alpha1: node-parallel softmax -> PACKED (bf16 alpha | src) head-major + inv ----------------
__global__ __launch_bounds__(256) void alpha1_kernel(const int* __restrict__ offsets,
                                                     const int* __restrict__ edge_src,
                                                     const float* __restrict__ asrc,
                                                     const float* __restrict__ adst,
                                                     unsigned int* __restrict__ alphaP,
                                                     float* __restrict__ inv1) {
  int w = threadIdx.x >> 6, lane = threadIdx.x & 63;
  int n = blockIdx.x * 4 + w;
  int base = offsets[n];
  int deg = offsets[n + 1] - base;
  int h = lane & 7, et = lane >> 3;
  float adv = adst[n * H1 + h];
  float evr[8];
  int   svr[8];
  float m = -INFINITY;
#pragma unroll
  for (int k = 0; k < 8; ++k) {
    int e = et + k * 8;
    float ev = -INFINITY;
    int sv = 0;
    if (e < deg) {
      sv = edge_src[base + e];
      ev = lrelu(asrc[sv * H1 + h] + adv);
    }
    evr[k] = ev; svr[k] = sv;
    m = fmaxf(m, ev);
  }
  for (int e = et + 64; e < deg; e += 8)   // guard, never runs for this graph
    m = fmaxf(m, lrelu(asrc[edge_src[base + e] * H1 + h] + adv));
  m = fmaxf(m, __shfl_xor(m, 8));
  m = fmaxf(m, __shfl_xor(m, 16));
  m = fmaxf(m, __shfl_xor(m, 32));
  float ss = 0.f;
#pragma unroll
  for (int k = 0; k < 8; ++k) {
    int e = et + k * 8;
    if (e < deg) {
      float a = __expf(evr[k] - m);
      alphaP[(size_t)h * EP + base + e] =
          ((unsigned int)f2bf(a) << 16) | (unsigned int)svr[k];
      ss += a;
    }
  }
  for (int e = et + 64; e < deg; e += 8) { // guard
    int sv = edge_src[base + e];
    float a = __expf(lrelu(asrc[sv * H1 + h] + adv) - m);
    alphaP[(size_t)h * EP + base + e] = ((unsigned int)f2bf(a) << 16) | (unsigned int)sv;
    ss += a;
  }
  ss += __shfl_xor(ss, 8);
  ss += __shfl_xor(ss, 16);
  ss += __shfl_xor(ss, 32);
  if (et == 0) inv1[n * H1 + h] = 1.f / (ss + 1e-16f);
}

// ---------------- agg1 gather: head-sliced XCD-affine, packed meta, x4 + meta prefetch pipeline ----------------
// bid&7 = head (round-robin block->XCD => per-XCD h1b re-read set = 2.56MB < 4MB L2).
// 2-stage pipeline: meta for iter i+1 loads during iter i's FMAs -> row loads never wait on meta.
__global__ __launch_bounds__(256) void agg1_gather(const int* __restrict__ offsets,
                                                   const unsigned int* __restrict__ alphaP,
                                                   const float* __restrict__ inv1,
                                                   const unsigned short* __restrict__ h1b,
                                                   const float* __restrict__ b1,
                                                   unsigned short* __restrict__ out1b) {
  int w = threadIdx.x >> 6, lane = threadIdx.x & 63;
  int bid = blockIdx.x;
  int head = bid & 7;
  int ng = bid >> 3;
  int sub = lane >> 3, cl = lane & 7;
  int n = ng * 32 + w * 8 + sub;
  int base = offsets[n];
  int deg = offsets[n + 1] - base;
  const unsigned int* pE = alphaP + (size_t)head * EP + base;
  const char* hb = (const char*)h1b + head * 128 + cl * 16;
  float inv = inv1[n * H1 + head];        // hoisted: latency hidden under the loop
  f32x2 accv[4] = {};
  unsigned int c0 = 0, c1 = 0, c2 = 0, c3 = 0;
  if (deg >= 4) { c0 = pE[0]; c1 = pE[1]; c2 = pE[2]; c3 = pE[3]; }
  int e = 0;
  for (; e + 3 < deg; e += 4) {
    // rows for current meta (meta already resident from previous iteration)
    uint4 u0 = *(const uint4*)(hb + ((size_t)(c0 & 0xffffu) << 10));
    uint4 u1 = *(const uint4*)(hb + ((size_t)(c1 & 0xffffu) << 10));
    uint4 u2 = *(const uint4*)(hb + ((size_t)(c2 & 0xffffu) << 10));
    uint4 u3 = *(const uint4*)(hb + ((size_t)(c3 & 0xffffu) << 10));
    // prefetch next iteration's meta (overlaps row latency + FMAs)
    unsigned int n0 = 0, n1 = 0, n2 = 0, n3 = 0;
    bool more = (e + 7 < deg);
    if (more) { n0 = pE[e + 4]; n1 = pE[e + 5]; n2 = pE[e + 6]; n3 = pE[e + 7]; }
    f32x2 a0 = {asf(c0 & 0xffff0000u), asf(c0 & 0xffff0000u)};
    f32x2 a1 = {asf(c1 & 0xffff0000u), asf(c1 & 0xffff0000u)};
    f32x2 a2 = {asf(c2 & 0xffff0000u), asf(c2 & 0xffff0000u)};
    f32x2 a3 = {asf(c3 & 0xffff0000u), asf(c3 & 0xffff0000u)};
#pragma unroll
    for (int j = 0; j < 4; ++j) {
      unsigned int x0 = ((const unsigned int*)&u0)[j];
      unsigned int x1 = ((const unsigned int*)&u1)[j];
      unsigned int x2 = ((const unsigned int*)&u2)[j];
      unsigned int x3 = ((const unsigned int*)&u3)[j];
      f32x2 h0 = {asf(x0 << 16), asf(x0 & 0xffff0000u)};
      f32x2 h1v = {asf(x1 << 16), asf(x1 & 0xffff0000u)};
      f32x2 h2v = {asf(x2 << 16), asf(x2 & 0xffff0000u)};
      f32x2 h3v = {asf(x3 << 16), asf(x3 & 0xffff0000u)};
      accv[j] += a0 * h0 + a1 * h1v + a2 * h2v + a3 * h3v;
    }
    c0 = n0; c1 = n1; c2 = n2; c3 = n3;
  }
  if (e + 1 < deg) {           // x2 tail
    unsigned int p0 = pE[e], p1 = pE[e + 1];
    uint4 u0 = *(const uint4*)(hb + ((size_t)(p0 & 0xffffu) << 10));
    uint4 u1 = *(const uint4*)(hb + ((size_t)(p1 & 0xffffu) << 10));
    f32x2 a0 = {asf(p0 & 0xffff0000u), asf(p0 & 0xffff0000u)};
    f32x2 a1 = {asf(p1 & 0xffff0000u), asf(p1 & 0xffff0000u)};
#pragma unroll
    for (int j = 0; j < 4; ++j) {
      unsigned int x0 = ((const unsigned int*)&u0)[j];
      unsigned int x1 = ((const unsigned int*)&u1)[j];
      f32x2 h0 = {asf(x0 << 16), asf(x0 & 0xffff0000u)};
      f32x2 h1v = {asf(x1 << 16), asf(x1 & 0xffff0000u)};
      accv[j] += a0 * h0 + a1 * h1v;
    }
    e += 2;
  }
  if (e < deg) {               // x1 tail
    unsigned int p0 = pE[e];
    uint4 uv = *(const uint4*)(hb + ((size_t)(p0 & 0xffffu) << 10));
    f32x2 a0 = {asf(p0 & 0xffff0000u), asf(p0 & 0xffff0000u)};
#pragma unroll
    for (int j = 0; j < 4; ++j) {
      unsigned int u = ((const unsigned int*)&uv)[j];
      f32x2 h0 = {asf(u << 16), asf(u & 0xffff0000u)};
      accv[j] += a0 * h0;
    }
  }
  int c0i = head * NHID + cl * 8;
  float4 b0 = *(const float4*)&b1[c0i];
  float4 b4 = *(const float4*)&b1[c0i + 4];
  float v[8];
  v[0] = accv[0].x * inv + b0.x; v[1] = accv[0].y * inv + b0.y;
  v[2] = accv[1].x * inv + b0.z; v[3] = accv[1].y * inv + b0.w;
  v[4] = accv[2].x * inv + b4.x; v[5] = accv[2].y * inv + b4.y;
  v[6] = accv[3].x * inv + b4.z; v[7] = accv[3].y * inv + b4.w;
#pragma unroll
  for (int j = 0; j < 8; ++j) v[j] = v[j] > 0.f ? v[j] : (__expf(v[j]) - 1.f);  // ELU
  ushort4 o0 = make_ushort4(f2bf(v[0]), f2bf(v[1]), f2bf(v[2]), f2bf(v[3]));
  ushort4 o1 = make_ushort4(f2bf(v[4]), f2bf(v[5]), f2bf(v[6]), f2bf(v[7]));
  *(ushort4*)&out1b[(size_t)n * D1 + c0i] = o0;
  *(ushort4*)&out1b[(size_t)n * D1 + c0i + 4] = o1;
}

// ---------------- GEMM2 (MFMA): h2(f32) = out1b @ W2 (+pad), fused alpha2 ----------------
__global__ __launch_bounds__(256) void gemm2_mfma(const unsigned short* __restrict__ ab,
                                                  const unsigned short* __restrict__ wb2t,
                                                  const float* __restrict__ a_src2,
                                                  const float* __restrict__ a_dst2,
                                                  float* __restrict__ h2,
                                                  float* __restrict__ asrc,
                                                  float* __restrict__ adst) {
  __shared__ unsigned short As[64 * 64];
  __shared__ unsigned short Bs[48 * 64];
  int tid = threadIdx.x;
  int w = tid >> 6, lane = tid & 63;
  int row0 = blockIdx.x * 64;
  int cl = lane & 15, hi = lane >> 4;
  f32x4 acc[3] = {};
  for (int k0 = 0; k0 < D1; k0 += 64) {
#pragma unroll
    for (int c = 0; c < 2; ++c) {
      int slot = c * 256 + tid;
      int r = slot >> 3;
      int q = (slot & 7) ^ (r & 7);
      gload16(ab + (size_t)(row0 + r) * D1 + k0 + q * 8, (char*)As + (c * 256 + w * 64) * 16);
    }
    {
      int r = tid >> 3;
      int q = (tid & 7) ^ (r & 7);
      gload16(wb2t + (size_t)r * D1 + k0 + q * 8, (char*)Bs + (w * 64) * 16);
      if (tid < 128) {
        int slot2 = 256 + tid;
        int r2 = slot2 >> 3;
        int q2 = (slot2 & 7) ^ (r2 & 7);
        gload16(wb2t + (size_t)r2 * D1 + k0 + q2 * 8, (char*)Bs + ((256 + w * 64)) * 16);
      }
    }
    __syncthreads();
#pragma unroll
    for (int kk = 0; kk < 2; ++kk) {
      int ra = w * 16 + cl;
      bf16x8 a = *(const bf16x8*)&As[ra * 64 + (((kk * 4 + hi) ^ (ra & 7)) << 3)];
#pragma unroll
      for (int n = 0; n < 3; ++n) {
        int rb = n * 16 + cl;
        bf16x8 b = *(const bf16x8*)&Bs[rb * 64 + (((kk * 4 + hi) ^ (rb & 7)) << 3)];
        acc[n] = __builtin_amdgcn_mfma_f32_16x16x32_bf16(a, b, acc[n], 0, 0, 0);
      }
    }
    __syncthreads();
  }
  float asv[3], adv[3];
#pragma unroll
  for (int n = 0; n < 3; ++n) {
    int c = n * 16 + cl;
    asv[n] = (c < NCLS) ? a_src2[c] : 0.f;
    adv[n] = (c < NCLS) ? a_dst2[c] : 0.f;
  }
#pragma unroll
  for (int r = 0; r < 4; ++r) {
    int grow = row0 + w * 16 + hi * 4 + r;
    float ps = acc[0][r] * asv[0] + acc[1][r] * asv[1] + acc[2][r] * asv[2];
    float pd = acc[0][r] * adv[0] + acc[1][r] * adv[1] + acc[2][r] * adv[2];
#pragma unroll
    for (int o = 8; o > 0; o >>= 1) { ps += __shfl_xor(ps, o); pd += __shfl_xor(pd, o); }
    if (grow < N_NODES) {
#pragma unroll
      for (int n = 0; n < 3; ++n) {
        int c = n * 16 + cl;
        if (c < NCLS) h2[(size_t)grow * NCLS + c] = acc[n][r];
      }
      if (cl == 0) { asrc[grow] = ps; adst[grow] = pd; }
    }
  }
}

// ---------------- agg2: LDS alpha + f32x2 gather (6 edges/iter, pk-f32) + b2 + log_softmax ----------------
__global__ __launch_bounds__(256) void agg2_kernel(const int* __restrict__ offsets,
                                                   const int* __restrict__ edge_src,
                                                   const float* __restrict__ asrc,
                                                   const float* __restrict__ adst,
                                                   const float* __restrict__ h2,
                                                   const float* __restrict__ b2,
                                                   float* __restrict__ out) {
  __shared__ float lalpha[4][MAXD + 8];
  __shared__ int   lsoff[4][MAXD + 8];
  int w = threadIdx.x >> 6;
  int lane = threadIdx.x & 63;
  int n = blockIdx.x * 4 + w;
  int base = offsets[n];
  int deg = offsets[n + 1] - base;
  int degc = min(deg, MAXD);
  int degp = ((degc + 5) / 6) * 6;

  float advv = adst[n];
  float m = -INFINITY;
  for (int e = lane; e < deg; e += 64) {
    int s = edge_src[base + e];
    float ev = lrelu(asrc[s] + advv);
    if (e < MAXD) { lsoff[w][e] = s * (NCLS * 4); lalpha[w][e] = ev; }
    m = fmaxf(m, ev);
  }
  m = wave_max(m);
  float ssum = 0.f;
  for (int e = lane; e < deg; e += 64) {
    float ev;
    if (e < MAXD) ev = lalpha[w][e];
    else { int s = edge_src[base + e]; ev = lrelu(asrc[s] + advv); }
    ssum += __expf(ev - m);
  }
  float inv = 1.f / (wave_sum(ssum) + 1e-16f);
  for (int e = lane; e < degc; e += 64) lalpha[w][e] = __expf(lalpha[w][e] - m) * inv;
  {
    int e = degc + lane;
    if (e < degp) { lalpha[w][e] = 0.f; lsoff[w][e] = 0; }
  }
  __builtin_amdgcn_wave_barrier();

  int esub = lane / 20;
  int cg = lane - esub * 20;
  bool act = esub < 3;
  f32x2 axy = {0.f, 0.f};
  const char* hb = (const char*)h2 + cg * 8;
  for (int i = 0; i < degp; i += 6) {
    if (act) {
      int sA = i + esub, sB = i + 3 + esub;
      float aA = lalpha[w][sA], aB = lalpha[w][sB];
      int oA = lsoff[w][sA], oB = lsoff[w][sB];
      float2 hA = *(const float2*)(hb + oA);
      float2 hB = *(const float2*)(hb + oB);
      f32x2 vA = {hA.x, hA.y}, vB = {hB.x, hB.y};
      f32x2 aA2 = {aA, aA}, aB2 = {aB, aB};
      axy += aA2 * vA + aB2 * vB;
    }
  }
  for (int e = MAXD + esub; e < deg; e += 3) {   // guard, never runs
    if (act) {
      int s = edge_src[base + e];
      float a = __expf(lrelu(asrc[s] + advv) - m) * inv;
      float2 hv = *(const float2*)(hb + (size_t)s * (NCLS * 4));
      axy.x += a * hv.x; axy.y += a * hv.y;
    }
  }
  float ax = axy.x, ay = axy.y;
  float ax1 = __shfl(ax, lane + 20), ax2 = __shfl(ax, lane + 40);
  float ay1 = __shfl(ay, lane + 20), ay2 = __shfl(ay, lane + 40);
  float v0 = -INFINITY, v1 = -INFINITY;
  if (lane < 20) {
    v0 = ax + ax1 + ax2 + b2[2 * cg];
    v1 = ay + ay1 + ay2 + b2[2 * cg + 1];
  }
  float m2 = wave_max(fmaxf(v0, v1));
  float se = wave_sum(lane < 20 ? __expf(v0 - m2) + __expf(v1 - m2) : 0.f);
  if (lane < 20) {
    float ls = logf(se);
    *(float2*)&out[(size_t)n * NCLS + 2 * cg] = make_float2(v0 - m2 - ls, v1 - m2 - ls);
  }
}

extern "C" void kernel_launch(void* const* d_in, const int* in_sizes, int n_in,
                              void* d_out, int out_size, void* d_ws, size_t ws_size,
                              hipStream_t stream) {
  const float* x   = (const float*)d_in[0];
  const int*   ei  = (const int*)d_in[1];
  const float* W1  = (const float*)d_in[2];
  const float* as1 = (const float*)d_in[3];
  const float* ad1 = (const float*)d_in[4];
  const float* b1  = (const float*)d_in[5];
  const float* W2  = (const float*)d_in[6];
  const float* as2 = (const float*)d_in[7];
  const float* ad2 = (const float*)d_in[8];
  const float* b2  = (const float*)d_in[9];
  float* out = (float*)d_out;

  char* ws = (char*)d_ws;
  size_t off = 0;
  auto alloc = [&](size_t bytes) -> char* {
    char* p = ws + off;
    off += (bytes + 255) & ~(size_t)255;
    return p;
  };
  int* deg      = (int*)alloc((size_t)N_NODES * 4);   // deg+cursor adjacent: one memset
  int* cursor   = (int*)alloc((size_t)N_NODES * 4);
  int* offsets  = (int*)alloc((size_t)(N_NODES + 1) * 4);
  int* edge_src = (int*)alloc((size_t)EP * 4);
  unsigned short* xb    = (unsigned short*)alloc((size_t)MPAD * F_IN * 2);
  unsigned short* wb1t  = (unsigned short*)alloc((size_t)D1 * F_IN * 2);
  unsigned short* wb2t  = (unsigned short*)alloc((size_t)48 * D1 * 2);
  unsigned short* h1b   = (unsigned short*)alloc((size_t)N_NODES * D1 * 2);
  unsigned short* out1b = (unsigned short*)alloc((size_t)MPAD * D1 * 2);
  float* asrc1  = (float*)alloc((size_t)N_NODES * H1 * 4);
  float* adst1  = (float*)alloc((size_t)N_NODES * H1 * 4);
  unsigned int* alphaP = (unsigned int*)alloc((size_t)H1 * EP * 4);
  float* inv1   = (float*)alloc((size_t)N_NODES * H1 * 4);
  float* h2     = (float*)alloc((size_t)N_NODES * NCLS * 4);
  float* asrc2  = (float*)alloc((size_t)N_NODES * 4);
  float* adst2  = (float*)alloc((size_t)N_NODES * 4);

  hipMemsetAsync(deg, 0, (size_t)((char*)offsets - (char*)deg), stream);  // deg + cursor

  prep_kernel<<<PB_CNT, 256, 0, stream>>>(x, W1, W2, ei, xb, wb1t, wb2t, deg, out1b);
  scan_kernel<<<1, SCAN_T, 0, stream>>>(deg, offsets);
  gemm1_mfma<<<G1_BLOCKS + 1329, 256, 0, stream>>>(xb, wb1t, as1, ad1, h1b, asrc1, adst1,
                                                   ei, offsets, cursor, edge_src);
  alpha1_kernel<<<N_NODES / 4, 256, 0, stream>>>(offsets, edge_src, asrc1, adst1, alphaP, inv1);
  agg1_gather<<<(N_NODES / 32) * 8, 256, 0, stream>>>(offsets, alphaP, inv1, h1b, b1, out1b);

  gemm2_mfma<<<MPAD / 64, 256, 0, stream>>>(out1b, wb2t, as2, ad2, h2, asrc2, adst2);
  agg2_kernel<<<N_NODES / 4, 256, 0, stream>>>(offsets, edge_src, asrc2, adst2, h2, b2, out);
}